// Round 1
// baseline (1253.751 us; speedup 1.0000x reference)
//
#include <hip/hip_runtime.h>
#include <math.h>

#define NN 30000          // nodes
#define NE 480000         // edges
#define FEA 16            // edge feature dim
#define HID 64
#define NHEAD 4
#define NPROJ 256         // NHEAD*HID
#define CIN1 128          // F + HID
#define NG 64             // graphs
#define LEAKK 0.2f

// ---- small-constant region layout (float offsets) ----
#define S_MEANEA 0    // 16
#define S_KF1    16   // 64  (K1 [16,4])
#define S_C1     80   // 4
#define S_AEL1   84   // 4
#define S_KF2    88   // 64
#define S_C2     152  // 4
#define S_AEL2   156  // 4
#define S_MS1    160  // 512 (Ms1 [128,4])
#define S_MD1    672  // 512
#define S_MS2    1184 // 256 (Ms2 [64,4])
#define S_MD2    1440 // 256

__device__ __forceinline__ float eluf(float v) { return v > 0.f ? v : expm1f(v); }
__device__ __forceinline__ float leakyf(float v) { return v >= 0.f ? v : LEAKK * v; }

// ---- mean of edge_attr over rows: accumulate sums into S[S_MEANEA..] ----
__global__ void edge_mean_kernel(const float* __restrict__ EA, float* __restrict__ S) {
    __shared__ float red[256];
    int t = threadIdx.x;
    int col = t & 15;
    int rbase = blockIdx.x * 1024 + (t >> 4);
    float sum = 0.f;
    for (int i = 0; i < 64; i++) {
        int r = rbase + i * 16;
        if (r < NE) sum += EA[(size_t)r * FEA + col];
    }
    red[t] = sum;
    __syncthreads();
    if (t < 16) {
        float v = 0.f;
        for (int j = 0; j < 16; j++) v += red[t + j * 16];
        atomicAdd(&S[S_MEANEA + t], v);
    }
}

// ---- fold all attention weight matrices into small matrices ----
__global__ void prep_small_kernel(
    const float* __restrict__ W1, const float* __restrict__ as1, const float* __restrict__ ad1,
    const float* __restrict__ ae1, const float* __restrict__ leW1,
    const float* __restrict__ W2, const float* __restrict__ as2, const float* __restrict__ ad2,
    const float* __restrict__ ae2, const float* __restrict__ leW2,
    const float* __restrict__ edge_W, const float* __restrict__ edge_b, float* __restrict__ S) {
    __shared__ float M1[256], M2[256], meh[64];
    int t = threadIdx.x;
    if (t < 16) S[S_MEANEA + t] *= (1.0f / (float)NE);
    __syncthreads();
    // M[k,h] = sum_c leW[k, h*64+c] * ae[h,c]
    {
        int k = t >> 2, h = t & 3;
        float m1 = 0.f, m2 = 0.f;
        for (int c = 0; c < 64; c++) {
            m1 += leW1[k * 256 + h * 64 + c] * ae1[h * 64 + c];
            m2 += leW2[k * 256 + h * 64 + c] * ae2[h * 64 + c];
        }
        M1[t] = m1; M2[t] = m2;
    }
    // mean_eh[k] = meanEA @ edge_W + edge_b   (layer independent)
    if (t < 64) {
        float v = edge_b[t];
        for (int f = 0; f < FEA; f++) v += S[S_MEANEA + f] * edge_W[f * 64 + t];
        meh[t] = v;
    }
    __syncthreads();
    if (t < 64) { // Kf[f,h] = edge_W @ M
        int f = t >> 2, h = t & 3;
        float k1 = 0.f, k2 = 0.f;
        for (int k = 0; k < 64; k++) {
            k1 += edge_W[f * 64 + k] * M1[k * 4 + h];
            k2 += edge_W[f * 64 + k] * M2[k * 4 + h];
        }
        S[S_KF1 + t] = k1; S[S_KF2 + t] = k2;
    } else if (t < 68) {
        int h = t - 64;
        float c1 = 0.f, c2 = 0.f, a1 = 0.f, a2 = 0.f;
        for (int k = 0; k < 64; k++) {
            c1 += edge_b[k] * M1[k * 4 + h];
            c2 += edge_b[k] * M2[k * 4 + h];
            a1 += meh[k] * M1[k * 4 + h];
            a2 += meh[k] * M2[k * 4 + h];
        }
        S[S_C1 + h] = c1; S[S_C2 + h] = c2;
        S[S_AEL1 + h] = a1; S[S_AEL2 + h] = a2;
    }
    // Ms1/Md1 [128,4]
    for (int i = t; i < 512; i += 256) {
        int k = i >> 2, h = i & 3;
        float s = 0.f, d = 0.f;
        for (int c = 0; c < 64; c++) {
            float w = W1[k * 256 + h * 64 + c];
            s += w * as1[h * 64 + c];
            d += w * ad1[h * 64 + c];
        }
        S[S_MS1 + i] = s; S[S_MD1 + i] = d;
    }
    // Ms2/Md2 [64,4]
    for (int i = t; i < 256; i += 256) {
        int k = i >> 2, h = i & 3;
        float s = 0.f, d = 0.f;
        for (int c = 0; c < 64; c++) {
            float w = W2[k * 256 + h * 64 + c];
            s += w * as2[h * 64 + c];
            d += w * ad2[h * 64 + c];
        }
        S[S_MS2 + i] = s; S[S_MD2 + i] = d;
    }
}

// ---- h0 = concat(x, node_emb[node_type]) ----
__global__ void build_h0_kernel(const float* __restrict__ x, const float* __restrict__ node_emb,
                                const int* __restrict__ node_type, float* __restrict__ h0) {
    size_t i = (size_t)blockIdx.x * 256 + threadIdx.x;
    if (i >= (size_t)NN * 128) return;
    int n = (int)(i >> 7);
    int k = (int)(i & 127);
    h0[i] = (k < 64) ? x[(size_t)n * 64 + k] : node_emb[node_type[n] * 64 + (k - 64)];
}

// ---- CSR build ----
__global__ void count_kernel(const int* __restrict__ dst, int* __restrict__ cnt) {
    int e = blockIdx.x * 256 + threadIdx.x;
    if (e < NE) atomicAdd(&cnt[dst[e]], 1);
}

__global__ void scan_kernel(const int* __restrict__ cnt, int* __restrict__ off) {
    __shared__ int sbuf[1024];
    __shared__ int carry;
    int tid = threadIdx.x;
    if (tid == 0) carry = 0;
    __syncthreads();
    for (int base = 0; base < NN; base += 1024) {
        int i = base + tid;
        int v = (i < NN) ? cnt[i] : 0;
        sbuf[tid] = v;
        __syncthreads();
        for (int ofs = 1; ofs < 1024; ofs <<= 1) {
            int tv = (tid >= ofs) ? sbuf[tid - ofs] : 0;
            __syncthreads();
            sbuf[tid] += tv;
            __syncthreads();
        }
        int incl = sbuf[tid];
        if (i < NN) off[i] = carry + incl - v;
        __syncthreads();
        if (tid == 0) carry += sbuf[1023];
        __syncthreads();
    }
    if (tid == 0) off[NN] = carry;
}

__global__ void scatter_kernel(const int* __restrict__ dst, const int* __restrict__ eoff,
                               int* __restrict__ pos, int* __restrict__ esort) {
    int e = blockIdx.x * 256 + threadIdx.x;
    if (e >= NE) return;
    int d = dst[e];
    int p = atomicAdd(&pos[d], 1);
    esort[eoff[d] + p] = e;
}

__global__ void gcount_kernel(const int* __restrict__ batch, int* __restrict__ gcnt) {
    int n = blockIdx.x * 256 + threadIdx.x;
    if (n < NN) atomicAdd(&gcnt[batch[n]], 1);
}

__global__ void goff_kernel(const int* __restrict__ gcnt, int* __restrict__ goff) {
    if (threadIdx.x == 0) {
        int run = 0;
        for (int g = 0; g < NG; g++) { goff[g] = run; run += gcnt[g]; }
        goff[NG] = run;
    }
}

// ---- tiled fp32 GEMM: C[M,Nc] = A[M,K] @ B[K,Nc]; Nc multiple of 64, K multiple of 16 ----
__global__ void gemm_kernel(const float* __restrict__ A, const float* __restrict__ B,
                            float* __restrict__ C, int M, int Nc, int K) {
    __shared__ float As[16][68];
    __shared__ float Bs[16][68];
    int tx = threadIdx.x & 15, ty = threadIdx.x >> 4;
    int m0 = blockIdx.x * 64, n0 = blockIdx.y * 64;
    float acc[4][4] = {};
    for (int k0 = 0; k0 < K; k0 += 16) {
        for (int i = threadIdx.x; i < 64 * 16; i += 256) {
            int r = i >> 4, c = i & 15;
            int m = m0 + r;
            As[c][r] = (m < M) ? A[(size_t)m * K + k0 + c] : 0.f;
        }
        for (int i = threadIdx.x; i < 16 * 64; i += 256) {
            int r = i >> 6, c = i & 63;
            Bs[r][c] = B[(size_t)(k0 + r) * Nc + n0 + c];
        }
        __syncthreads();
#pragma unroll
        for (int k = 0; k < 16; k++) {
            float a[4], b[4];
#pragma unroll
            for (int i = 0; i < 4; i++) a[i] = As[k][ty * 4 + i];
#pragma unroll
            for (int j = 0; j < 4; j++) b[j] = Bs[k][tx * 4 + j];
#pragma unroll
            for (int i = 0; i < 4; i++)
#pragma unroll
                for (int j = 0; j < 4; j++) acc[i][j] += a[i] * b[j];
        }
        __syncthreads();
    }
    for (int i = 0; i < 4; i++) {
        int m = m0 + ty * 4 + i;
        if (m < M)
            for (int j = 0; j < 4; j++) C[(size_t)m * Nc + n0 + tx * 4 + j] = acc[i][j];
    }
}

// ---- a_s/a_d = X @ Ms / Md  ([N,4] each) ----
template <int KD>
__global__ void attn_sd_kernel(const float* __restrict__ X, const float* __restrict__ Ms,
                               const float* __restrict__ Md, float* __restrict__ as_,
                               float* __restrict__ ad_) {
    __shared__ float xt[64 * (KD + 1)];
    __shared__ float ms[KD * 4];
    __shared__ float md[KD * 4];
    int n0 = blockIdx.x * 64;
    for (int i = threadIdx.x; i < 64 * KD; i += 256) {
        int r = i / KD, k = i - r * KD;
        int n = n0 + r;
        xt[r * (KD + 1) + k] = (n < NN) ? X[(size_t)n * KD + k] : 0.f;
    }
    for (int i = threadIdx.x; i < KD * 4; i += 256) { ms[i] = Ms[i]; md[i] = Md[i]; }
    __syncthreads();
    int r = threadIdx.x >> 2, h = threadIdx.x & 3;
    float s = 0.f, d = 0.f;
#pragma unroll 8
    for (int k = 0; k < KD; k++) {
        float xv = xt[r * (KD + 1) + k];
        s += xv * ms[k * 4 + h];
        d += xv * md[k * 4 + h];
    }
    int n = n0 + r;
    if (n < NN) { as_[n * 4 + h] = s; ad_[n * 4 + h] = d; }
}

// ---- per-edge scores: ex = exp(leaky(a_s[src]+a_d[dst]+a_e)); den[dst] += ex ----
__global__ void score_kernel(const int* __restrict__ src, const int* __restrict__ dst,
                             const float* __restrict__ EA, const float* __restrict__ S,
                             int kf_off, int c_off, const float* __restrict__ as_,
                             const float* __restrict__ ad_, float* __restrict__ sc,
                             float* __restrict__ den) {
    int e = blockIdx.x * 256 + threadIdx.x;
    if (e >= NE) return;
    int s = src[e], d = dst[e];
    float ae[4];
#pragma unroll
    for (int h = 0; h < 4; h++) ae[h] = S[c_off + h];
    const float4* EA4 = (const float4*)(EA + (size_t)e * FEA);
#pragma unroll
    for (int q = 0; q < 4; q++) {
        float4 v = EA4[q];
        float vv[4] = {v.x, v.y, v.z, v.w};
#pragma unroll
        for (int j = 0; j < 4; j++) {
            int f = q * 4 + j;
#pragma unroll
            for (int h = 0; h < 4; h++) ae[h] += vv[j] * S[kf_off + f * 4 + h];
        }
    }
#pragma unroll
    for (int h = 0; h < 4; h++) {
        float x = as_[s * 4 + h] + ad_[d * 4 + h] + ae[h];
        x = leakyf(x);
        float ex = expf(x);
        sc[(size_t)e * 4 + h] = ex;
        atomicAdd(&den[d * 4 + h], ex);
    }
}

// ---- add self-loop contribution to den ----
__global__ void selfloop_den_kernel(const float* __restrict__ as_, const float* __restrict__ ad_,
                                    const float* __restrict__ Sael, float* __restrict__ den) {
    int i = blockIdx.x * 256 + threadIdx.x;
    if (i >= NN * 4) return;
    int h = i & 3;
    float x = leakyf(as_[i] + ad_[i] + Sael[h]);
    den[i] += expf(x);
}

// ---- GAT aggregation: block per dst node; out = elu(mean_h(sum alpha*h[src]) + bias) ----
__global__ void gat_agg_kernel(const int* __restrict__ eoff, const int* __restrict__ esort,
                               const int* __restrict__ src, const float* __restrict__ sc,
                               const float* __restrict__ den, const float* __restrict__ hproj,
                               const float* __restrict__ as_, const float* __restrict__ ad_,
                               const float* __restrict__ Sael, const float* __restrict__ bias,
                               float* __restrict__ out) {
    __shared__ float red[256];
    int n = blockIdx.x;
    int t = threadIdx.x;
    int h = t >> 6;
    float invden = 1.f / den[n * 4 + h];
    float acc = 0.f;
    int b = eoff[n], e_end = eoff[n + 1];
    for (int idx = b; idx < e_end; ++idx) {
        int e = esort[idx];
        int s = src[e];
        acc += sc[(size_t)e * 4 + h] * hproj[(size_t)s * NPROJ + t];
    }
    // self loop
    float x = leakyf(as_[n * 4 + h] + ad_[n * 4 + h] + Sael[h]);
    acc += expf(x) * hproj[(size_t)n * NPROJ + t];
    acc *= invden;
    red[t] = acc;
    __syncthreads();
    if (t < 64) {
        float v = red[t] + red[t + 64] + red[t + 128] + red[t + 192];
        v = 0.25f * v + bias[t];
        out[(size_t)n * HID + t] = eluf(v);
    }
}

// ---- SAGE mean aggregation ----
__global__ void sage_agg_kernel(const float* __restrict__ h2, const int* __restrict__ eoff,
                                const int* __restrict__ esort, const int* __restrict__ src,
                                const int* __restrict__ cnt, float* __restrict__ aggout) {
    int n = blockIdx.x * 4 + (threadIdx.x >> 6);
    if (n >= NN) return;
    int c = threadIdx.x & 63;
    float sum = 0.f;
    int b = eoff[n], e = eoff[n + 1];
    for (int idx = b; idx < e; ++idx) {
        int ed = esort[idx];
        int s = src[ed];
        sum += h2[(size_t)s * HID + c];
    }
    float dg = (float)cnt[n];
    if (dg < 1.f) dg = 1.f;
    aggout[(size_t)n * HID + c] = sum / dg;
}

// ---- h3 = elu(agg @ Wl + bl + h2 @ Wr) ----
__global__ void sage_kernel(const float* __restrict__ agg, const float* __restrict__ h2,
                            const float* __restrict__ Wl, const float* __restrict__ bl,
                            const float* __restrict__ Wr, float* __restrict__ h3) {
    __shared__ float Aa[64][64];
    __shared__ float Ah[64][64];
    __shared__ float Bl[64][64];
    __shared__ float Br[64][64];
    int n0 = blockIdx.x * 64;
    int t = threadIdx.x;
    for (int i = t; i < 4096; i += 256) {
        int r = i >> 6, c = i & 63;
        int n = n0 + r;
        Aa[r][c] = (n < NN) ? agg[(size_t)n * HID + c] : 0.f;
        Ah[r][c] = (n < NN) ? h2[(size_t)n * HID + c] : 0.f;
        Bl[r][c] = Wl[i];
        Br[r][c] = Wr[i];
    }
    __syncthreads();
    int c = t & 63;
    for (int j = 0; j < 16; j++) {
        int r = (t >> 6) + 4 * j;
        int n = n0 + r;
        if (n >= NN) continue;
        float acc = bl[c];
        for (int k = 0; k < 64; k++) acc += Aa[r][k] * Bl[k][c] + Ah[r][k] * Br[k][c];
        h3[(size_t)n * HID + c] = eluf(acc);
    }
}

// ---- per-graph mean pool (batch sorted -> contiguous ranges) ----
__global__ void pool_kernel(const float* __restrict__ h3, const int* __restrict__ goff,
                            float* __restrict__ gmean) {
    __shared__ float red[256];
    int g = blockIdx.x, t = threadIdx.x;
    int c = t & 63, li = t >> 6;
    int b = goff[g], e = goff[g + 1];
    float sum = 0.f;
    for (int r = b + li; r < e; r += 4) sum += h3[(size_t)r * HID + c];
    red[t] = sum;
    __syncthreads();
    if (t < 64) {
        float v = red[t] + red[t + 64] + red[t + 128] + red[t + 192];
        float cntf = (float)(e - b);
        if (cntf < 1.f) cntf = 1.f;
        gmean[g * HID + t] = v / cntf;
    }
}

// ---- final MLP head -> d_out[192] ----
__global__ void mlp_kernel(const float* __restrict__ gmean, const float* __restrict__ lin1W,
                           const float* __restrict__ lin1b, const float* __restrict__ lin2W,
                           const float* __restrict__ lin2b, const float* __restrict__ telW,
                           const float* __restrict__ telb, const float* __restrict__ compW,
                           const float* __restrict__ compb, const float* __restrict__ pchW,
                           const float* __restrict__ pchb, float* __restrict__ out) {
    __shared__ float G[4096], Wb[4096], G1[4096], G2[4096];
    int t = threadIdx.x;
    for (int i = t; i < 4096; i += 256) { G[i] = gmean[i]; Wb[i] = lin1W[i]; }
    __syncthreads();
    int c = t & 63;
    for (int j = 0; j < 16; j++) {
        int r = (t >> 6) + 4 * j;
        float acc = lin1b[c];
        for (int k = 0; k < 64; k++) acc += G[r * 64 + k] * Wb[k * 64 + c];
        G1[r * 64 + c] = eluf(acc);
    }
    __syncthreads();
    for (int i = t; i < 4096; i += 256) Wb[i] = lin2W[i];
    __syncthreads();
    for (int j = 0; j < 16; j++) {
        int r = (t >> 6) + 4 * j;
        float acc = lin2b[c];
        for (int k = 0; k < 64; k++) acc += G1[r * 64 + k] * Wb[k * 64 + c];
        G2[r * 64 + c] = acc;
    }
    __syncthreads();
    if (t < 64) {
        int r = t;
        float a = telb[0], b_ = compb[0], p = pchb[0];
        for (int k = 0; k < 64; k++) {
            float v = G2[r * 64 + k];
            a += v * telW[k];
            b_ += v * compW[k];
            p += v * pchW[k];
        }
        out[r] = a;
        out[64 + r] = b_;
        out[128 + r] = p;
    }
}

extern "C" void kernel_launch(void* const* d_in, const int* in_sizes, int n_in,
                              void* d_out, int out_size, void* d_ws, size_t ws_size,
                              hipStream_t stream) {
    const float* x        = (const float*)d_in[0];
    const float* EA       = (const float*)d_in[1];
    const float* node_emb = (const float*)d_in[2];
    const float* edge_W   = (const float*)d_in[3];
    const float* edge_b   = (const float*)d_in[4];
    const float* W1       = (const float*)d_in[5];
    const float* as1      = (const float*)d_in[6];
    const float* ad1      = (const float*)d_in[7];
    const float* ae1      = (const float*)d_in[8];
    const float* leW1     = (const float*)d_in[9];
    const float* b1       = (const float*)d_in[10];
    const float* W2       = (const float*)d_in[11];
    const float* as2      = (const float*)d_in[12];
    const float* ad2      = (const float*)d_in[13];
    const float* ae2      = (const float*)d_in[14];
    const float* leW2     = (const float*)d_in[15];
    const float* b2       = (const float*)d_in[16];
    const float* sage_Wl  = (const float*)d_in[17];
    const float* sage_bl  = (const float*)d_in[18];
    const float* sage_Wr  = (const float*)d_in[19];
    const float* lin1_W   = (const float*)d_in[20];
    const float* lin1_b   = (const float*)d_in[21];
    const float* lin2_W   = (const float*)d_in[22];
    const float* lin2_b   = (const float*)d_in[23];
    const float* tel_W    = (const float*)d_in[24];
    const float* tel_b    = (const float*)d_in[25];
    const float* comp_W   = (const float*)d_in[26];
    const float* comp_b   = (const float*)d_in[27];
    const float* pch_W    = (const float*)d_in[28];
    const float* pch_b    = (const float*)d_in[29];
    const int* edge_index = (const int*)d_in[30];
    const int* batch      = (const int*)d_in[31];
    const int* node_type  = (const int*)d_in[32];
    float* outp = (float*)d_out;

    const int* srcp = edge_index;
    const int* dstp = edge_index + NE;

    float* wf = (float*)d_ws;
    constexpr size_t OFF_H0    = 0;                               // N*128 (later aliased: agg + h3)
    constexpr size_t OFF_HPROJ = OFF_H0 + (size_t)NN * 128;       // N*256
    constexpr size_t OFF_H1    = OFF_HPROJ + (size_t)NN * 256;    // N*64
    constexpr size_t OFF_H2    = OFF_H1 + (size_t)NN * 64;        // N*64
    constexpr size_t OFF_SC    = OFF_H2 + (size_t)NN * 64;        // E*4
    constexpr size_t OFF_DEN   = OFF_SC + (size_t)NE * 4;         // N*4
    constexpr size_t OFF_AS    = OFF_DEN + (size_t)NN * 4;        // N*4
    constexpr size_t OFF_AD    = OFF_AS + (size_t)NN * 4;         // N*4
    constexpr size_t OFF_SMALL = OFF_AD + (size_t)NN * 4;         // 4096
    constexpr size_t OFF_GMEAN = OFF_SMALL + 4096;                // 4096
    constexpr size_t F_TOTAL   = OFF_GMEAN + 4096;

    int* wi    = (int*)(wf + F_TOTAL);
    int* cnt   = wi;                  // N
    int* eoff  = wi + NN;             // N+1
    int* pos   = eoff + (NN + 1);     // N
    int* esort = pos + NN;            // E
    int* gcnt  = esort + NE;          // 64
    int* goff  = gcnt + NG;           // 65

    float* h0    = wf + OFF_H0;
    float* hproj = wf + OFF_HPROJ;
    float* h1    = wf + OFF_H1;
    float* h2    = wf + OFF_H2;
    float* sc    = wf + OFF_SC;
    float* den   = wf + OFF_DEN;
    float* as_   = wf + OFF_AS;
    float* ad_   = wf + OFF_AD;
    float* S     = wf + OFF_SMALL;
    float* gmean = wf + OFF_GMEAN;
    float* aggb  = wf + OFF_H0;                      // alias (h0 dead by then)
    float* h3    = wf + OFF_H0 + (size_t)NN * 64;    // alias

    // zero accumulators
    hipMemsetAsync(S + S_MEANEA, 0, 16 * sizeof(float), stream);
    hipMemsetAsync(cnt, 0, NN * sizeof(int), stream);
    hipMemsetAsync(pos, 0, NN * sizeof(int), stream);
    hipMemsetAsync(gcnt, 0, NG * sizeof(int), stream);

    // constants prep
    edge_mean_kernel<<<(NE + 1023) / 1024, 256, 0, stream>>>(EA, S);
    prep_small_kernel<<<1, 256, 0, stream>>>(W1, as1, ad1, ae1, leW1,
                                             W2, as2, ad2, ae2, leW2,
                                             edge_W, edge_b, S);
    build_h0_kernel<<<(NN * 128 + 255) / 256, 256, 0, stream>>>(x, node_emb, node_type, h0);

    // CSR
    count_kernel<<<(NE + 255) / 256, 256, 0, stream>>>(dstp, cnt);
    scan_kernel<<<1, 1024, 0, stream>>>(cnt, eoff);
    scatter_kernel<<<(NE + 255) / 256, 256, 0, stream>>>(dstp, eoff, pos, esort);
    gcount_kernel<<<(NN + 255) / 256, 256, 0, stream>>>(batch, gcnt);
    goff_kernel<<<1, 64, 0, stream>>>(gcnt, goff);

    // ----- GAT layer 1 -----
    gemm_kernel<<<dim3((NN + 63) / 64, 4), 256, 0, stream>>>(h0, W1, hproj, NN, NPROJ, CIN1);
    attn_sd_kernel<128><<<(NN + 63) / 64, 256, 0, stream>>>(h0, S + S_MS1, S + S_MD1, as_, ad_);
    hipMemsetAsync(den, 0, (size_t)NN * 4 * sizeof(float), stream);
    score_kernel<<<(NE + 255) / 256, 256, 0, stream>>>(srcp, dstp, EA, S, S_KF1, S_C1, as_, ad_, sc, den);
    selfloop_den_kernel<<<(NN * 4 + 255) / 256, 256, 0, stream>>>(as_, ad_, S + S_AEL1, den);
    gat_agg_kernel<<<NN, 256, 0, stream>>>(eoff, esort, srcp, sc, den, hproj, as_, ad_, S + S_AEL1, b1, h1);

    // ----- GAT layer 2 -----
    gemm_kernel<<<dim3((NN + 63) / 64, 4), 256, 0, stream>>>(h1, W2, hproj, NN, NPROJ, HID);
    attn_sd_kernel<64><<<(NN + 63) / 64, 256, 0, stream>>>(h1, S + S_MS2, S + S_MD2, as_, ad_);
    hipMemsetAsync(den, 0, (size_t)NN * 4 * sizeof(float), stream);
    score_kernel<<<(NE + 255) / 256, 256, 0, stream>>>(srcp, dstp, EA, S, S_KF2, S_C2, as_, ad_, sc, den);
    selfloop_den_kernel<<<(NN * 4 + 255) / 256, 256, 0, stream>>>(as_, ad_, S + S_AEL2, den);
    gat_agg_kernel<<<NN, 256, 0, stream>>>(eoff, esort, srcp, sc, den, hproj, as_, ad_, S + S_AEL2, b2, h2);

    // ----- SAGE -----
    sage_agg_kernel<<<(NN + 3) / 4, 256, 0, stream>>>(h2, eoff, esort, srcp, cnt, aggb);
    sage_kernel<<<(NN + 63) / 64, 256, 0, stream>>>(aggb, h2, sage_Wl, sage_bl, sage_Wr, h3);

    // ----- pool + MLP head -----
    pool_kernel<<<NG, 256, 0, stream>>>(h3, goff, gmean);
    mlp_kernel<<<1, 256, 0, stream>>>(gmean, lin1_W, lin1_b, lin2_W, lin2_b,
                                      tel_W, tel_b, comp_W, comp_b, pch_W, pch_b, outp);
}

// Round 2
// 777.196 us; speedup vs baseline: 1.6132x; 1.6132x over previous
//
#include <hip/hip_runtime.h>
#include <math.h>

#define NN 30000          // nodes
#define NE 480000         // edges
#define FEA 16            // edge feature dim
#define HID 64
#define NHEAD 4
#define NPROJ 256         // NHEAD*HID
#define CIN1 128          // F + HID
#define NG 64             // graphs
#define LEAKK 0.2f

// ---- small-constant region layout (float offsets) ----
#define S_MEANEA 0    // 16
#define S_KF1    16   // 64  (K1 [16,4])
#define S_C1     80   // 4
#define S_AEL1   84   // 4
#define S_KF2    88   // 64
#define S_C2     152  // 4
#define S_AEL2   156  // 4
#define S_MS1    160  // 512 (Ms1 [128,4])
#define S_MD1    672  // 512
#define S_MS2    1184 // 256 (Ms2 [64,4])
#define S_MD2    1440 // 256

__device__ __forceinline__ float eluf(float v) { return v > 0.f ? v : expm1f(v); }
__device__ __forceinline__ float leakyf(float v) { return v >= 0.f ? v : LEAKK * v; }

// ---- mean of edge_attr over rows: accumulate sums into S[S_MEANEA..] ----
__global__ void edge_mean_kernel(const float* __restrict__ EA, float* __restrict__ S) {
    __shared__ float red[256];
    int t = threadIdx.x;
    int col = t & 15;
    int rbase = blockIdx.x * 1024 + (t >> 4);
    float sum = 0.f;
    for (int i = 0; i < 64; i++) {
        int r = rbase + i * 16;
        if (r < NE) sum += EA[(size_t)r * FEA + col];
    }
    red[t] = sum;
    __syncthreads();
    if (t < 16) {
        float v = 0.f;
        for (int j = 0; j < 16; j++) v += red[t + j * 16];
        atomicAdd(&S[S_MEANEA + t], v);
    }
}

// ---- fold all attention weight matrices into small matrices ----
__global__ void prep_small_kernel(
    const float* __restrict__ W1, const float* __restrict__ as1, const float* __restrict__ ad1,
    const float* __restrict__ ae1, const float* __restrict__ leW1,
    const float* __restrict__ W2, const float* __restrict__ as2, const float* __restrict__ ad2,
    const float* __restrict__ ae2, const float* __restrict__ leW2,
    const float* __restrict__ edge_W, const float* __restrict__ edge_b, float* __restrict__ S) {
    __shared__ float M1[256], M2[256], meh[64];
    int t = threadIdx.x;
    if (t < 16) S[S_MEANEA + t] *= (1.0f / (float)NE);
    __syncthreads();
    {
        int k = t >> 2, h = t & 3;
        float m1 = 0.f, m2 = 0.f;
        for (int c = 0; c < 64; c++) {
            m1 += leW1[k * 256 + h * 64 + c] * ae1[h * 64 + c];
            m2 += leW2[k * 256 + h * 64 + c] * ae2[h * 64 + c];
        }
        M1[t] = m1; M2[t] = m2;
    }
    if (t < 64) {
        float v = edge_b[t];
        for (int f = 0; f < FEA; f++) v += S[S_MEANEA + f] * edge_W[f * 64 + t];
        meh[t] = v;
    }
    __syncthreads();
    if (t < 64) {
        int f = t >> 2, h = t & 3;
        float k1 = 0.f, k2 = 0.f;
        for (int k = 0; k < 64; k++) {
            k1 += edge_W[f * 64 + k] * M1[k * 4 + h];
            k2 += edge_W[f * 64 + k] * M2[k * 4 + h];
        }
        S[S_KF1 + t] = k1; S[S_KF2 + t] = k2;
    } else if (t < 68) {
        int h = t - 64;
        float c1 = 0.f, c2 = 0.f, a1 = 0.f, a2 = 0.f;
        for (int k = 0; k < 64; k++) {
            c1 += edge_b[k] * M1[k * 4 + h];
            c2 += edge_b[k] * M2[k * 4 + h];
            a1 += meh[k] * M1[k * 4 + h];
            a2 += meh[k] * M2[k * 4 + h];
        }
        S[S_C1 + h] = c1; S[S_C2 + h] = c2;
        S[S_AEL1 + h] = a1; S[S_AEL2 + h] = a2;
    }
    for (int i = t; i < 512; i += 256) {
        int k = i >> 2, h = i & 3;
        float s = 0.f, d = 0.f;
        for (int c = 0; c < 64; c++) {
            float w = W1[k * 256 + h * 64 + c];
            s += w * as1[h * 64 + c];
            d += w * ad1[h * 64 + c];
        }
        S[S_MS1 + i] = s; S[S_MD1 + i] = d;
    }
    for (int i = t; i < 256; i += 256) {
        int k = i >> 2, h = i & 3;
        float s = 0.f, d = 0.f;
        for (int c = 0; c < 64; c++) {
            float w = W2[k * 256 + h * 64 + c];
            s += w * as2[h * 64 + c];
            d += w * ad2[h * 64 + c];
        }
        S[S_MS2 + i] = s; S[S_MD2 + i] = d;
    }
}

// ---- h0 = concat(x, node_emb[node_type]) ----
__global__ void build_h0_kernel(const float* __restrict__ x, const float* __restrict__ node_emb,
                                const int* __restrict__ node_type, float* __restrict__ h0) {
    size_t i = (size_t)blockIdx.x * 256 + threadIdx.x;
    if (i >= (size_t)NN * 128) return;
    int n = (int)(i >> 7);
    int k = (int)(i & 127);
    h0[i] = (k < 64) ? x[(size_t)n * 64 + k] : node_emb[node_type[n] * 64 + (k - 64)];
}

// ---- CSR build ----
__global__ void count_kernel(const int* __restrict__ dst, int* __restrict__ cnt) {
    int e = blockIdx.x * 256 + threadIdx.x;
    if (e < NE) atomicAdd(&cnt[dst[e]], 1);
}

// 3-kernel decoupled scan
__global__ void scan_blocks_kernel(const int* __restrict__ cnt, int* __restrict__ eoff,
                                   int* __restrict__ bsum) {
    __shared__ int wsum[16];
    int t = threadIdx.x;
    int i = blockIdx.x * 1024 + t;
    int v = (i < NN) ? cnt[i] : 0;
    int lane = t & 63;
    int incl = v;
#pragma unroll
    for (int ofs = 1; ofs < 64; ofs <<= 1) {
        int u = __shfl_up(incl, ofs, 64);
        if (lane >= ofs) incl += u;
    }
    int wid = t >> 6;
    if (lane == 63) wsum[wid] = incl;
    __syncthreads();
    if (t < 16) {
        int s = wsum[t];
#pragma unroll
        for (int ofs = 1; ofs < 16; ofs <<= 1) {
            int u = __shfl_up(s, ofs, 64);
            if (t >= ofs) s += u;
        }
        wsum[t] = s;
    }
    __syncthreads();
    int excl = incl - v + (wid > 0 ? wsum[wid - 1] : 0);
    if (i < NN) eoff[i] = excl;
    if (t == 1023) bsum[blockIdx.x] = excl + v;
}

__global__ void scan_tops_kernel(const int* __restrict__ bsum, int* __restrict__ boff, int nb) {
    int t = threadIdx.x; // 64
    int v = (t < nb) ? bsum[t] : 0;
    int incl = v;
#pragma unroll
    for (int ofs = 1; ofs < 64; ofs <<= 1) {
        int u = __shfl_up(incl, ofs, 64);
        if (t >= ofs) incl += u;
    }
    boff[t] = incl - v;
}

__global__ void scan_add_kernel(const int* __restrict__ boff, int* __restrict__ eoff) {
    int i = blockIdx.x * 256 + threadIdx.x;
    if (i < NN) eoff[i] += boff[i >> 10];
    if (i == 0) eoff[NN] = NE;
}

__global__ void scatter_kernel(const int* __restrict__ dst, const int* __restrict__ eoff,
                               int* __restrict__ pos, int* __restrict__ esort) {
    int e = blockIdx.x * 256 + threadIdx.x;
    if (e >= NE) return;
    int d = dst[e];
    int p = atomicAdd(&pos[d], 1);
    esort[eoff[d] + p] = e;
}

__global__ void gcount_kernel(const int* __restrict__ batch, int* __restrict__ gcnt) {
    int n = blockIdx.x * 256 + threadIdx.x;
    if (n < NN) atomicAdd(&gcnt[batch[n]], 1);
}

__global__ void goff_kernel(const int* __restrict__ gcnt, int* __restrict__ goff) {
    if (threadIdx.x == 0) {
        int run = 0;
        for (int g = 0; g < NG; g++) { goff[g] = run; run += gcnt[g]; }
        goff[NG] = run;
    }
}

// ---- fp32 GEMM: C[M,Nc] = A[M,K] @ B[K,Nc]; 128x128 tile, 8x8/thread, K%32==0, Nc%128==0 ----
__global__ __launch_bounds__(256) void gemm128_kernel(const float* __restrict__ A,
                                                      const float* __restrict__ B,
                                                      float* __restrict__ C,
                                                      int M, int Nc, int K) {
    __shared__ float As[32 * 132];
    __shared__ float Bs[32 * 132];
    int t = threadIdx.x;
    int tx = t & 15, ty = t >> 4;
    int m_base = blockIdx.x * 128, n_base = blockIdx.y * 128;
    float acc[8][8] = {};
    for (int k0 = 0; k0 < K; k0 += 32) {
#pragma unroll
        for (int i = 0; i < 4; i++) {
            int lin = t + i * 256;
            int row = lin >> 3;
            int kq = (lin & 7) * 4;
            int m = m_base + row;
            float4 f = {0.f, 0.f, 0.f, 0.f};
            if (m < M) f = *(const float4*)(A + (size_t)m * K + k0 + kq);
            As[(kq + 0) * 132 + row] = f.x;
            As[(kq + 1) * 132 + row] = f.y;
            As[(kq + 2) * 132 + row] = f.z;
            As[(kq + 3) * 132 + row] = f.w;
        }
#pragma unroll
        for (int i = 0; i < 4; i++) {
            int lin = t + i * 256;
            int kr = lin >> 5;
            int nc = (lin & 31) * 4;
            float4 f = *(const float4*)(B + (size_t)(k0 + kr) * Nc + n_base + nc);
            *(float4*)(&Bs[kr * 132 + nc]) = f;
        }
        __syncthreads();
#pragma unroll
        for (int k = 0; k < 32; k++) {
            float a[8], b[8];
            *(float4*)(a)     = *(const float4*)(&As[k * 132 + ty * 8]);
            *(float4*)(a + 4) = *(const float4*)(&As[k * 132 + ty * 8 + 4]);
            *(float4*)(b)     = *(const float4*)(&Bs[k * 132 + tx * 8]);
            *(float4*)(b + 4) = *(const float4*)(&Bs[k * 132 + tx * 8 + 4]);
#pragma unroll
            for (int i = 0; i < 8; i++)
#pragma unroll
                for (int j = 0; j < 8; j++) acc[i][j] += a[i] * b[j];
        }
        __syncthreads();
    }
    for (int i = 0; i < 8; i++) {
        int m = m_base + ty * 8 + i;
        if (m >= M) continue;
        float4 o0 = {acc[i][0], acc[i][1], acc[i][2], acc[i][3]};
        float4 o1 = {acc[i][4], acc[i][5], acc[i][6], acc[i][7]};
        *(float4*)(C + (size_t)m * Nc + n_base + tx * 8) = o0;
        *(float4*)(C + (size_t)m * Nc + n_base + tx * 8 + 4) = o1;
    }
}

// ---- a_s/a_d = X @ Ms / Md  ([N,4] each) ----
template <int KD>
__global__ void attn_sd_kernel(const float* __restrict__ X, const float* __restrict__ Ms,
                               const float* __restrict__ Md, float* __restrict__ as_,
                               float* __restrict__ ad_) {
    __shared__ float xt[64 * (KD + 1)];
    __shared__ float ms[KD * 4];
    __shared__ float md[KD * 4];
    int n0 = blockIdx.x * 64;
    for (int i = threadIdx.x; i < 64 * KD; i += 256) {
        int r = i / KD, k = i - r * KD;
        int n = n0 + r;
        xt[r * (KD + 1) + k] = (n < NN) ? X[(size_t)n * KD + k] : 0.f;
    }
    for (int i = threadIdx.x; i < KD * 4; i += 256) { ms[i] = Ms[i]; md[i] = Md[i]; }
    __syncthreads();
    int r = threadIdx.x >> 2, h = threadIdx.x & 3;
    float s = 0.f, d = 0.f;
#pragma unroll 8
    for (int k = 0; k < KD; k++) {
        float xv = xt[r * (KD + 1) + k];
        s += xv * ms[k * 4 + h];
        d += xv * md[k * 4 + h];
    }
    int n = n0 + r;
    if (n < NN) { as_[n * 4 + h] = s; ad_[n * 4 + h] = d; }
}

// ---- per-edge scores in CSR order: sc_sorted[idx], src_sorted[idx] ----
__global__ void score2_kernel(const int* __restrict__ esort, const int* __restrict__ src,
                              const int* __restrict__ dst, const float* __restrict__ EA,
                              const float* __restrict__ S, int kf_off, int c_off,
                              const float* __restrict__ as_, const float* __restrict__ ad_,
                              int* __restrict__ src_sorted, float* __restrict__ sc_sorted) {
    int idx = blockIdx.x * 256 + threadIdx.x;
    if (idx >= NE) return;
    int e = esort[idx];
    int s = src[e], d = dst[e];
    src_sorted[idx] = s;
    float ae[4];
#pragma unroll
    for (int h = 0; h < 4; h++) ae[h] = S[c_off + h];
    const float4* EA4 = (const float4*)(EA + (size_t)e * FEA);
#pragma unroll
    for (int q = 0; q < 4; q++) {
        float4 v = EA4[q];
        float vv[4] = {v.x, v.y, v.z, v.w};
#pragma unroll
        for (int j = 0; j < 4; j++) {
            int f = q * 4 + j;
#pragma unroll
            for (int h = 0; h < 4; h++) ae[h] += vv[j] * S[kf_off + f * 4 + h];
        }
    }
    float4 asv = ((const float4*)as_)[s];
    float4 adv = ((const float4*)ad_)[d];
    float4 r;
    r.x = expf(leakyf(asv.x + adv.x + ae[0]));
    r.y = expf(leakyf(asv.y + adv.y + ae[1]));
    r.z = expf(leakyf(asv.z + adv.z + ae[2]));
    r.w = expf(leakyf(asv.w + adv.w + ae[3]));
    ((float4*)sc_sorted)[idx] = r;
}

// ---- GAT aggregation: wave per node, float4 row loads, den folded in ----
__global__ __launch_bounds__(256) void gat_agg2_kernel(
    const int* __restrict__ eoff, const int* __restrict__ src_sorted,
    const float* __restrict__ sc_sorted, const float* __restrict__ hproj,
    const float* __restrict__ as_, const float* __restrict__ ad_,
    const float* __restrict__ Sael, const float* __restrict__ bias,
    float* __restrict__ out) {
    int n = blockIdx.x * 4 + (threadIdx.x >> 6);
    if (n >= NN) return;
    int lane = threadIdx.x & 63;
    int h = lane >> 4;            // head
    int c4 = lane & 15;           // float4 index within head
    int colq = h * 16 + c4;       // float4 column in 256-wide row
    const float4* hp4 = (const float4*)hproj;
    float ax = 0.f, ay = 0.f, az = 0.f, aw = 0.f;
    float den = 0.f;
    int b = eoff[n], e_end = eoff[n + 1];
    int idx = b;
    for (; idx + 4 <= e_end; idx += 4) {
        int s0 = src_sorted[idx], s1 = src_sorted[idx + 1];
        int s2 = src_sorted[idx + 2], s3 = src_sorted[idx + 3];
        float w0 = sc_sorted[(size_t)(idx) * 4 + h];
        float w1 = sc_sorted[(size_t)(idx + 1) * 4 + h];
        float w2 = sc_sorted[(size_t)(idx + 2) * 4 + h];
        float w3 = sc_sorted[(size_t)(idx + 3) * 4 + h];
        float4 v0 = hp4[(size_t)s0 * 64 + colq];
        float4 v1 = hp4[(size_t)s1 * 64 + colq];
        float4 v2 = hp4[(size_t)s2 * 64 + colq];
        float4 v3 = hp4[(size_t)s3 * 64 + colq];
        ax += w0 * v0.x + w1 * v1.x + w2 * v2.x + w3 * v3.x;
        ay += w0 * v0.y + w1 * v1.y + w2 * v2.y + w3 * v3.y;
        az += w0 * v0.z + w1 * v1.z + w2 * v2.z + w3 * v3.z;
        aw += w0 * v0.w + w1 * v1.w + w2 * v2.w + w3 * v3.w;
        den += (w0 + w1) + (w2 + w3);
    }
    for (; idx < e_end; idx++) {
        int s0 = src_sorted[idx];
        float w0 = sc_sorted[(size_t)idx * 4 + h];
        float4 v0 = hp4[(size_t)s0 * 64 + colq];
        ax += w0 * v0.x; ay += w0 * v0.y; az += w0 * v0.z; aw += w0 * v0.w;
        den += w0;
    }
    // self loop
    float xs = leakyf(as_[n * 4 + h] + ad_[n * 4 + h] + Sael[h]);
    float ex = expf(xs);
    float4 vs = hp4[(size_t)n * 64 + colq];
    ax += ex * vs.x; ay += ex * vs.y; az += ex * vs.z; aw += ex * vs.w;
    den += ex;
    float inv = 1.f / den;
    ax *= inv; ay *= inv; az *= inv; aw *= inv;
    // head-mean: sum lanes {l, l^16, l^32, l^48}
#pragma unroll
    for (int mask = 16; mask <= 32; mask <<= 1) {
        ax += __shfl_xor(ax, mask, 64);
        ay += __shfl_xor(ay, mask, 64);
        az += __shfl_xor(az, mask, 64);
        aw += __shfl_xor(aw, mask, 64);
    }
    if (h == 0) {
        float4 bv = ((const float4*)bias)[c4];
        float4 o;
        o.x = eluf(0.25f * ax + bv.x);
        o.y = eluf(0.25f * ay + bv.y);
        o.z = eluf(0.25f * az + bv.z);
        o.w = eluf(0.25f * aw + bv.w);
        ((float4*)out)[(size_t)n * 16 + c4] = o;
    }
}

// ---- SAGE mean aggregation: 16 lanes per node, float4 ----
__global__ __launch_bounds__(256) void sage_agg2_kernel(
    const float* __restrict__ h2, const int* __restrict__ eoff,
    const int* __restrict__ src_sorted, float* __restrict__ aggout) {
    int n = blockIdx.x * 16 + (threadIdx.x >> 4);
    if (n >= NN) return;
    int l = threadIdx.x & 15;
    const float4* h24 = (const float4*)h2;
    float ax = 0.f, ay = 0.f, az = 0.f, aw = 0.f;
    int b = eoff[n], e_end = eoff[n + 1];
    int idx = b;
    for (; idx + 4 <= e_end; idx += 4) {
        int s0 = src_sorted[idx], s1 = src_sorted[idx + 1];
        int s2 = src_sorted[idx + 2], s3 = src_sorted[idx + 3];
        float4 v0 = h24[(size_t)s0 * 16 + l];
        float4 v1 = h24[(size_t)s1 * 16 + l];
        float4 v2 = h24[(size_t)s2 * 16 + l];
        float4 v3 = h24[(size_t)s3 * 16 + l];
        ax += (v0.x + v1.x) + (v2.x + v3.x);
        ay += (v0.y + v1.y) + (v2.y + v3.y);
        az += (v0.z + v1.z) + (v2.z + v3.z);
        aw += (v0.w + v1.w) + (v2.w + v3.w);
    }
    for (; idx < e_end; idx++) {
        float4 v0 = h24[(size_t)src_sorted[idx] * 16 + l];
        ax += v0.x; ay += v0.y; az += v0.z; aw += v0.w;
    }
    float dg = (float)(e_end - b);
    if (dg < 1.f) dg = 1.f;
    float inv = 1.f / dg;
    float4 o = {ax * inv, ay * inv, az * inv, aw * inv};
    ((float4*)aggout)[(size_t)n * 16 + l] = o;
}

// ---- h3 = elu(agg @ Wl + bl + h2 @ Wr) ----
__global__ void sage_kernel(const float* __restrict__ agg, const float* __restrict__ h2,
                            const float* __restrict__ Wl, const float* __restrict__ bl,
                            const float* __restrict__ Wr, float* __restrict__ h3) {
    __shared__ float Aa[64][64];
    __shared__ float Ah[64][64];
    __shared__ float Bl[64][64];
    __shared__ float Br[64][64];
    int n0 = blockIdx.x * 64;
    int t = threadIdx.x;
    for (int i = t; i < 4096; i += 256) {
        int r = i >> 6, c = i & 63;
        int n = n0 + r;
        Aa[r][c] = (n < NN) ? agg[(size_t)n * HID + c] : 0.f;
        Ah[r][c] = (n < NN) ? h2[(size_t)n * HID + c] : 0.f;
        Bl[r][c] = Wl[i];
        Br[r][c] = Wr[i];
    }
    __syncthreads();
    int c = t & 63;
    for (int j = 0; j < 16; j++) {
        int r = (t >> 6) + 4 * j;
        int n = n0 + r;
        if (n >= NN) continue;
        float acc = bl[c];
        for (int k = 0; k < 64; k++) acc += Aa[r][k] * Bl[k][c] + Ah[r][k] * Br[k][c];
        h3[(size_t)n * HID + c] = eluf(acc);
    }
}

// ---- per-graph mean pool ----
__global__ void pool_kernel(const float* __restrict__ h3, const int* __restrict__ goff,
                            float* __restrict__ gmean) {
    __shared__ float red[256];
    int g = blockIdx.x, t = threadIdx.x;
    int c = t & 63, li = t >> 6;
    int b = goff[g], e = goff[g + 1];
    float sum = 0.f;
    for (int r = b + li; r < e; r += 4) sum += h3[(size_t)r * HID + c];
    red[t] = sum;
    __syncthreads();
    if (t < 64) {
        float v = red[t] + red[t + 64] + red[t + 128] + red[t + 192];
        float cntf = (float)(e - b);
        if (cntf < 1.f) cntf = 1.f;
        gmean[g * HID + t] = v / cntf;
    }
}

// ---- final MLP head -> d_out[192] ----
__global__ void mlp_kernel(const float* __restrict__ gmean, const float* __restrict__ lin1W,
                           const float* __restrict__ lin1b, const float* __restrict__ lin2W,
                           const float* __restrict__ lin2b, const float* __restrict__ telW,
                           const float* __restrict__ telb, const float* __restrict__ compW,
                           const float* __restrict__ compb, const float* __restrict__ pchW,
                           const float* __restrict__ pchb, float* __restrict__ out) {
    __shared__ float G[4096], Wb[4096], G1[4096], G2[4096];
    int t = threadIdx.x;
    for (int i = t; i < 4096; i += 256) { G[i] = gmean[i]; Wb[i] = lin1W[i]; }
    __syncthreads();
    int c = t & 63;
    for (int j = 0; j < 16; j++) {
        int r = (t >> 6) + 4 * j;
        float acc = lin1b[c];
        for (int k = 0; k < 64; k++) acc += G[r * 64 + k] * Wb[k * 64 + c];
        G1[r * 64 + c] = eluf(acc);
    }
    __syncthreads();
    for (int i = t; i < 4096; i += 256) Wb[i] = lin2W[i];
    __syncthreads();
    for (int j = 0; j < 16; j++) {
        int r = (t >> 6) + 4 * j;
        float acc = lin2b[c];
        for (int k = 0; k < 64; k++) acc += G1[r * 64 + k] * Wb[k * 64 + c];
        G2[r * 64 + c] = acc;
    }
    __syncthreads();
    if (t < 64) {
        int r = t;
        float a = telb[0], b_ = compb[0], p = pchb[0];
        for (int k = 0; k < 64; k++) {
            float v = G2[r * 64 + k];
            a += v * telW[k];
            b_ += v * compW[k];
            p += v * pchW[k];
        }
        out[r] = a;
        out[64 + r] = b_;
        out[128 + r] = p;
    }
}

extern "C" void kernel_launch(void* const* d_in, const int* in_sizes, int n_in,
                              void* d_out, int out_size, void* d_ws, size_t ws_size,
                              hipStream_t stream) {
    const float* x        = (const float*)d_in[0];
    const float* EA       = (const float*)d_in[1];
    const float* node_emb = (const float*)d_in[2];
    const float* edge_W   = (const float*)d_in[3];
    const float* edge_b   = (const float*)d_in[4];
    const float* W1       = (const float*)d_in[5];
    const float* as1      = (const float*)d_in[6];
    const float* ad1      = (const float*)d_in[7];
    const float* ae1      = (const float*)d_in[8];
    const float* leW1     = (const float*)d_in[9];
    const float* b1       = (const float*)d_in[10];
    const float* W2       = (const float*)d_in[11];
    const float* as2      = (const float*)d_in[12];
    const float* ad2      = (const float*)d_in[13];
    const float* ae2      = (const float*)d_in[14];
    const float* leW2     = (const float*)d_in[15];
    const float* b2       = (const float*)d_in[16];
    const float* sage_Wl  = (const float*)d_in[17];
    const float* sage_bl  = (const float*)d_in[18];
    const float* sage_Wr  = (const float*)d_in[19];
    const float* lin1_W   = (const float*)d_in[20];
    const float* lin1_b   = (const float*)d_in[21];
    const float* lin2_W   = (const float*)d_in[22];
    const float* lin2_b   = (const float*)d_in[23];
    const float* tel_W    = (const float*)d_in[24];
    const float* tel_b    = (const float*)d_in[25];
    const float* comp_W   = (const float*)d_in[26];
    const float* comp_b   = (const float*)d_in[27];
    const float* pch_W    = (const float*)d_in[28];
    const float* pch_b    = (const float*)d_in[29];
    const int* edge_index = (const int*)d_in[30];
    const int* batch      = (const int*)d_in[31];
    const int* node_type  = (const int*)d_in[32];
    float* outp = (float*)d_out;

    const int* srcp = edge_index;
    const int* dstp = edge_index + NE;

    float* wf = (float*)d_ws;
    constexpr size_t OFF_H0    = 0;                               // N*128 (aliased later: agg + h3)
    constexpr size_t OFF_HPROJ = OFF_H0 + (size_t)NN * 128;       // N*256
    constexpr size_t OFF_H1    = OFF_HPROJ + (size_t)NN * 256;    // N*64
    constexpr size_t OFF_H2    = OFF_H1 + (size_t)NN * 64;        // N*64
    constexpr size_t OFF_SC    = OFF_H2 + (size_t)NN * 64;        // E*4
    constexpr size_t OFF_AS    = OFF_SC + (size_t)NE * 4;         // N*4
    constexpr size_t OFF_AD    = OFF_AS + (size_t)NN * 4;         // N*4
    constexpr size_t OFF_SMALL = OFF_AD + (size_t)NN * 4;         // 4096
    constexpr size_t OFF_GMEAN = OFF_SMALL + 4096;                // 4096
    constexpr size_t F_TOTAL   = OFF_GMEAN + 4096;

    int* wi        = (int*)(wf + F_TOTAL);
    int* cnt       = wi;                        // N
    int* eoff      = wi + NN;                   // N+1
    int* pos       = eoff + (NN + 1);           // N
    int* esort     = pos + NN;                  // E
    int* src_sorted= esort + NE;                // E
    int* gcnt      = src_sorted + NE;           // 64
    int* goff      = gcnt + NG;                 // 65
    int* bsum      = goff + (NG + 1);           // 64
    int* boff      = bsum + 64;                 // 64

    float* h0    = wf + OFF_H0;
    float* hproj = wf + OFF_HPROJ;
    float* h1    = wf + OFF_H1;
    float* h2    = wf + OFF_H2;
    float* sc    = wf + OFF_SC;
    float* as_   = wf + OFF_AS;
    float* ad_   = wf + OFF_AD;
    float* S     = wf + OFF_SMALL;
    float* gmean = wf + OFF_GMEAN;
    float* aggb  = wf + OFF_H0;                      // alias (h0 dead by then)
    float* h3    = wf + OFF_H0 + (size_t)NN * 64;    // alias

    // zero accumulators
    hipMemsetAsync(S + S_MEANEA, 0, 16 * sizeof(float), stream);
    hipMemsetAsync(cnt, 0, NN * sizeof(int), stream);
    hipMemsetAsync(pos, 0, NN * sizeof(int), stream);
    hipMemsetAsync(gcnt, 0, NG * sizeof(int), stream);

    // constants prep
    edge_mean_kernel<<<(NE + 1023) / 1024, 256, 0, stream>>>(EA, S);
    prep_small_kernel<<<1, 256, 0, stream>>>(W1, as1, ad1, ae1, leW1,
                                             W2, as2, ad2, ae2, leW2,
                                             edge_W, edge_b, S);
    build_h0_kernel<<<(NN * 128 + 255) / 256, 256, 0, stream>>>(x, node_emb, node_type, h0);

    // CSR
    count_kernel<<<(NE + 255) / 256, 256, 0, stream>>>(dstp, cnt);
    {
        int nb = (NN + 1023) / 1024;  // 30
        scan_blocks_kernel<<<nb, 1024, 0, stream>>>(cnt, eoff, bsum);
        scan_tops_kernel<<<1, 64, 0, stream>>>(bsum, boff, nb);
        scan_add_kernel<<<(NN + 255) / 256, 256, 0, stream>>>(boff, eoff);
    }
    scatter_kernel<<<(NE + 255) / 256, 256, 0, stream>>>(dstp, eoff, pos, esort);
    gcount_kernel<<<(NN + 255) / 256, 256, 0, stream>>>(batch, gcnt);
    goff_kernel<<<1, 64, 0, stream>>>(gcnt, goff);

    // ----- GAT layer 1 -----
    gemm128_kernel<<<dim3((NN + 127) / 128, NPROJ / 128), 256, 0, stream>>>(h0, W1, hproj, NN, NPROJ, CIN1);
    attn_sd_kernel<128><<<(NN + 63) / 64, 256, 0, stream>>>(h0, S + S_MS1, S + S_MD1, as_, ad_);
    score2_kernel<<<(NE + 255) / 256, 256, 0, stream>>>(esort, srcp, dstp, EA, S, S_KF1, S_C1,
                                                        as_, ad_, src_sorted, sc);
    gat_agg2_kernel<<<(NN + 3) / 4, 256, 0, stream>>>(eoff, src_sorted, sc, hproj,
                                                      as_, ad_, S + S_AEL1, b1, h1);

    // ----- GAT layer 2 -----
    gemm128_kernel<<<dim3((NN + 127) / 128, NPROJ / 128), 256, 0, stream>>>(h1, W2, hproj, NN, NPROJ, HID);
    attn_sd_kernel<64><<<(NN + 63) / 64, 256, 0, stream>>>(h1, S + S_MS2, S + S_MD2, as_, ad_);
    score2_kernel<<<(NE + 255) / 256, 256, 0, stream>>>(esort, srcp, dstp, EA, S, S_KF2, S_C2,
                                                        as_, ad_, src_sorted, sc);
    gat_agg2_kernel<<<(NN + 3) / 4, 256, 0, stream>>>(eoff, src_sorted, sc, hproj,
                                                      as_, ad_, S + S_AEL2, b2, h2);

    // ----- SAGE -----
    sage_agg2_kernel<<<(NN + 15) / 16, 256, 0, stream>>>(h2, eoff, src_sorted, aggb);
    sage_kernel<<<(NN + 63) / 64, 256, 0, stream>>>(aggb, h2, sage_Wl, sage_bl, sage_Wr, h3);

    // ----- pool + MLP head -----
    pool_kernel<<<NG, 256, 0, stream>>>(h3, goff, gmean);
    mlp_kernel<<<1, 256, 0, stream>>>(gmean, lin1_W, lin1_b, lin2_W, lin2_b,
                                      tel_W, tel_b, comp_W, comp_b, pch_W, pch_b, outp);
}

// Round 3
// 773.198 us; speedup vs baseline: 1.6215x; 1.0052x over previous
//
#include <hip/hip_runtime.h>
#include <math.h>

#define NN 30000          // nodes
#define NE 480000         // edges
#define FEA 16            // edge feature dim
#define HID 64
#define NHEAD 4
#define NPROJ 256         // NHEAD*HID
#define CIN1 128          // F + HID
#define NG 64             // graphs
#define LEAKK 0.2f

// ---- small-constant region layout (float offsets) ----
#define S_MEANEA 0    // 16
#define S_KF1    16   // 64  (K1 [16,4])
#define S_C1     80   // 4
#define S_AEL1   84   // 4
#define S_KF2    88   // 64
#define S_C2     152  // 4
#define S_AEL2   156  // 4
#define S_MS1    160  // 512 (Ms1 [128,4])
#define S_MD1    672  // 512
#define S_MS2    1184 // 256 (Ms2 [64,4])
#define S_MD2    1440 // 256

__device__ __forceinline__ float eluf(float v) { return v > 0.f ? v : expm1f(v); }
__device__ __forceinline__ float leakyf(float v) { return v >= 0.f ? v : LEAKK * v; }

// ---- mean of edge_attr over rows: accumulate sums into S[S_MEANEA..] ----
__global__ void edge_mean_kernel(const float* __restrict__ EA, float* __restrict__ S) {
    __shared__ float red[256];
    int t = threadIdx.x;
    int col = t & 15;
    int rbase = blockIdx.x * 1024 + (t >> 4);
    float sum = 0.f;
    for (int i = 0; i < 64; i++) {
        int r = rbase + i * 16;
        if (r < NE) sum += EA[(size_t)r * FEA + col];
    }
    red[t] = sum;
    __syncthreads();
    if (t < 16) {
        float v = 0.f;
        for (int j = 0; j < 16; j++) v += red[t + j * 16];
        atomicAdd(&S[S_MEANEA + t], v);
    }
}

// ---- fold attention weights into small matrices; also build B128=[Wl;Wr] ----
__global__ void prep_small_kernel(
    const float* __restrict__ W1, const float* __restrict__ as1, const float* __restrict__ ad1,
    const float* __restrict__ ae1, const float* __restrict__ leW1,
    const float* __restrict__ W2, const float* __restrict__ as2, const float* __restrict__ ad2,
    const float* __restrict__ ae2, const float* __restrict__ leW2,
    const float* __restrict__ edge_W, const float* __restrict__ edge_b,
    const float* __restrict__ Wl, const float* __restrict__ Wr,
    float* __restrict__ S, float* __restrict__ B128) {
    __shared__ float M1[256], M2[256], meh[64];
    int t = threadIdx.x;
    if (t < 16) S[S_MEANEA + t] *= (1.0f / (float)NE);
    __syncthreads();
    {
        int k = t >> 2, h = t & 3;
        float m1 = 0.f, m2 = 0.f;
        for (int c = 0; c < 64; c++) {
            m1 += leW1[k * 256 + h * 64 + c] * ae1[h * 64 + c];
            m2 += leW2[k * 256 + h * 64 + c] * ae2[h * 64 + c];
        }
        M1[t] = m1; M2[t] = m2;
    }
    if (t < 64) {
        float v = edge_b[t];
        for (int f = 0; f < FEA; f++) v += S[S_MEANEA + f] * edge_W[f * 64 + t];
        meh[t] = v;
    }
    __syncthreads();
    if (t < 64) {
        int f = t >> 2, h = t & 3;
        float k1 = 0.f, k2 = 0.f;
        for (int k = 0; k < 64; k++) {
            k1 += edge_W[f * 64 + k] * M1[k * 4 + h];
            k2 += edge_W[f * 64 + k] * M2[k * 4 + h];
        }
        S[S_KF1 + t] = k1; S[S_KF2 + t] = k2;
    } else if (t < 68) {
        int h = t - 64;
        float c1 = 0.f, c2 = 0.f, a1 = 0.f, a2 = 0.f;
        for (int k = 0; k < 64; k++) {
            c1 += edge_b[k] * M1[k * 4 + h];
            c2 += edge_b[k] * M2[k * 4 + h];
            a1 += meh[k] * M1[k * 4 + h];
            a2 += meh[k] * M2[k * 4 + h];
        }
        S[S_C1 + h] = c1; S[S_C2 + h] = c2;
        S[S_AEL1 + h] = a1; S[S_AEL2 + h] = a2;
    }
    for (int i = t; i < 512; i += 256) {
        int k = i >> 2, h = i & 3;
        float s = 0.f, d = 0.f;
        for (int c = 0; c < 64; c++) {
            float w = W1[k * 256 + h * 64 + c];
            s += w * as1[h * 64 + c];
            d += w * ad1[h * 64 + c];
        }
        S[S_MS1 + i] = s; S[S_MD1 + i] = d;
    }
    for (int i = t; i < 256; i += 256) {
        int k = i >> 2, h = i & 3;
        float s = 0.f, d = 0.f;
        for (int c = 0; c < 64; c++) {
            float w = W2[k * 256 + h * 64 + c];
            s += w * as2[h * 64 + c];
            d += w * ad2[h * 64 + c];
        }
        S[S_MS2 + i] = s; S[S_MD2 + i] = d;
    }
    // B128 = [Wl; Wr]  (128x64)
    for (int i = t; i < 8192; i += 256) {
        int k = i >> 6, c = i & 63;
        B128[i] = (k < 64) ? Wl[k * 64 + c] : Wr[(k - 64) * 64 + c];
    }
}

// ---- h0 = concat(x, node_emb[node_type]) ----
__global__ void build_h0_kernel(const float* __restrict__ x, const float* __restrict__ node_emb,
                                const int* __restrict__ node_type, float* __restrict__ h0) {
    size_t i = (size_t)blockIdx.x * 256 + threadIdx.x;
    if (i >= (size_t)NN * 128) return;
    int n = (int)(i >> 7);
    int k = (int)(i & 127);
    h0[i] = (k < 64) ? x[(size_t)n * 64 + k] : node_emb[node_type[n] * 64 + (k - 64)];
}

// ---- CSR build ----
__global__ void count_kernel(const int* __restrict__ dst, int* __restrict__ cnt) {
    int e = blockIdx.x * 256 + threadIdx.x;
    if (e < NE) atomicAdd(&cnt[dst[e]], 1);
}

__global__ void scan_blocks_kernel(const int* __restrict__ cnt, int* __restrict__ eoff,
                                   int* __restrict__ bsum) {
    __shared__ int wsum[16];
    int t = threadIdx.x;
    int i = blockIdx.x * 1024 + t;
    int v = (i < NN) ? cnt[i] : 0;
    int lane = t & 63;
    int incl = v;
#pragma unroll
    for (int ofs = 1; ofs < 64; ofs <<= 1) {
        int u = __shfl_up(incl, ofs, 64);
        if (lane >= ofs) incl += u;
    }
    int wid = t >> 6;
    if (lane == 63) wsum[wid] = incl;
    __syncthreads();
    if (t < 16) {
        int s = wsum[t];
#pragma unroll
        for (int ofs = 1; ofs < 16; ofs <<= 1) {
            int u = __shfl_up(s, ofs, 64);
            if (t >= ofs) s += u;
        }
        wsum[t] = s;
    }
    __syncthreads();
    int excl = incl - v + (wid > 0 ? wsum[wid - 1] : 0);
    if (i < NN) eoff[i] = excl;
    if (t == 1023) bsum[blockIdx.x] = excl + v;
}

__global__ void scan_tops_kernel(const int* __restrict__ bsum, int* __restrict__ boff, int nb) {
    int t = threadIdx.x; // 64
    int v = (t < nb) ? bsum[t] : 0;
    int incl = v;
#pragma unroll
    for (int ofs = 1; ofs < 64; ofs <<= 1) {
        int u = __shfl_up(incl, ofs, 64);
        if (t >= ofs) incl += u;
    }
    boff[t] = incl - v;
}

__global__ void scan_add_kernel(const int* __restrict__ boff, int* __restrict__ eoff) {
    int i = blockIdx.x * 256 + threadIdx.x;
    if (i < NN) eoff[i] += boff[i >> 10];
    if (i == 0) eoff[NN] = NE;
}

__global__ void scatter_kernel(const int* __restrict__ dst, const int* __restrict__ eoff,
                               int* __restrict__ pos, int* __restrict__ esort) {
    int e = blockIdx.x * 256 + threadIdx.x;
    if (e >= NE) return;
    int d = dst[e];
    int p = atomicAdd(&pos[d], 1);
    esort[eoff[d] + p] = e;
}

// ---- goff via binary search over sorted batch (no atomics) ----
__global__ void goff_bs_kernel(const int* __restrict__ batch, int* __restrict__ goff) {
    int g = threadIdx.x;
    if (g > NG) return;
    int lo = 0, hi = NN;
    while (lo < hi) {
        int mid = (lo + hi) >> 1;
        if (batch[mid] < g) lo = mid + 1; else hi = mid;
    }
    goff[g] = lo;
}

// ---- fp32 GEMM 128x128 tile + fused a_s/a_d epilogue on blockIdx.y==0 ----
__global__ __launch_bounds__(256) void gemm_attn_kernel(
    const float* __restrict__ A, const float* __restrict__ B, float* __restrict__ C,
    int M, int Nc, int K, const float* __restrict__ S, int ms_off, int md_off,
    float* __restrict__ as_, float* __restrict__ ad_) {
    __shared__ float As[32 * 132];
    __shared__ float Bs[32 * 132];
    __shared__ float ms[128], md[128];
    int t = threadIdx.x;
    int tx = t & 15, ty = t >> 4;
    int m_base = blockIdx.x * 128, n_base = blockIdx.y * 128;
    bool doA = (blockIdx.y == 0);
    int ar = t >> 1, hb = (t & 1) * 2;
    float s0 = 0.f, s1 = 0.f, d0 = 0.f, d1 = 0.f;
    float acc[8][8] = {};
    for (int k0 = 0; k0 < K; k0 += 32) {
#pragma unroll
        for (int i = 0; i < 4; i++) {
            int lin = t + i * 256;
            int row = lin >> 3;
            int kq = (lin & 7) * 4;
            int m = m_base + row;
            float4 f = {0.f, 0.f, 0.f, 0.f};
            if (m < M) f = *(const float4*)(A + (size_t)m * K + k0 + kq);
            As[(kq + 0) * 132 + row] = f.x;
            As[(kq + 1) * 132 + row] = f.y;
            As[(kq + 2) * 132 + row] = f.z;
            As[(kq + 3) * 132 + row] = f.w;
        }
#pragma unroll
        for (int i = 0; i < 4; i++) {
            int lin = t + i * 256;
            int kr = lin >> 5;
            int nc = (lin & 31) * 4;
            float4 f = *(const float4*)(B + (size_t)(k0 + kr) * Nc + n_base + nc);
            *(float4*)(&Bs[kr * 132 + nc]) = f;
        }
        if (t < 128) ms[t] = S[ms_off + k0 * 4 + t];
        else md[t - 128] = S[md_off + k0 * 4 + (t - 128)];
        __syncthreads();
#pragma unroll
        for (int k = 0; k < 32; k++) {
            float a[8], b[8];
            *(float4*)(a)     = *(const float4*)(&As[k * 132 + ty * 8]);
            *(float4*)(a + 4) = *(const float4*)(&As[k * 132 + ty * 8 + 4]);
            *(float4*)(b)     = *(const float4*)(&Bs[k * 132 + tx * 8]);
            *(float4*)(b + 4) = *(const float4*)(&Bs[k * 132 + tx * 8 + 4]);
#pragma unroll
            for (int i = 0; i < 8; i++)
#pragma unroll
                for (int j = 0; j < 8; j++) acc[i][j] += a[i] * b[j];
        }
        if (doA) {
#pragma unroll
            for (int k = 0; k < 32; k++) {
                float xv = As[k * 132 + ar];
                s0 += xv * ms[k * 4 + hb];
                s1 += xv * ms[k * 4 + hb + 1];
                d0 += xv * md[k * 4 + hb];
                d1 += xv * md[k * 4 + hb + 1];
            }
        }
        __syncthreads();
    }
    for (int i = 0; i < 8; i++) {
        int m = m_base + ty * 8 + i;
        if (m >= M) continue;
        float4 o0 = {acc[i][0], acc[i][1], acc[i][2], acc[i][3]};
        float4 o1 = {acc[i][4], acc[i][5], acc[i][6], acc[i][7]};
        *(float4*)(C + (size_t)m * Nc + n_base + tx * 8) = o0;
        *(float4*)(C + (size_t)m * Nc + n_base + tx * 8 + 4) = o1;
    }
    if (doA) {
        int m = m_base + ar;
        if (m < M) {
            as_[m * 4 + hb] = s0; as_[m * 4 + hb + 1] = s1;
            ad_[m * 4 + hb] = d0; ad_[m * 4 + hb + 1] = d1;
        }
    }
}

// ---- edge prep: sc1 (layer-1 scores), ae2s, src_sorted, dst_sorted ----
__global__ void edge_prep_kernel(const int* __restrict__ esort, const int* __restrict__ src,
                                 const int* __restrict__ dst, const float* __restrict__ EA,
                                 const float* __restrict__ S,
                                 const float* __restrict__ as_, const float* __restrict__ ad_,
                                 int* __restrict__ src_sorted, int* __restrict__ dst_sorted,
                                 float* __restrict__ sc1, float* __restrict__ ae2s) {
    int idx = blockIdx.x * 256 + threadIdx.x;
    if (idx >= NE) return;
    int e = esort[idx];
    int s = src[e], d = dst[e];
    src_sorted[idx] = s;
    dst_sorted[idx] = d;
    float a1[4], a2[4];
#pragma unroll
    for (int h = 0; h < 4; h++) { a1[h] = S[S_C1 + h]; a2[h] = S[S_C2 + h]; }
    const float4* EA4 = (const float4*)(EA + (size_t)e * FEA);
#pragma unroll
    for (int q = 0; q < 4; q++) {
        float4 v = EA4[q];
        float vv[4] = {v.x, v.y, v.z, v.w};
#pragma unroll
        for (int j = 0; j < 4; j++) {
            int f = q * 4 + j;
#pragma unroll
            for (int h = 0; h < 4; h++) {
                a1[h] += vv[j] * S[S_KF1 + f * 4 + h];
                a2[h] += vv[j] * S[S_KF2 + f * 4 + h];
            }
        }
    }
    ((float4*)ae2s)[idx] = make_float4(a2[0], a2[1], a2[2], a2[3]);
    float4 asv = ((const float4*)as_)[s];
    float4 adv = ((const float4*)ad_)[d];
    float4 r;
    r.x = expf(leakyf(asv.x + adv.x + a1[0]));
    r.y = expf(leakyf(asv.y + adv.y + a1[1]));
    r.z = expf(leakyf(asv.z + adv.z + a1[2]));
    r.w = expf(leakyf(asv.w + adv.w + a1[3]));
    ((float4*)sc1)[idx] = r;
}

// ---- layer-2 scores: all reads coalesced except two 16B gathers ----
__global__ void score_l2_kernel(const int* __restrict__ src_sorted,
                                const int* __restrict__ dst_sorted,
                                const float* __restrict__ ae2s,
                                const float* __restrict__ as_, const float* __restrict__ ad_,
                                float* __restrict__ sc) {
    int idx = blockIdx.x * 256 + threadIdx.x;
    if (idx >= NE) return;
    int s = src_sorted[idx], d = dst_sorted[idx];
    float4 ae = ((const float4*)ae2s)[idx];
    float4 asv = ((const float4*)as_)[s];
    float4 adv = ((const float4*)ad_)[d];
    float4 r;
    r.x = expf(leakyf(asv.x + adv.x + ae.x));
    r.y = expf(leakyf(asv.y + adv.y + ae.y));
    r.z = expf(leakyf(asv.z + adv.z + ae.z));
    r.w = expf(leakyf(asv.w + adv.w + ae.w));
    ((float4*)sc)[idx] = r;
}

// ---- GAT aggregation: wave per node, 8-wide software pipeline ----
__global__ __launch_bounds__(256) void gat_agg3_kernel(
    const int* __restrict__ eoff, const int* __restrict__ src_sorted,
    const float* __restrict__ sc_sorted, const float* __restrict__ hproj,
    const float* __restrict__ as_, const float* __restrict__ ad_,
    const float* __restrict__ Sael, const float* __restrict__ bias,
    float* __restrict__ out) {
    int n = blockIdx.x * 4 + (threadIdx.x >> 6);
    if (n >= NN) return;
    int lane = threadIdx.x & 63;
    int h = lane >> 4;
    int c4 = lane & 15;
    int colq = h * 16 + c4;
    const float4* hp4 = (const float4*)hproj;
    float ax = 0.f, ay = 0.f, az = 0.f, aw = 0.f;
    float den = 0.f;
    int b = eoff[n], e_end = eoff[n + 1];
    int idx = b;
    int stop = b + ((e_end - b) & ~7);
    if (idx < stop) {
        int sreg[8]; float wreg[8];
#pragma unroll
        for (int u = 0; u < 8; u++) {
            sreg[u] = src_sorted[idx + u];
            wreg[u] = sc_sorted[(size_t)(idx + u) * 4 + h];
        }
        idx += 8;
        while (true) {
            int sn[8]; float wn[8];
            bool more = idx < stop;
            if (more) {
#pragma unroll
                for (int u = 0; u < 8; u++) {
                    sn[u] = src_sorted[idx + u];
                    wn[u] = sc_sorted[(size_t)(idx + u) * 4 + h];
                }
            }
#pragma unroll
            for (int u = 0; u < 8; u++) {
                float4 v = hp4[(size_t)sreg[u] * 64 + colq];
                ax += wreg[u] * v.x; ay += wreg[u] * v.y;
                az += wreg[u] * v.z; aw += wreg[u] * v.w;
                den += wreg[u];
            }
            if (!more) break;
#pragma unroll
            for (int u = 0; u < 8; u++) { sreg[u] = sn[u]; wreg[u] = wn[u]; }
            idx += 8;
        }
    }
    for (; idx + 4 <= e_end; idx += 4) {
        int s0 = src_sorted[idx], s1 = src_sorted[idx + 1];
        int s2 = src_sorted[idx + 2], s3 = src_sorted[idx + 3];
        float w0 = sc_sorted[(size_t)(idx) * 4 + h];
        float w1 = sc_sorted[(size_t)(idx + 1) * 4 + h];
        float w2 = sc_sorted[(size_t)(idx + 2) * 4 + h];
        float w3 = sc_sorted[(size_t)(idx + 3) * 4 + h];
        float4 v0 = hp4[(size_t)s0 * 64 + colq];
        float4 v1 = hp4[(size_t)s1 * 64 + colq];
        float4 v2 = hp4[(size_t)s2 * 64 + colq];
        float4 v3 = hp4[(size_t)s3 * 64 + colq];
        ax += w0 * v0.x + w1 * v1.x + w2 * v2.x + w3 * v3.x;
        ay += w0 * v0.y + w1 * v1.y + w2 * v2.y + w3 * v3.y;
        az += w0 * v0.z + w1 * v1.z + w2 * v2.z + w3 * v3.z;
        aw += w0 * v0.w + w1 * v1.w + w2 * v2.w + w3 * v3.w;
        den += (w0 + w1) + (w2 + w3);
    }
    for (; idx < e_end; idx++) {
        int s0 = src_sorted[idx];
        float w0 = sc_sorted[(size_t)idx * 4 + h];
        float4 v0 = hp4[(size_t)s0 * 64 + colq];
        ax += w0 * v0.x; ay += w0 * v0.y; az += w0 * v0.z; aw += w0 * v0.w;
        den += w0;
    }
    // self loop
    float xs = leakyf(as_[n * 4 + h] + ad_[n * 4 + h] + Sael[h]);
    float ex = expf(xs);
    float4 vs = hp4[(size_t)n * 64 + colq];
    ax += ex * vs.x; ay += ex * vs.y; az += ex * vs.z; aw += ex * vs.w;
    den += ex;
    float inv = 1.f / den;
    ax *= inv; ay *= inv; az *= inv; aw *= inv;
#pragma unroll
    for (int mask = 16; mask <= 32; mask <<= 1) {
        ax += __shfl_xor(ax, mask, 64);
        ay += __shfl_xor(ay, mask, 64);
        az += __shfl_xor(az, mask, 64);
        aw += __shfl_xor(aw, mask, 64);
    }
    if (h == 0) {
        float4 bv = ((const float4*)bias)[c4];
        float4 o;
        o.x = eluf(0.25f * ax + bv.x);
        o.y = eluf(0.25f * ay + bv.y);
        o.z = eluf(0.25f * az + bv.z);
        o.w = eluf(0.25f * aw + bv.w);
        ((float4*)out)[(size_t)n * 16 + c4] = o;
    }
}

// ---- SAGE mean aggregation into AB[:,0:64]; copy h2 into AB[:,64:128] ----
__global__ __launch_bounds__(256) void sage_agg3_kernel(
    const float* __restrict__ h2, const int* __restrict__ eoff,
    const int* __restrict__ src_sorted, float* __restrict__ AB) {
    int n = blockIdx.x * 16 + (threadIdx.x >> 4);
    if (n >= NN) return;
    int l = threadIdx.x & 15;
    const float4* h24 = (const float4*)h2;
    float4* AB4 = (float4*)AB;
    float ax = 0.f, ay = 0.f, az = 0.f, aw = 0.f;
    int b = eoff[n], e_end = eoff[n + 1];
    int idx = b;
    int stop = b + ((e_end - b) & ~7);
    if (idx < stop) {
        int sreg[8];
#pragma unroll
        for (int u = 0; u < 8; u++) sreg[u] = src_sorted[idx + u];
        idx += 8;
        while (true) {
            int sn[8];
            bool more = idx < stop;
            if (more) {
#pragma unroll
                for (int u = 0; u < 8; u++) sn[u] = src_sorted[idx + u];
            }
#pragma unroll
            for (int u = 0; u < 8; u++) {
                float4 v = h24[(size_t)sreg[u] * 16 + l];
                ax += v.x; ay += v.y; az += v.z; aw += v.w;
            }
            if (!more) break;
#pragma unroll
            for (int u = 0; u < 8; u++) sreg[u] = sn[u];
            idx += 8;
        }
    }
    for (; idx < e_end; idx++) {
        float4 v0 = h24[(size_t)src_sorted[idx] * 16 + l];
        ax += v0.x; ay += v0.y; az += v0.z; aw += v0.w;
    }
    float dg = (float)(e_end - b);
    if (dg < 1.f) dg = 1.f;
    float inv = 1.f / dg;
    AB4[(size_t)n * 32 + l] = make_float4(ax * inv, ay * inv, az * inv, aw * inv);
    AB4[(size_t)n * 32 + 16 + l] = h24[(size_t)n * 16 + l];
}

// ---- h3 = elu(AB @ B128 + bl): 128-row tile, K=128, Nc=64 ----
__global__ __launch_bounds__(256) void sage_mm_kernel(const float* __restrict__ AB,
                                                      const float* __restrict__ B128,
                                                      const float* __restrict__ bl,
                                                      float* __restrict__ h3) {
    __shared__ float As[32 * 132];
    __shared__ float Bs[32 * 68];
    int t = threadIdx.x;
    int tx = t & 15, ty = t >> 4;
    int m_base = blockIdx.x * 128;
    float acc[8][4] = {};
    for (int k0 = 0; k0 < 128; k0 += 32) {
#pragma unroll
        for (int i = 0; i < 4; i++) {
            int lin = t + i * 256;
            int row = lin >> 3;
            int kq = (lin & 7) * 4;
            int m = m_base + row;
            float4 f = {0.f, 0.f, 0.f, 0.f};
            if (m < NN) f = *(const float4*)(AB + (size_t)m * 128 + k0 + kq);
            As[(kq + 0) * 132 + row] = f.x;
            As[(kq + 1) * 132 + row] = f.y;
            As[(kq + 2) * 132 + row] = f.z;
            As[(kq + 3) * 132 + row] = f.w;
        }
#pragma unroll
        for (int i = 0; i < 2; i++) {
            int lin = t + i * 256;
            int kr = lin >> 4;
            int nc = (lin & 15) * 4;
            float4 f = *(const float4*)(B128 + (size_t)(k0 + kr) * 64 + nc);
            *(float4*)(&Bs[kr * 68 + nc]) = f;
        }
        __syncthreads();
#pragma unroll
        for (int k = 0; k < 32; k++) {
            float a[8], b[4];
            *(float4*)(a)     = *(const float4*)(&As[k * 132 + ty * 8]);
            *(float4*)(a + 4) = *(const float4*)(&As[k * 132 + ty * 8 + 4]);
            *(float4*)(b)     = *(const float4*)(&Bs[k * 68 + tx * 4]);
#pragma unroll
            for (int i = 0; i < 8; i++)
#pragma unroll
                for (int j = 0; j < 4; j++) acc[i][j] += a[i] * b[j];
        }
        __syncthreads();
    }
    float4 bv = ((const float4*)bl)[tx];
    for (int i = 0; i < 8; i++) {
        int m = m_base + ty * 8 + i;
        if (m >= NN) continue;
        float4 o;
        o.x = eluf(acc[i][0] + bv.x);
        o.y = eluf(acc[i][1] + bv.y);
        o.z = eluf(acc[i][2] + bv.z);
        o.w = eluf(acc[i][3] + bv.w);
        *(float4*)(h3 + (size_t)m * 64 + tx * 4) = o;
    }
}

// ---- per-graph mean pool ----
__global__ void pool_kernel(const float* __restrict__ h3, const int* __restrict__ goff,
                            float* __restrict__ gmean) {
    __shared__ float red[256];
    int g = blockIdx.x, t = threadIdx.x;
    int c = t & 63, li = t >> 6;
    int b = goff[g], e = goff[g + 1];
    float sum = 0.f;
    for (int r = b + li; r < e; r += 4) sum += h3[(size_t)r * HID + c];
    red[t] = sum;
    __syncthreads();
    if (t < 64) {
        float v = red[t] + red[t + 64] + red[t + 128] + red[t + 192];
        float cntf = (float)(e - b);
        if (cntf < 1.f) cntf = 1.f;
        gmean[g * HID + t] = v / cntf;
    }
}

// ---- final MLP head -> d_out[192] ----
__global__ void mlp_kernel(const float* __restrict__ gmean, const float* __restrict__ lin1W,
                           const float* __restrict__ lin1b, const float* __restrict__ lin2W,
                           const float* __restrict__ lin2b, const float* __restrict__ telW,
                           const float* __restrict__ telb, const float* __restrict__ compW,
                           const float* __restrict__ compb, const float* __restrict__ pchW,
                           const float* __restrict__ pchb, float* __restrict__ out) {
    __shared__ float G[4096], Wb[4096], G1[4096], G2[4096];
    int t = threadIdx.x;
    for (int i = t; i < 4096; i += 256) { G[i] = gmean[i]; Wb[i] = lin1W[i]; }
    __syncthreads();
    int c = t & 63;
    for (int j = 0; j < 16; j++) {
        int r = (t >> 6) + 4 * j;
        float acc = lin1b[c];
        for (int k = 0; k < 64; k++) acc += G[r * 64 + k] * Wb[k * 64 + c];
        G1[r * 64 + c] = eluf(acc);
    }
    __syncthreads();
    for (int i = t; i < 4096; i += 256) Wb[i] = lin2W[i];
    __syncthreads();
    for (int j = 0; j < 16; j++) {
        int r = (t >> 6) + 4 * j;
        float acc = lin2b[c];
        for (int k = 0; k < 64; k++) acc += G1[r * 64 + k] * Wb[k * 64 + c];
        G2[r * 64 + c] = acc;
    }
    __syncthreads();
    if (t < 64) {
        int r = t;
        float a = telb[0], b_ = compb[0], p = pchb[0];
        for (int k = 0; k < 64; k++) {
            float v = G2[r * 64 + k];
            a += v * telW[k];
            b_ += v * compW[k];
            p += v * pchW[k];
        }
        out[r] = a;
        out[64 + r] = b_;
        out[128 + r] = p;
    }
}

extern "C" void kernel_launch(void* const* d_in, const int* in_sizes, int n_in,
                              void* d_out, int out_size, void* d_ws, size_t ws_size,
                              hipStream_t stream) {
    const float* x        = (const float*)d_in[0];
    const float* EA       = (const float*)d_in[1];
    const float* node_emb = (const float*)d_in[2];
    const float* edge_W   = (const float*)d_in[3];
    const float* edge_b   = (const float*)d_in[4];
    const float* W1       = (const float*)d_in[5];
    const float* as1      = (const float*)d_in[6];
    const float* ad1      = (const float*)d_in[7];
    const float* ae1      = (const float*)d_in[8];
    const float* leW1     = (const float*)d_in[9];
    const float* b1       = (const float*)d_in[10];
    const float* W2       = (const float*)d_in[11];
    const float* as2      = (const float*)d_in[12];
    const float* ad2      = (const float*)d_in[13];
    const float* ae2      = (const float*)d_in[14];
    const float* leW2     = (const float*)d_in[15];
    const float* b2       = (const float*)d_in[16];
    const float* sage_Wl  = (const float*)d_in[17];
    const float* sage_bl  = (const float*)d_in[18];
    const float* sage_Wr  = (const float*)d_in[19];
    const float* lin1_W   = (const float*)d_in[20];
    const float* lin1_b   = (const float*)d_in[21];
    const float* lin2_W   = (const float*)d_in[22];
    const float* lin2_b   = (const float*)d_in[23];
    const float* tel_W    = (const float*)d_in[24];
    const float* tel_b    = (const float*)d_in[25];
    const float* comp_W   = (const float*)d_in[26];
    const float* comp_b   = (const float*)d_in[27];
    const float* pch_W    = (const float*)d_in[28];
    const float* pch_b    = (const float*)d_in[29];
    const int* edge_index = (const int*)d_in[30];
    const int* batch      = (const int*)d_in[31];
    const int* node_type  = (const int*)d_in[32];
    float* outp = (float*)d_out;

    const int* srcp = edge_index;
    const int* dstp = edge_index + NE;

    float* wf = (float*)d_ws;
    constexpr size_t OFF_H0    = 0;                               // N*128 (h0; h3 aliases first N*64 later)
    constexpr size_t OFF_HPROJ = OFF_H0 + (size_t)NN * 128;       // N*256 (AB aliases first N*128 later)
    constexpr size_t OFF_H1    = OFF_HPROJ + (size_t)NN * 256;    // N*64
    constexpr size_t OFF_H2    = OFF_H1 + (size_t)NN * 64;        // N*64
    constexpr size_t OFF_SC    = OFF_H2 + (size_t)NN * 64;        // E*4
    constexpr size_t OFF_AE2   = OFF_SC + (size_t)NE * 4;         // E*4
    constexpr size_t OFF_AS    = OFF_AE2 + (size_t)NE * 4;        // N*4
    constexpr size_t OFF_AD    = OFF_AS + (size_t)NN * 4;         // N*4
    constexpr size_t OFF_SMALL = OFF_AD + (size_t)NN * 4;         // 4096
    constexpr size_t OFF_GMEAN = OFF_SMALL + 4096;                // 4096
    constexpr size_t OFF_B128  = OFF_GMEAN + 4096;                // 8192
    constexpr size_t F_TOTAL   = OFF_B128 + 8192;

    int* wi         = (int*)(wf + F_TOTAL);
    int* cnt        = wi;                        // N
    int* pos        = wi + NN;                   // N   (adjacent to cnt: one memset)
    int* eoff       = pos + NN;                  // N+1
    int* esort      = eoff + (NN + 1);           // E
    int* src_sorted = esort + NE;                // E
    int* dst_sorted = src_sorted + NE;           // E
    int* goff       = dst_sorted + NE;           // NG+1
    int* bsum       = goff + (NG + 1);           // 64
    int* boff       = bsum + 64;                 // 64

    float* h0    = wf + OFF_H0;
    float* hproj = wf + OFF_HPROJ;
    float* h1    = wf + OFF_H1;
    float* h2    = wf + OFF_H2;
    float* sc    = wf + OFF_SC;
    float* ae2s  = wf + OFF_AE2;
    float* as_   = wf + OFF_AS;
    float* ad_   = wf + OFF_AD;
    float* S     = wf + OFF_SMALL;
    float* gmean = wf + OFF_GMEAN;
    float* B128  = wf + OFF_B128;
    float* AB    = wf + OFF_HPROJ;               // alias (hproj dead after gat_agg L2)
    float* h3    = wf + OFF_H0;                  // alias (h0 dead after gemm L1)

    hipMemsetAsync(S + S_MEANEA, 0, 16 * sizeof(float), stream);
    hipMemsetAsync(cnt, 0, 2 * NN * sizeof(int), stream);   // cnt + pos

    edge_mean_kernel<<<(NE + 1023) / 1024, 256, 0, stream>>>(EA, S);
    prep_small_kernel<<<1, 256, 0, stream>>>(W1, as1, ad1, ae1, leW1,
                                             W2, as2, ad2, ae2, leW2,
                                             edge_W, edge_b, sage_Wl, sage_Wr, S, B128);
    build_h0_kernel<<<(NN * 128 + 255) / 256, 256, 0, stream>>>(x, node_emb, node_type, h0);

    // CSR
    count_kernel<<<(NE + 255) / 256, 256, 0, stream>>>(dstp, cnt);
    {
        int nb = (NN + 1023) / 1024;  // 30
        scan_blocks_kernel<<<nb, 1024, 0, stream>>>(cnt, eoff, bsum);
        scan_tops_kernel<<<1, 64, 0, stream>>>(bsum, boff, nb);
        scan_add_kernel<<<(NN + 255) / 256, 256, 0, stream>>>(boff, eoff);
    }
    scatter_kernel<<<(NE + 255) / 256, 256, 0, stream>>>(dstp, eoff, pos, esort);
    goff_bs_kernel<<<1, 128, 0, stream>>>(batch, goff);

    // ----- GAT layer 1 -----
    gemm_attn_kernel<<<dim3((NN + 127) / 128, 2), 256, 0, stream>>>(
        h0, W1, hproj, NN, NPROJ, CIN1, S, S_MS1, S_MD1, as_, ad_);
    edge_prep_kernel<<<(NE + 255) / 256, 256, 0, stream>>>(
        esort, srcp, dstp, EA, S, as_, ad_, src_sorted, dst_sorted, sc, ae2s);
    gat_agg3_kernel<<<(NN + 3) / 4, 256, 0, stream>>>(eoff, src_sorted, sc, hproj,
                                                      as_, ad_, S + S_AEL1, b1, h1);

    // ----- GAT layer 2 -----
    gemm_attn_kernel<<<dim3((NN + 127) / 128, 2), 256, 0, stream>>>(
        h1, W2, hproj, NN, NPROJ, HID, S, S_MS2, S_MD2, as_, ad_);
    score_l2_kernel<<<(NE + 255) / 256, 256, 0, stream>>>(src_sorted, dst_sorted, ae2s,
                                                          as_, ad_, sc);
    gat_agg3_kernel<<<(NN + 3) / 4, 256, 0, stream>>>(eoff, src_sorted, sc, hproj,
                                                      as_, ad_, S + S_AEL2, b2, h2);

    // ----- SAGE -----
    sage_agg3_kernel<<<(NN + 15) / 16, 256, 0, stream>>>(h2, eoff, src_sorted, AB);
    sage_mm_kernel<<<(NN + 127) / 128, 256, 0, stream>>>(AB, B128, sage_bl, h3);

    // ----- pool + MLP head -----
    pool_kernel<<<NG, 256, 0, stream>>>(h3, goff, gmean);
    mlp_kernel<<<1, 256, 0, stream>>>(gmean, lin1_W, lin1_b, lin2_W, lin2_b,
                                      tel_W, tel_b, comp_W, comp_b, pch_W, pch_b, outp);
}

// Round 4
// 641.676 us; speedup vs baseline: 1.9539x; 1.2050x over previous
//
#include <hip/hip_runtime.h>
#include <math.h>

#define NN 30000          // nodes
#define NE 480000         // edges
#define FEA 16            // edge feature dim
#define HID 64
#define NHEAD 4
#define CIN1 128          // F + HID
#define NG 64             // graphs
#define LEAKK 0.2f

// ---- small-constant region layout (float offsets) ----
#define S_MEANEA 0    // 16
#define S_KF1    16   // 64  (K1 [16,4])
#define S_C1     80   // 4
#define S_AEL1   84   // 4
#define S_KF2    88   // 64
#define S_C2     152  // 4
#define S_AEL2   156  // 4
#define S_MS1    160  // 512 (Ms1 [128,4])
#define S_MD1    672  // 512
#define S_MS2    1184 // 256 (Ms2 [64,4])
#define S_MD2    1440 // 256

__device__ __forceinline__ float eluf(float v) { return v > 0.f ? v : expm1f(v); }
__device__ __forceinline__ float leakyf(float v) { return v >= 0.f ? v : LEAKK * v; }
__device__ __forceinline__ void fma4(float4& a, float w, const float4& x) {
    a.x += w * x.x; a.y += w * x.y; a.z += w * x.z; a.w += w * x.w;
}

// ---- mean of edge_attr over rows ----
__global__ void edge_mean_kernel(const float* __restrict__ EA, float* __restrict__ S) {
    __shared__ float red[256];
    int t = threadIdx.x;
    int col = t & 15;
    int rbase = blockIdx.x * 1024 + (t >> 4);
    float sum = 0.f;
    for (int i = 0; i < 64; i++) {
        int r = rbase + i * 16;
        if (r < NE) sum += EA[(size_t)r * FEA + col];
    }
    red[t] = sum;
    __syncthreads();
    if (t < 16) {
        float v = 0.f;
        for (int j = 0; j < 16; j++) v += red[t + j * 16];
        atomicAdd(&S[S_MEANEA + t], v);
    }
}

// ---- fold attention weights into small matrices; build Wcomb1/Wcomb2/B128 ----
__global__ void prep_small_kernel(
    const float* __restrict__ W1, const float* __restrict__ as1, const float* __restrict__ ad1,
    const float* __restrict__ ae1, const float* __restrict__ leW1,
    const float* __restrict__ W2, const float* __restrict__ as2, const float* __restrict__ ad2,
    const float* __restrict__ ae2, const float* __restrict__ leW2,
    const float* __restrict__ edge_W, const float* __restrict__ edge_b,
    const float* __restrict__ Wl, const float* __restrict__ Wr,
    float* __restrict__ S, float* __restrict__ WC1, float* __restrict__ WC2,
    float* __restrict__ B128) {
    __shared__ float M1[256], M2[256], meh[64];
    int t = threadIdx.x;
    if (t < 16) S[S_MEANEA + t] *= (1.0f / (float)NE);
    __syncthreads();
    {
        int k = t >> 2, h = t & 3;
        float m1 = 0.f, m2 = 0.f;
        for (int c = 0; c < 64; c++) {
            m1 += leW1[k * 256 + h * 64 + c] * ae1[h * 64 + c];
            m2 += leW2[k * 256 + h * 64 + c] * ae2[h * 64 + c];
        }
        M1[t] = m1; M2[t] = m2;
    }
    if (t < 64) {
        float v = edge_b[t];
        for (int f = 0; f < FEA; f++) v += S[S_MEANEA + f] * edge_W[f * 64 + t];
        meh[t] = v;
    }
    __syncthreads();
    if (t < 64) {
        int f = t >> 2, h = t & 3;
        float k1 = 0.f, k2 = 0.f;
        for (int k = 0; k < 64; k++) {
            k1 += edge_W[f * 64 + k] * M1[k * 4 + h];
            k2 += edge_W[f * 64 + k] * M2[k * 4 + h];
        }
        S[S_KF1 + t] = k1; S[S_KF2 + t] = k2;
    } else if (t < 68) {
        int h = t - 64;
        float c1 = 0.f, c2 = 0.f, a1 = 0.f, a2 = 0.f;
        for (int k = 0; k < 64; k++) {
            c1 += edge_b[k] * M1[k * 4 + h];
            c2 += edge_b[k] * M2[k * 4 + h];
            a1 += meh[k] * M1[k * 4 + h];
            a2 += meh[k] * M2[k * 4 + h];
        }
        S[S_C1 + h] = c1; S[S_C2 + h] = c2;
        S[S_AEL1 + h] = a1; S[S_AEL2 + h] = a2;
    }
    for (int i = t; i < 512; i += 256) {
        int k = i >> 2, h = i & 3;
        float s = 0.f, d = 0.f;
        for (int c = 0; c < 64; c++) {
            float w = W1[k * 256 + h * 64 + c];
            s += w * as1[h * 64 + c];
            d += w * ad1[h * 64 + c];
        }
        S[S_MS1 + i] = s; S[S_MD1 + i] = d;
    }
    for (int i = t; i < 256; i += 256) {
        int k = i >> 2, h = i & 3;
        float s = 0.f, d = 0.f;
        for (int c = 0; c < 64; c++) {
            float w = W2[k * 256 + h * 64 + c];
            s += w * as2[h * 64 + c];
            d += w * ad2[h * 64 + c];
        }
        S[S_MS2 + i] = s; S[S_MD2 + i] = d;
    }
    // WC1[(h*128+k)*64+c] = 0.25*W1[k*256+h*64+c]   (512x64)
    for (int i = t; i < 32768; i += 256) {
        int hk = i >> 6, c = i & 63;
        int h = hk >> 7, k = hk & 127;
        WC1[i] = 0.25f * W1[k * 256 + h * 64 + c];
    }
    // WC2[(h*64+k)*64+c] = 0.25*W2[k*256+h*64+c]    (256x64)
    for (int i = t; i < 16384; i += 256) {
        int hk = i >> 6, c = i & 63;
        int h = hk >> 6, k = hk & 63;
        WC2[i] = 0.25f * W2[k * 256 + h * 64 + c];
    }
    // B128 = [Wl; Wr]  (128x64)
    for (int i = t; i < 8192; i += 256) {
        int k = i >> 6, c = i & 63;
        B128[i] = (k < 64) ? Wl[k * 64 + c] : Wr[(k - 64) * 64 + c];
    }
}

// ---- h0 = concat(x, node_emb[node_type]) ----
__global__ void build_h0_kernel(const float* __restrict__ x, const float* __restrict__ node_emb,
                                const int* __restrict__ node_type, float* __restrict__ h0) {
    size_t i = (size_t)blockIdx.x * 256 + threadIdx.x;
    if (i >= (size_t)NN * 128) return;
    int n = (int)(i >> 7);
    int k = (int)(i & 127);
    h0[i] = (k < 64) ? x[(size_t)n * 64 + k] : node_emb[node_type[n] * 64 + (k - 64)];
}

// ---- CSR build ----
__global__ void count_kernel(const int* __restrict__ dst, int* __restrict__ cnt) {
    int e = blockIdx.x * 256 + threadIdx.x;
    if (e < NE) atomicAdd(&cnt[dst[e]], 1);
}

__global__ void scan_blocks_kernel(const int* __restrict__ cnt, int* __restrict__ eoff,
                                   int* __restrict__ bsum) {
    __shared__ int wsum[16];
    int t = threadIdx.x;
    int i = blockIdx.x * 1024 + t;
    int v = (i < NN) ? cnt[i] : 0;
    int lane = t & 63;
    int incl = v;
#pragma unroll
    for (int ofs = 1; ofs < 64; ofs <<= 1) {
        int u = __shfl_up(incl, ofs, 64);
        if (lane >= ofs) incl += u;
    }
    int wid = t >> 6;
    if (lane == 63) wsum[wid] = incl;
    __syncthreads();
    if (t < 16) {
        int s = wsum[t];
#pragma unroll
        for (int ofs = 1; ofs < 16; ofs <<= 1) {
            int u = __shfl_up(s, ofs, 64);
            if (t >= ofs) s += u;
        }
        wsum[t] = s;
    }
    __syncthreads();
    int excl = incl - v + (wid > 0 ? wsum[wid - 1] : 0);
    if (i < NN) eoff[i] = excl;
    if (t == 1023) bsum[blockIdx.x] = excl + v;
}

__global__ void scan_tops_kernel(const int* __restrict__ bsum, int* __restrict__ boff, int nb) {
    int t = threadIdx.x; // 64
    int v = (t < nb) ? bsum[t] : 0;
    int incl = v;
#pragma unroll
    for (int ofs = 1; ofs < 64; ofs <<= 1) {
        int u = __shfl_up(incl, ofs, 64);
        if (t >= ofs) incl += u;
    }
    boff[t] = incl - v;
}

__global__ void scan_add_kernel(const int* __restrict__ boff, int* __restrict__ eoff) {
    int i = blockIdx.x * 256 + threadIdx.x;
    if (i < NN) eoff[i] += boff[i >> 10];
    if (i == 0) eoff[NN] = NE;
}

__global__ void scatter_kernel(const int* __restrict__ dst, const int* __restrict__ eoff,
                               int* __restrict__ pos, int* __restrict__ esort) {
    int e = blockIdx.x * 256 + threadIdx.x;
    if (e >= NE) return;
    int d = dst[e];
    int p = atomicAdd(&pos[d], 1);
    esort[eoff[d] + p] = e;
}

// ---- goff via binary search over sorted batch ----
__global__ void goff_bs_kernel(const int* __restrict__ batch, int* __restrict__ goff) {
    int g = threadIdx.x;
    if (g > NG) return;
    int lo = 0, hi = NN;
    while (lo < hi) {
        int mid = (lo + hi) >> 1;
        if (batch[mid] < g) lo = mid + 1; else hi = mid;
    }
    goff[g] = lo;
}

// ---- a_s/a_d = X @ Ms / Md  ([N,4] each) ----
template <int KD>
__global__ void attn_sd_kernel(const float* __restrict__ X, const float* __restrict__ Ms,
                               const float* __restrict__ Md, float* __restrict__ as_,
                               float* __restrict__ ad_) {
    __shared__ float xt[64 * (KD + 1)];
    __shared__ float ms[KD * 4];
    __shared__ float md[KD * 4];
    int n0 = blockIdx.x * 64;
    for (int i = threadIdx.x; i < 64 * KD; i += 256) {
        int r = i / KD, k = i - r * KD;
        int n = n0 + r;
        xt[r * (KD + 1) + k] = (n < NN) ? X[(size_t)n * KD + k] : 0.f;
    }
    for (int i = threadIdx.x; i < KD * 4; i += 256) { ms[i] = Ms[i]; md[i] = Md[i]; }
    __syncthreads();
    int r = threadIdx.x >> 2, h = threadIdx.x & 3;
    float s = 0.f, d = 0.f;
#pragma unroll 8
    for (int k = 0; k < KD; k++) {
        float xv = xt[r * (KD + 1) + k];
        s += xv * ms[k * 4 + h];
        d += xv * md[k * 4 + h];
    }
    int n = n0 + r;
    if (n < NN) { as_[n * 4 + h] = s; ad_[n * 4 + h] = d; }
}

// ---- edge prep: layer-1 scores (CSR order), layer-2 folded edge term, src_sorted ----
__global__ void edge_prep_kernel(const int* __restrict__ esort, const int* __restrict__ src,
                                 const int* __restrict__ dst, const float* __restrict__ EA,
                                 const float* __restrict__ S,
                                 const float* __restrict__ as_, const float* __restrict__ ad_,
                                 int* __restrict__ src_sorted,
                                 float* __restrict__ sc1, float* __restrict__ ae2s) {
    int idx = blockIdx.x * 256 + threadIdx.x;
    if (idx >= NE) return;
    int e = esort[idx];
    int s = src[e], d = dst[e];
    src_sorted[idx] = s;
    float a1[4], a2[4];
#pragma unroll
    for (int h = 0; h < 4; h++) { a1[h] = S[S_C1 + h]; a2[h] = S[S_C2 + h]; }
    const float4* EA4 = (const float4*)(EA + (size_t)e * FEA);
#pragma unroll
    for (int q = 0; q < 4; q++) {
        float4 v = EA4[q];
        float vv[4] = {v.x, v.y, v.z, v.w};
#pragma unroll
        for (int j = 0; j < 4; j++) {
            int f = q * 4 + j;
#pragma unroll
            for (int h = 0; h < 4; h++) {
                a1[h] += vv[j] * S[S_KF1 + f * 4 + h];
                a2[h] += vv[j] * S[S_KF2 + f * 4 + h];
            }
        }
    }
    ((float4*)ae2s)[idx] = make_float4(a2[0], a2[1], a2[2], a2[3]);
    float4 asv = ((const float4*)as_)[s];
    float4 adv = ((const float4*)ad_)[d];
    float4 r;
    r.x = expf(leakyf(asv.x + adv.x + a1[0]));
    r.y = expf(leakyf(asv.y + adv.y + a1[1]));
    r.z = expf(leakyf(asv.z + adv.z + a1[2]));
    r.w = expf(leakyf(asv.w + adv.w + a1[3]));
    ((float4*)sc1)[idx] = r;
}

// ---- GAT aggregate-first: agg[n,h,:] = (sum_e w_eh X[s,:] + ex*X[n,:]) / den_h ----
// KD = source feature dim (128 or 64). CW: compute w from ae2s+as/ad in-loop (layer 2).
template <int KD, bool CW>
__global__ __launch_bounds__(256) void agg_gat_kernel(
    const int* __restrict__ eoff, const int* __restrict__ src_sorted,
    const float* __restrict__ wsrc,   // CW ? ae2s : sc1   ([E,4], CSR order)
    const float* __restrict__ X,
    const float* __restrict__ as_, const float* __restrict__ ad_,
    const float* __restrict__ Sael, float* __restrict__ agg) {
    constexpr int CHUNKS = KD / 4;    // float4 per row
    constexpr int EPW = 64 / CHUNKS;  // edges in flight per wave
    int n = blockIdx.x * 4 + (threadIdx.x >> 6);
    if (n >= NN) return;
    int lane = threadIdx.x & 63;
    int sub = lane / CHUNKS;
    int ch = lane % CHUNKS;
    const float4* X4 = (const float4*)X;
    const float4* W4 = (const float4*)wsrc;
    const float4* AS4 = (const float4*)as_;
    float4 asn = AS4[n];
    float4 adn = ((const float4*)ad_)[n];
    float4 a0 = {0,0,0,0}, a1 = a0, a2 = a0, a3 = a0, dn = a0;
    int b = eoff[n], e = eoff[n + 1];
    int nE = e - b;
    int i = sub;
    for (; i + EPW < nE; i += 2 * EPW) {
        int idx0 = b + i, idx1 = b + i + EPW;
        int s0 = src_sorted[idx0], s1 = src_sorted[idx1];
        float4 w0 = W4[idx0], w1 = W4[idx1];
        if (CW) {
            float4 q0 = AS4[s0], q1 = AS4[s1];
            w0.x = expf(leakyf(q0.x + adn.x + w0.x));
            w0.y = expf(leakyf(q0.y + adn.y + w0.y));
            w0.z = expf(leakyf(q0.z + adn.z + w0.z));
            w0.w = expf(leakyf(q0.w + adn.w + w0.w));
            w1.x = expf(leakyf(q1.x + adn.x + w1.x));
            w1.y = expf(leakyf(q1.y + adn.y + w1.y));
            w1.z = expf(leakyf(q1.z + adn.z + w1.z));
            w1.w = expf(leakyf(q1.w + adn.w + w1.w));
        }
        float4 x0 = X4[(size_t)s0 * CHUNKS + ch];
        float4 x1 = X4[(size_t)s1 * CHUNKS + ch];
        fma4(a0, w0.x, x0); fma4(a1, w0.y, x0); fma4(a2, w0.z, x0); fma4(a3, w0.w, x0);
        fma4(a0, w1.x, x1); fma4(a1, w1.y, x1); fma4(a2, w1.z, x1); fma4(a3, w1.w, x1);
        dn.x += w0.x + w1.x; dn.y += w0.y + w1.y;
        dn.z += w0.z + w1.z; dn.w += w0.w + w1.w;
    }
    for (; i < nE; i += EPW) {
        int idx0 = b + i;
        int s0 = src_sorted[idx0];
        float4 w0 = W4[idx0];
        if (CW) {
            float4 q0 = AS4[s0];
            w0.x = expf(leakyf(q0.x + adn.x + w0.x));
            w0.y = expf(leakyf(q0.y + adn.y + w0.y));
            w0.z = expf(leakyf(q0.z + adn.z + w0.z));
            w0.w = expf(leakyf(q0.w + adn.w + w0.w));
        }
        float4 x0 = X4[(size_t)s0 * CHUNKS + ch];
        fma4(a0, w0.x, x0); fma4(a1, w0.y, x0); fma4(a2, w0.z, x0); fma4(a3, w0.w, x0);
        dn.x += w0.x; dn.y += w0.y; dn.z += w0.z; dn.w += w0.w;
    }
    if (sub == 0) {  // self loop
        float e0 = expf(leakyf(asn.x + adn.x + Sael[0]));
        float e1 = expf(leakyf(asn.y + adn.y + Sael[1]));
        float e2 = expf(leakyf(asn.z + adn.z + Sael[2]));
        float e3 = expf(leakyf(asn.w + adn.w + Sael[3]));
        float4 xs = X4[(size_t)n * CHUNKS + ch];
        fma4(a0, e0, xs); fma4(a1, e1, xs); fma4(a2, e2, xs); fma4(a3, e3, xs);
        dn.x += e0; dn.y += e1; dn.z += e2; dn.w += e3;
    }
#pragma unroll
    for (int mask = CHUNKS; mask < 64; mask <<= 1) {
        a0.x += __shfl_xor(a0.x, mask, 64); a0.y += __shfl_xor(a0.y, mask, 64);
        a0.z += __shfl_xor(a0.z, mask, 64); a0.w += __shfl_xor(a0.w, mask, 64);
        a1.x += __shfl_xor(a1.x, mask, 64); a1.y += __shfl_xor(a1.y, mask, 64);
        a1.z += __shfl_xor(a1.z, mask, 64); a1.w += __shfl_xor(a1.w, mask, 64);
        a2.x += __shfl_xor(a2.x, mask, 64); a2.y += __shfl_xor(a2.y, mask, 64);
        a2.z += __shfl_xor(a2.z, mask, 64); a2.w += __shfl_xor(a2.w, mask, 64);
        a3.x += __shfl_xor(a3.x, mask, 64); a3.y += __shfl_xor(a3.y, mask, 64);
        a3.z += __shfl_xor(a3.z, mask, 64); a3.w += __shfl_xor(a3.w, mask, 64);
        dn.x += __shfl_xor(dn.x, mask, 64); dn.y += __shfl_xor(dn.y, mask, 64);
        dn.z += __shfl_xor(dn.z, mask, 64); dn.w += __shfl_xor(dn.w, mask, 64);
    }
    if (sub == 0) {
        float i0 = 1.f / dn.x, i1 = 1.f / dn.y, i2 = 1.f / dn.z, i3 = 1.f / dn.w;
        float4* agg4 = (float4*)agg;
        size_t base = (size_t)n * 4 * CHUNKS + ch;
        agg4[base]              = make_float4(a0.x * i0, a0.y * i0, a0.z * i0, a0.w * i0);
        agg4[base + CHUNKS]     = make_float4(a1.x * i1, a1.y * i1, a1.z * i1, a1.w * i1);
        agg4[base + 2 * CHUNKS] = make_float4(a2.x * i2, a2.y * i2, a2.z * i2, a2.w * i2);
        agg4[base + 3 * CHUNKS] = make_float4(a3.x * i3, a3.y * i3, a3.z * i3, a3.w * i3);
    }
}

// ---- C[M,64] = elu(A[M,K] @ B[K,64] + bias): 128-row tile, acc 8x4 ----
template <int K>
__global__ __launch_bounds__(256) void gemm_n64_kernel(const float* __restrict__ A,
                                                       const float* __restrict__ B,
                                                       const float* __restrict__ bias,
                                                       float* __restrict__ out) {
    __shared__ float As[32 * 132];
    __shared__ float Bs[32 * 68];
    int t = threadIdx.x;
    int tx = t & 15, ty = t >> 4;
    int m_base = blockIdx.x * 128;
    float acc[8][4] = {};
    for (int k0 = 0; k0 < K; k0 += 32) {
#pragma unroll
        for (int i = 0; i < 4; i++) {
            int lin = t + i * 256;
            int row = lin >> 3;
            int kq = (lin & 7) * 4;
            int m = m_base + row;
            float4 f = {0.f, 0.f, 0.f, 0.f};
            if (m < NN) f = *(const float4*)(A + (size_t)m * K + k0 + kq);
            As[(kq + 0) * 132 + row] = f.x;
            As[(kq + 1) * 132 + row] = f.y;
            As[(kq + 2) * 132 + row] = f.z;
            As[(kq + 3) * 132 + row] = f.w;
        }
#pragma unroll
        for (int i = 0; i < 2; i++) {
            int lin = t + i * 256;
            int kr = lin >> 4;
            int nc = (lin & 15) * 4;
            *(float4*)(&Bs[kr * 68 + nc]) = *(const float4*)(B + (size_t)(k0 + kr) * 64 + nc);
        }
        __syncthreads();
#pragma unroll
        for (int k = 0; k < 32; k++) {
            float a[8], bb[4];
            *(float4*)(a)     = *(const float4*)(&As[k * 132 + ty * 8]);
            *(float4*)(a + 4) = *(const float4*)(&As[k * 132 + ty * 8 + 4]);
            *(float4*)(bb)    = *(const float4*)(&Bs[k * 68 + tx * 4]);
#pragma unroll
            for (int i = 0; i < 8; i++)
#pragma unroll
                for (int j = 0; j < 4; j++) acc[i][j] += a[i] * bb[j];
        }
        __syncthreads();
    }
    float4 bv = ((const float4*)bias)[tx];
    for (int i = 0; i < 8; i++) {
        int m = m_base + ty * 8 + i;
        if (m >= NN) continue;
        float4 o;
        o.x = eluf(acc[i][0] + bv.x);
        o.y = eluf(acc[i][1] + bv.y);
        o.z = eluf(acc[i][2] + bv.z);
        o.w = eluf(acc[i][3] + bv.w);
        *(float4*)(out + (size_t)m * 64 + tx * 4) = o;
    }
}

// ---- SAGE mean aggregation into AB[:,0:64]; copy h2 into AB[:,64:128] ----
__global__ __launch_bounds__(256) void sage_agg3_kernel(
    const float* __restrict__ h2, const int* __restrict__ eoff,
    const int* __restrict__ src_sorted, float* __restrict__ AB) {
    int n = blockIdx.x * 16 + (threadIdx.x >> 4);
    if (n >= NN) return;
    int l = threadIdx.x & 15;
    const float4* h24 = (const float4*)h2;
    float4* AB4 = (float4*)AB;
    float ax = 0.f, ay = 0.f, az = 0.f, aw = 0.f;
    int b = eoff[n], e_end = eoff[n + 1];
    int idx = b;
    int stop = b + ((e_end - b) & ~7);
    if (idx < stop) {
        int sreg[8];
#pragma unroll
        for (int u = 0; u < 8; u++) sreg[u] = src_sorted[idx + u];
        idx += 8;
        while (true) {
            int sn[8];
            bool more = idx < stop;
            if (more) {
#pragma unroll
                for (int u = 0; u < 8; u++) sn[u] = src_sorted[idx + u];
            }
#pragma unroll
            for (int u = 0; u < 8; u++) {
                float4 v = h24[(size_t)sreg[u] * 16 + l];
                ax += v.x; ay += v.y; az += v.z; aw += v.w;
            }
            if (!more) break;
#pragma unroll
            for (int u = 0; u < 8; u++) sreg[u] = sn[u];
            idx += 8;
        }
    }
    for (; idx < e_end; idx++) {
        float4 v0 = h24[(size_t)src_sorted[idx] * 16 + l];
        ax += v0.x; ay += v0.y; az += v0.z; aw += v0.w;
    }
    float dg = (float)(e_end - b);
    if (dg < 1.f) dg = 1.f;
    float inv = 1.f / dg;
    AB4[(size_t)n * 32 + l] = make_float4(ax * inv, ay * inv, az * inv, aw * inv);
    AB4[(size_t)n * 32 + 16 + l] = h24[(size_t)n * 16 + l];
}

// ---- per-graph mean pool ----
__global__ void pool_kernel(const float* __restrict__ h3, const int* __restrict__ goff,
                            float* __restrict__ gmean) {
    __shared__ float red[256];
    int g = blockIdx.x, t = threadIdx.x;
    int c = t & 63, li = t >> 6;
    int b = goff[g], e = goff[g + 1];
    float sum = 0.f;
    for (int r = b + li; r < e; r += 4) sum += h3[(size_t)r * HID + c];
    red[t] = sum;
    __syncthreads();
    if (t < 64) {
        float v = red[t] + red[t + 64] + red[t + 128] + red[t + 192];
        float cntf = (float)(e - b);
        if (cntf < 1.f) cntf = 1.f;
        gmean[g * HID + t] = v / cntf;
    }
}

// ---- final MLP head -> d_out[192] ----
__global__ void mlp_kernel(const float* __restrict__ gmean, const float* __restrict__ lin1W,
                           const float* __restrict__ lin1b, const float* __restrict__ lin2W,
                           const float* __restrict__ lin2b, const float* __restrict__ telW,
                           const float* __restrict__ telb, const float* __restrict__ compW,
                           const float* __restrict__ compb, const float* __restrict__ pchW,
                           const float* __restrict__ pchb, float* __restrict__ out) {
    __shared__ float G[4096], Wb[4096], G1[4096], G2[4096];
    int t = threadIdx.x;
    for (int i = t; i < 4096; i += 256) { G[i] = gmean[i]; Wb[i] = lin1W[i]; }
    __syncthreads();
    int c = t & 63;
    for (int j = 0; j < 16; j++) {
        int r = (t >> 6) + 4 * j;
        float acc = lin1b[c];
        for (int k = 0; k < 64; k++) acc += G[r * 64 + k] * Wb[k * 64 + c];
        G1[r * 64 + c] = eluf(acc);
    }
    __syncthreads();
    for (int i = t; i < 4096; i += 256) Wb[i] = lin2W[i];
    __syncthreads();
    for (int j = 0; j < 16; j++) {
        int r = (t >> 6) + 4 * j;
        float acc = lin2b[c];
        for (int k = 0; k < 64; k++) acc += G1[r * 64 + k] * Wb[k * 64 + c];
        G2[r * 64 + c] = acc;
    }
    __syncthreads();
    if (t < 64) {
        int r = t;
        float a = telb[0], b_ = compb[0], p = pchb[0];
        for (int k = 0; k < 64; k++) {
            float v = G2[r * 64 + k];
            a += v * telW[k];
            b_ += v * compW[k];
            p += v * pchW[k];
        }
        out[r] = a;
        out[64 + r] = b_;
        out[128 + r] = p;
    }
}

extern "C" void kernel_launch(void* const* d_in, const int* in_sizes, int n_in,
                              void* d_out, int out_size, void* d_ws, size_t ws_size,
                              hipStream_t stream) {
    const float* x        = (const float*)d_in[0];
    const float* EA       = (const float*)d_in[1];
    const float* node_emb = (const float*)d_in[2];
    const float* edge_W   = (const float*)d_in[3];
    const float* edge_b   = (const float*)d_in[4];
    const float* W1       = (const float*)d_in[5];
    const float* as1      = (const float*)d_in[6];
    const float* ad1      = (const float*)d_in[7];
    const float* ae1      = (const float*)d_in[8];
    const float* leW1     = (const float*)d_in[9];
    const float* b1       = (const float*)d_in[10];
    const float* W2       = (const float*)d_in[11];
    const float* as2      = (const float*)d_in[12];
    const float* ad2      = (const float*)d_in[13];
    const float* ae2      = (const float*)d_in[14];
    const float* leW2     = (const float*)d_in[15];
    const float* b2       = (const float*)d_in[16];
    const float* sage_Wl  = (const float*)d_in[17];
    const float* sage_bl  = (const float*)d_in[18];
    const float* sage_Wr  = (const float*)d_in[19];
    const float* lin1_W   = (const float*)d_in[20];
    const float* lin1_b   = (const float*)d_in[21];
    const float* lin2_W   = (const float*)d_in[22];
    const float* lin2_b   = (const float*)d_in[23];
    const float* tel_W    = (const float*)d_in[24];
    const float* tel_b    = (const float*)d_in[25];
    const float* comp_W   = (const float*)d_in[26];
    const float* comp_b   = (const float*)d_in[27];
    const float* pch_W    = (const float*)d_in[28];
    const float* pch_b    = (const float*)d_in[29];
    const int* edge_index = (const int*)d_in[30];
    const int* batch      = (const int*)d_in[31];
    const int* node_type  = (const int*)d_in[32];
    float* outp = (float*)d_out;

    const int* srcp = edge_index;
    const int* dstp = edge_index + NE;

    float* wf = (float*)d_ws;
    constexpr size_t OFF_H0    = 0;                               // N*128 (h3 aliases later)
    constexpr size_t OFF_AGG   = OFF_H0 + (size_t)NN * 128;       // N*512 (agg1; agg2; AB alias)
    constexpr size_t OFF_H1    = OFF_AGG + (size_t)NN * 512;      // N*64
    constexpr size_t OFF_H2    = OFF_H1 + (size_t)NN * 64;        // N*64
    constexpr size_t OFF_SC    = OFF_H2 + (size_t)NN * 64;        // E*4
    constexpr size_t OFF_AE2   = OFF_SC + (size_t)NE * 4;         // E*4
    constexpr size_t OFF_AS    = OFF_AE2 + (size_t)NE * 4;        // N*4
    constexpr size_t OFF_AD    = OFF_AS + (size_t)NN * 4;         // N*4
    constexpr size_t OFF_SMALL = OFF_AD + (size_t)NN * 4;         // 4096
    constexpr size_t OFF_GMEAN = OFF_SMALL + 4096;                // 4096
    constexpr size_t OFF_WC1   = OFF_GMEAN + 4096;                // 32768
    constexpr size_t OFF_WC2   = OFF_WC1 + 32768;                 // 16384
    constexpr size_t OFF_B128  = OFF_WC2 + 16384;                 // 8192
    constexpr size_t F_TOTAL   = OFF_B128 + 8192;

    int* wi         = (int*)(wf + F_TOTAL);
    int* cnt        = wi;                        // N
    int* pos        = wi + NN;                   // N   (adjacent: one memset)
    int* eoff       = pos + NN;                  // N+1
    int* esort      = eoff + (NN + 1);           // E
    int* src_sorted = esort + NE;                // E
    int* goff       = src_sorted + NE;           // NG+1
    int* bsum       = goff + (NG + 1);           // 64
    int* boff       = bsum + 64;                 // 64

    float* h0    = wf + OFF_H0;
    float* aggb  = wf + OFF_AGG;
    float* h1    = wf + OFF_H1;
    float* h2    = wf + OFF_H2;
    float* sc    = wf + OFF_SC;
    float* ae2s  = wf + OFF_AE2;
    float* as_   = wf + OFF_AS;
    float* ad_   = wf + OFF_AD;
    float* S     = wf + OFF_SMALL;
    float* gmean = wf + OFF_GMEAN;
    float* WC1   = wf + OFF_WC1;
    float* WC2   = wf + OFF_WC2;
    float* B128  = wf + OFF_B128;
    float* AB    = wf + OFF_AGG;                 // alias (agg dead after gemm L2)
    float* h3    = wf + OFF_H0;                  // alias (h0 dead after agg L1)

    hipMemsetAsync(S + S_MEANEA, 0, 16 * sizeof(float), stream);
    hipMemsetAsync(cnt, 0, 2 * NN * sizeof(int), stream);   // cnt + pos

    edge_mean_kernel<<<(NE + 1023) / 1024, 256, 0, stream>>>(EA, S);
    prep_small_kernel<<<1, 256, 0, stream>>>(W1, as1, ad1, ae1, leW1,
                                             W2, as2, ad2, ae2, leW2,
                                             edge_W, edge_b, sage_Wl, sage_Wr,
                                             S, WC1, WC2, B128);
    build_h0_kernel<<<(NN * 128 + 255) / 256, 256, 0, stream>>>(x, node_emb, node_type, h0);

    // CSR
    count_kernel<<<(NE + 255) / 256, 256, 0, stream>>>(dstp, cnt);
    {
        int nb = (NN + 1023) / 1024;  // 30
        scan_blocks_kernel<<<nb, 1024, 0, stream>>>(cnt, eoff, bsum);
        scan_tops_kernel<<<1, 64, 0, stream>>>(bsum, boff, nb);
        scan_add_kernel<<<(NN + 255) / 256, 256, 0, stream>>>(boff, eoff);
    }
    scatter_kernel<<<(NE + 255) / 256, 256, 0, stream>>>(dstp, eoff, pos, esort);
    goff_bs_kernel<<<1, 128, 0, stream>>>(batch, goff);

    // ----- GAT layer 1: attn coeffs -> scores -> aggregate(X) -> project -----
    attn_sd_kernel<128><<<(NN + 63) / 64, 256, 0, stream>>>(h0, S + S_MS1, S + S_MD1, as_, ad_);
    edge_prep_kernel<<<(NE + 255) / 256, 256, 0, stream>>>(
        esort, srcp, dstp, EA, S, as_, ad_, src_sorted, sc, ae2s);
    agg_gat_kernel<128, false><<<(NN + 3) / 4, 256, 0, stream>>>(
        eoff, src_sorted, sc, h0, as_, ad_, S + S_AEL1, aggb);
    gemm_n64_kernel<512><<<(NN + 127) / 128, 256, 0, stream>>>(aggb, WC1, b1, h1);

    // ----- GAT layer 2 -----
    attn_sd_kernel<64><<<(NN + 63) / 64, 256, 0, stream>>>(h1, S + S_MS2, S + S_MD2, as_, ad_);
    agg_gat_kernel<64, true><<<(NN + 3) / 4, 256, 0, stream>>>(
        eoff, src_sorted, ae2s, h1, as_, ad_, S + S_AEL2, aggb);
    gemm_n64_kernel<256><<<(NN + 127) / 128, 256, 0, stream>>>(aggb, WC2, b2, h2);

    // ----- SAGE -----
    sage_agg3_kernel<<<(NN + 15) / 16, 256, 0, stream>>>(h2, eoff, src_sorted, AB);
    gemm_n64_kernel<128><<<(NN + 127) / 128, 256, 0, stream>>>(AB, B128, sage_bl, h3);

    // ----- pool + MLP head -----
    pool_kernel<<<NG, 256, 0, stream>>>(h3, goff, gmean);
    mlp_kernel<<<1, 256, 0, stream>>>(gmean, lin1_W, lin1_b, lin2_W, lin2_b,
                                      tel_W, tel_b, comp_W, comp_b, pch_W, pch_b, outp);
}

// Round 5
// 559.285 us; speedup vs baseline: 2.2417x; 1.1473x over previous
//
#include <hip/hip_runtime.h>
#include <math.h>

#define NN 30000          // nodes
#define NE 480000         // edges
#define FEA 16            // edge feature dim
#define HID 64
#define NG 64             // graphs
#define LEAKK 0.2f

// ---- small-constant region layout (float offsets) ----
#define S_MEANEA 0    // 16
#define S_KF1    16   // 64  (K1 [16,4])
#define S_C1     80   // 4
#define S_AEL1   84   // 4
#define S_KF2    88   // 64
#define S_C2     152  // 4
#define S_AEL2   156  // 4
#define S_MS1    160  // 512 (Ms1 [128,4])
#define S_MD1    672  // 512
#define S_MS2    1184 // 256 (Ms2 [64,4])
#define S_MD2    1440 // 256

__device__ __forceinline__ float eluf(float v) { return v > 0.f ? v : expm1f(v); }
__device__ __forceinline__ float leakyf(float v) { return v >= 0.f ? v : LEAKK * v; }
__device__ __forceinline__ void fma4(float4& a, float w, const float4& x) {
    a.x += w * x.x; a.y += w * x.y; a.z += w * x.z; a.w += w * x.w;
}

// ---- count (CSR degree) + mean of edge_attr, one pass over edges ----
__global__ void count_mean_kernel(const int* __restrict__ dst, const float* __restrict__ EA,
                                  int* __restrict__ cnt, float* __restrict__ S) {
    __shared__ float red[256];
    int t = threadIdx.x;
    int base = blockIdx.x * 1024;
#pragma unroll
    for (int i = 0; i < 4; i++) {
        int e = base + i * 256 + t;
        if (e < NE) atomicAdd(&cnt[dst[e]], 1);
    }
    int col = t & 15;
    int rbase = base + (t >> 4);
    float sum = 0.f;
    for (int i = 0; i < 64; i++) {
        int r = rbase + i * 16;
        if (r < NE) sum += EA[(size_t)r * FEA + col];
    }
    red[t] = sum;
    __syncthreads();
    if (t < 16) {
        float v = 0.f;
        for (int j = 0; j < 16; j++) v += red[t + j * 16];
        atomicAdd(&S[S_MEANEA + t], v);
    }
}

// ---- fold attention weights into small matrices; build WC1/WC2/B128 ----
__global__ void prep_small_kernel(
    const float* __restrict__ W1, const float* __restrict__ as1, const float* __restrict__ ad1,
    const float* __restrict__ ae1, const float* __restrict__ leW1,
    const float* __restrict__ W2, const float* __restrict__ as2, const float* __restrict__ ad2,
    const float* __restrict__ ae2, const float* __restrict__ leW2,
    const float* __restrict__ edge_W, const float* __restrict__ edge_b,
    const float* __restrict__ Wl, const float* __restrict__ Wr,
    float* __restrict__ S, float* __restrict__ WC1, float* __restrict__ WC2,
    float* __restrict__ B128) {
    __shared__ float M1[256], M2[256], meh[64];
    int t = threadIdx.x;
    if (t < 16) S[S_MEANEA + t] *= (1.0f / (float)NE);
    __syncthreads();
    {
        int k = t >> 2, h = t & 3;
        float m1 = 0.f, m2 = 0.f;
        for (int c = 0; c < 64; c++) {
            m1 += leW1[k * 256 + h * 64 + c] * ae1[h * 64 + c];
            m2 += leW2[k * 256 + h * 64 + c] * ae2[h * 64 + c];
        }
        M1[t] = m1; M2[t] = m2;
    }
    if (t < 64) {
        float v = edge_b[t];
        for (int f = 0; f < FEA; f++) v += S[S_MEANEA + f] * edge_W[f * 64 + t];
        meh[t] = v;
    }
    __syncthreads();
    if (t < 64) {
        int f = t >> 2, h = t & 3;
        float k1 = 0.f, k2 = 0.f;
        for (int k = 0; k < 64; k++) {
            k1 += edge_W[f * 64 + k] * M1[k * 4 + h];
            k2 += edge_W[f * 64 + k] * M2[k * 4 + h];
        }
        S[S_KF1 + t] = k1; S[S_KF2 + t] = k2;
    } else if (t < 68) {
        int h = t - 64;
        float c1 = 0.f, c2 = 0.f, a1 = 0.f, a2 = 0.f;
        for (int k = 0; k < 64; k++) {
            c1 += edge_b[k] * M1[k * 4 + h];
            c2 += edge_b[k] * M2[k * 4 + h];
            a1 += meh[k] * M1[k * 4 + h];
            a2 += meh[k] * M2[k * 4 + h];
        }
        S[S_C1 + h] = c1; S[S_C2 + h] = c2;
        S[S_AEL1 + h] = a1; S[S_AEL2 + h] = a2;
    }
    for (int i = t; i < 512; i += 256) {
        int k = i >> 2, h = i & 3;
        float s = 0.f, d = 0.f;
        for (int c = 0; c < 64; c++) {
            float w = W1[k * 256 + h * 64 + c];
            s += w * as1[h * 64 + c];
            d += w * ad1[h * 64 + c];
        }
        S[S_MS1 + i] = s; S[S_MD1 + i] = d;
    }
    for (int i = t; i < 256; i += 256) {
        int k = i >> 2, h = i & 3;
        float s = 0.f, d = 0.f;
        for (int c = 0; c < 64; c++) {
            float w = W2[k * 256 + h * 64 + c];
            s += w * as2[h * 64 + c];
            d += w * ad2[h * 64 + c];
        }
        S[S_MS2 + i] = s; S[S_MD2 + i] = d;
    }
    // WC1[(h*128+k)*64+c] = 0.25*W1[k*256+h*64+c]   (512x64)
    for (int i = t; i < 32768; i += 256) {
        int hk = i >> 6, c = i & 63;
        int h = hk >> 7, k = hk & 127;
        WC1[i] = 0.25f * W1[k * 256 + h * 64 + c];
    }
    // WC2[(h*64+k)*64+c] = 0.25*W2[k*256+h*64+c]    (256x64)
    for (int i = t; i < 16384; i += 256) {
        int hk = i >> 6, c = i & 63;
        int h = hk >> 6, k = hk & 63;
        WC2[i] = 0.25f * W2[k * 256 + h * 64 + c];
    }
    // B128 = [Wl; Wr]  (128x64)
    for (int i = t; i < 8192; i += 256) {
        int k = i >> 6, c = i & 63;
        B128[i] = (k < 64) ? Wl[k * 64 + c] : Wr[(k - 64) * 64 + c];
    }
}

// ---- build h0 = concat(x, emb[type]) AND compute layer-1 a_s/a_d ----
__global__ __launch_bounds__(256) void attn_h0_kernel(
    const float* __restrict__ x, const float* __restrict__ node_emb,
    const int* __restrict__ node_type, const float* __restrict__ S,
    float* __restrict__ h0, float* __restrict__ as_, float* __restrict__ ad_) {
    __shared__ float xt[64 * 132];
    __shared__ float ms[512], md[512];
    __shared__ int ntS[64];
    int t = threadIdx.x;
    int n0 = blockIdx.x * 64;
    if (t < 64) {
        int n = n0 + t;
        ntS[t] = (n < NN) ? node_type[n] : 0;
    }
    for (int i = t; i < 512; i += 256) { ms[i] = S[S_MS1 + i]; md[i] = S[S_MD1 + i]; }
    __syncthreads();
    for (int i = t; i < 1024; i += 256) {
        int r = i >> 4, c4 = (i & 15) * 4;
        int n = n0 + r;
        float4 f = {0, 0, 0, 0};
        if (n < NN) f = *(const float4*)(x + (size_t)n * 64 + c4);
        *(float4*)&xt[r * 132 + c4] = f;
    }
    for (int i = t; i < 1024; i += 256) {
        int r = i >> 4, c4 = (i & 15) * 4;
        int n = n0 + r;
        float4 f = {0, 0, 0, 0};
        if (n < NN) f = *(const float4*)(node_emb + (size_t)ntS[r] * 64 + c4);
        *(float4*)&xt[r * 132 + 64 + c4] = f;
    }
    __syncthreads();
    // write h0
    for (int i = t; i < 2048; i += 256) {
        int r = i >> 5, c4 = (i & 31) * 4;
        int n = n0 + r;
        if (n < NN) *(float4*)(h0 + (size_t)n * 128 + c4) = *(const float4*)&xt[r * 132 + c4];
    }
    // a_s/a_d
    int r = t >> 2, h = t & 3;
    float s = 0.f, d = 0.f;
#pragma unroll 8
    for (int k = 0; k < 128; k++) {
        float xv = xt[r * 132 + k];
        s += xv * ms[k * 4 + h];
        d += xv * md[k * 4 + h];
    }
    int n = n0 + r;
    if (n < NN) { as_[n * 4 + h] = s; ad_[n * 4 + h] = d; }
}

// ---- 3-kernel decoupled scan ----
__global__ void scan_blocks_kernel(const int* __restrict__ cnt, int* __restrict__ eoff,
                                   int* __restrict__ bsum) {
    __shared__ int wsum[16];
    int t = threadIdx.x;
    int i = blockIdx.x * 1024 + t;
    int v = (i < NN) ? cnt[i] : 0;
    int lane = t & 63;
    int incl = v;
#pragma unroll
    for (int ofs = 1; ofs < 64; ofs <<= 1) {
        int u = __shfl_up(incl, ofs, 64);
        if (lane >= ofs) incl += u;
    }
    int wid = t >> 6;
    if (lane == 63) wsum[wid] = incl;
    __syncthreads();
    if (t < 16) {
        int s = wsum[t];
#pragma unroll
        for (int ofs = 1; ofs < 16; ofs <<= 1) {
            int u = __shfl_up(s, ofs, 64);
            if (t >= ofs) s += u;
        }
        wsum[t] = s;
    }
    __syncthreads();
    int excl = incl - v + (wid > 0 ? wsum[wid - 1] : 0);
    if (i < NN) eoff[i] = excl;
    if (t == 1023) bsum[blockIdx.x] = excl + v;
}

__global__ void scan_tops_kernel(const int* __restrict__ bsum, int* __restrict__ boff, int nb) {
    int t = threadIdx.x; // 64
    int v = (t < nb) ? bsum[t] : 0;
    int incl = v;
#pragma unroll
    for (int ofs = 1; ofs < 64; ofs <<= 1) {
        int u = __shfl_up(incl, ofs, 64);
        if (t >= ofs) incl += u;
    }
    boff[t] = incl - v;
}

__global__ void scan_add_kernel(const int* __restrict__ boff, int* __restrict__ eoff) {
    int i = blockIdx.x * 256 + threadIdx.x;
    if (i < NN) eoff[i] += boff[i >> 10];
    if (i == 0) eoff[NN] = NE;
}

// ---- fused scatter + scoring: coalesced EA reads, scattered CSR writes ----
__global__ void scatter_score_kernel(const int* __restrict__ src, const int* __restrict__ dst,
                                     const float* __restrict__ EA, const float* __restrict__ S,
                                     const float* __restrict__ as_, const float* __restrict__ ad_,
                                     const int* __restrict__ eoff, int* __restrict__ pos,
                                     int* __restrict__ src_sorted,
                                     float* __restrict__ sc1, float* __restrict__ ae2s) {
    int e = blockIdx.x * 256 + threadIdx.x;
    if (e >= NE) return;
    int s = src[e], d = dst[e];
    float a1[4], a2[4];
#pragma unroll
    for (int h = 0; h < 4; h++) { a1[h] = S[S_C1 + h]; a2[h] = S[S_C2 + h]; }
    const float4* EA4 = (const float4*)(EA + (size_t)e * FEA);
#pragma unroll
    for (int q = 0; q < 4; q++) {
        float4 v = EA4[q];
        float vv[4] = {v.x, v.y, v.z, v.w};
#pragma unroll
        for (int j = 0; j < 4; j++) {
            int f = q * 4 + j;
#pragma unroll
            for (int h = 0; h < 4; h++) {
                a1[h] += vv[j] * S[S_KF1 + f * 4 + h];
                a2[h] += vv[j] * S[S_KF2 + f * 4 + h];
            }
        }
    }
    int p = atomicAdd(&pos[d], 1);
    int idx = eoff[d] + p;
    src_sorted[idx] = s;
    ((float4*)ae2s)[idx] = make_float4(a2[0], a2[1], a2[2], a2[3]);
    float4 asv = ((const float4*)as_)[s];
    float4 adv = ((const float4*)ad_)[d];
    float4 r;
    r.x = expf(leakyf(asv.x + adv.x + a1[0]));
    r.y = expf(leakyf(asv.y + adv.y + a1[1]));
    r.z = expf(leakyf(asv.z + adv.z + a1[2]));
    r.w = expf(leakyf(asv.w + adv.w + a1[3]));
    ((float4*)sc1)[idx] = r;
}

// ---- goff via binary search over sorted batch ----
__global__ void goff_bs_kernel(const int* __restrict__ batch, int* __restrict__ goff) {
    int g = threadIdx.x;
    if (g > NG) return;
    int lo = 0, hi = NN;
    while (lo < hi) {
        int mid = (lo + hi) >> 1;
        if (batch[mid] < g) lo = mid + 1; else hi = mid;
    }
    goff[g] = lo;
}

// ---- GAT aggregate-first (unchanged from R4) ----
template <int KD, bool CW>
__global__ __launch_bounds__(256) void agg_gat_kernel(
    const int* __restrict__ eoff, const int* __restrict__ src_sorted,
    const float* __restrict__ wsrc, const float* __restrict__ X,
    const float* __restrict__ as_, const float* __restrict__ ad_,
    const float* __restrict__ Sael, float* __restrict__ agg) {
    constexpr int CHUNKS = KD / 4;
    constexpr int EPW = 64 / CHUNKS;
    int n = blockIdx.x * 4 + (threadIdx.x >> 6);
    if (n >= NN) return;
    int lane = threadIdx.x & 63;
    int sub = lane / CHUNKS;
    int ch = lane % CHUNKS;
    const float4* X4 = (const float4*)X;
    const float4* W4 = (const float4*)wsrc;
    const float4* AS4 = (const float4*)as_;
    float4 asn = AS4[n];
    float4 adn = ((const float4*)ad_)[n];
    float4 a0 = {0, 0, 0, 0}, a1 = a0, a2 = a0, a3 = a0, dn = a0;
    int b = eoff[n], e = eoff[n + 1];
    int nE = e - b;
    int i = sub;
    for (; i + EPW < nE; i += 2 * EPW) {
        int idx0 = b + i, idx1 = b + i + EPW;
        int s0 = src_sorted[idx0], s1 = src_sorted[idx1];
        float4 w0 = W4[idx0], w1 = W4[idx1];
        if (CW) {
            float4 q0 = AS4[s0], q1 = AS4[s1];
            w0.x = expf(leakyf(q0.x + adn.x + w0.x));
            w0.y = expf(leakyf(q0.y + adn.y + w0.y));
            w0.z = expf(leakyf(q0.z + adn.z + w0.z));
            w0.w = expf(leakyf(q0.w + adn.w + w0.w));
            w1.x = expf(leakyf(q1.x + adn.x + w1.x));
            w1.y = expf(leakyf(q1.y + adn.y + w1.y));
            w1.z = expf(leakyf(q1.z + adn.z + w1.z));
            w1.w = expf(leakyf(q1.w + adn.w + w1.w));
        }
        float4 x0 = X4[(size_t)s0 * CHUNKS + ch];
        float4 x1 = X4[(size_t)s1 * CHUNKS + ch];
        fma4(a0, w0.x, x0); fma4(a1, w0.y, x0); fma4(a2, w0.z, x0); fma4(a3, w0.w, x0);
        fma4(a0, w1.x, x1); fma4(a1, w1.y, x1); fma4(a2, w1.z, x1); fma4(a3, w1.w, x1);
        dn.x += w0.x + w1.x; dn.y += w0.y + w1.y;
        dn.z += w0.z + w1.z; dn.w += w0.w + w1.w;
    }
    for (; i < nE; i += EPW) {
        int idx0 = b + i;
        int s0 = src_sorted[idx0];
        float4 w0 = W4[idx0];
        if (CW) {
            float4 q0 = AS4[s0];
            w0.x = expf(leakyf(q0.x + adn.x + w0.x));
            w0.y = expf(leakyf(q0.y + adn.y + w0.y));
            w0.z = expf(leakyf(q0.z + adn.z + w0.z));
            w0.w = expf(leakyf(q0.w + adn.w + w0.w));
        }
        float4 x0 = X4[(size_t)s0 * CHUNKS + ch];
        fma4(a0, w0.x, x0); fma4(a1, w0.y, x0); fma4(a2, w0.z, x0); fma4(a3, w0.w, x0);
        dn.x += w0.x; dn.y += w0.y; dn.z += w0.z; dn.w += w0.w;
    }
    if (sub == 0) {  // self loop
        float e0 = expf(leakyf(asn.x + adn.x + Sael[0]));
        float e1 = expf(leakyf(asn.y + adn.y + Sael[1]));
        float e2 = expf(leakyf(asn.z + adn.z + Sael[2]));
        float e3 = expf(leakyf(asn.w + adn.w + Sael[3]));
        float4 xs = X4[(size_t)n * CHUNKS + ch];
        fma4(a0, e0, xs); fma4(a1, e1, xs); fma4(a2, e2, xs); fma4(a3, e3, xs);
        dn.x += e0; dn.y += e1; dn.z += e2; dn.w += e3;
    }
#pragma unroll
    for (int mask = CHUNKS; mask < 64; mask <<= 1) {
        a0.x += __shfl_xor(a0.x, mask, 64); a0.y += __shfl_xor(a0.y, mask, 64);
        a0.z += __shfl_xor(a0.z, mask, 64); a0.w += __shfl_xor(a0.w, mask, 64);
        a1.x += __shfl_xor(a1.x, mask, 64); a1.y += __shfl_xor(a1.y, mask, 64);
        a1.z += __shfl_xor(a1.z, mask, 64); a1.w += __shfl_xor(a1.w, mask, 64);
        a2.x += __shfl_xor(a2.x, mask, 64); a2.y += __shfl_xor(a2.y, mask, 64);
        a2.z += __shfl_xor(a2.z, mask, 64); a2.w += __shfl_xor(a2.w, mask, 64);
        a3.x += __shfl_xor(a3.x, mask, 64); a3.y += __shfl_xor(a3.y, mask, 64);
        a3.z += __shfl_xor(a3.z, mask, 64); a3.w += __shfl_xor(a3.w, mask, 64);
        dn.x += __shfl_xor(dn.x, mask, 64); dn.y += __shfl_xor(dn.y, mask, 64);
        dn.z += __shfl_xor(dn.z, mask, 64); dn.w += __shfl_xor(dn.w, mask, 64);
    }
    if (sub == 0) {
        float i0 = 1.f / dn.x, i1 = 1.f / dn.y, i2 = 1.f / dn.z, i3 = 1.f / dn.w;
        float4* agg4 = (float4*)agg;
        size_t base = (size_t)n * 4 * CHUNKS + ch;
        agg4[base]              = make_float4(a0.x * i0, a0.y * i0, a0.z * i0, a0.w * i0);
        agg4[base + CHUNKS]     = make_float4(a1.x * i1, a1.y * i1, a1.z * i1, a1.w * i1);
        agg4[base + 2 * CHUNKS] = make_float4(a2.x * i2, a2.y * i2, a2.z * i2, a2.w * i2);
        agg4[base + 3 * CHUNKS] = make_float4(a3.x * i3, a3.y * i3, a3.z * i3, a3.w * i3);
    }
}

// ---- thin GEMM: out[M,64] = elu(A[M,K]@B[K,64]+bias); 32-row tiles, 938 blocks ----
// DOATT: also emit a_s/a_d = out @ Ms2/Md2 via in-register row reduction.
template <int K, bool DOATT>
__global__ __launch_bounds__(256) void gemm32_kernel(
    const float* __restrict__ A, const float* __restrict__ B,
    const float* __restrict__ bias, float* __restrict__ out,
    const float* __restrict__ ms_g, const float* __restrict__ md_g,
    float* __restrict__ as_, float* __restrict__ ad_) {
    __shared__ float As[32 * 34];   // [k][row], stride 34 (conflict-lite, b64-aligned)
    __shared__ float Bs[32 * 68];   // [k][c], stride 68 (b128-aligned)
    __shared__ float msS[256], mdS[256];
    int t = threadIdx.x;
    int tx = t & 15, ty = t >> 4;
    int m_base = blockIdx.x * 32;
    if (DOATT) { msS[t] = ms_g[t]; mdS[t] = md_g[t]; }
    float acc[2][4] = {};
    for (int k0 = 0; k0 < K; k0 += 32) {
        {   // stage A (coalesced 128B/row), k-major in LDS
            int row = t >> 3, kq = (t & 7) * 4;
            int m = m_base + row;
            float4 f = {0, 0, 0, 0};
            if (m < NN) f = *(const float4*)(A + (size_t)m * K + k0 + kq);
            As[(kq + 0) * 34 + row] = f.x;
            As[(kq + 1) * 34 + row] = f.y;
            As[(kq + 2) * 34 + row] = f.z;
            As[(kq + 3) * 34 + row] = f.w;
        }
        {   // stage B
            int kr = t >> 4, nc = (t & 15) * 4;
            *(float4*)&Bs[kr * 68 + nc] = *(const float4*)(B + (size_t)(k0 + kr) * 64 + nc);
            *(float4*)&Bs[(kr + 16) * 68 + nc] =
                *(const float4*)(B + (size_t)(k0 + kr + 16) * 64 + nc);
        }
        __syncthreads();
#pragma unroll
        for (int k = 0; k < 32; k++) {
            float a0 = As[k * 34 + ty * 2];
            float a1v = As[k * 34 + ty * 2 + 1];
            float4 bv = *(const float4*)&Bs[k * 68 + tx * 4];
            acc[0][0] += a0 * bv.x;  acc[0][1] += a0 * bv.y;
            acc[0][2] += a0 * bv.z;  acc[0][3] += a0 * bv.w;
            acc[1][0] += a1v * bv.x; acc[1][1] += a1v * bv.y;
            acc[1][2] += a1v * bv.z; acc[1][3] += a1v * bv.w;
        }
        __syncthreads();
    }
    float4 bvv = ((const float4*)bias)[tx];
    float o[2][4];
#pragma unroll
    for (int i = 0; i < 2; i++) {
        o[i][0] = eluf(acc[i][0] + bvv.x);
        o[i][1] = eluf(acc[i][1] + bvv.y);
        o[i][2] = eluf(acc[i][2] + bvv.z);
        o[i][3] = eluf(acc[i][3] + bvv.w);
        int m = m_base + ty * 2 + i;
        if (m < NN)
            *(float4*)(out + (size_t)m * 64 + tx * 4) =
                make_float4(o[i][0], o[i][1], o[i][2], o[i][3]);
    }
    if (DOATT) {
#pragma unroll
        for (int i = 0; i < 2; i++) {
            float ps[4] = {0, 0, 0, 0}, pd[4] = {0, 0, 0, 0};
#pragma unroll
            for (int j = 0; j < 4; j++) {
                float v = o[i][j];
                int kk = (tx * 4 + j) * 4;
#pragma unroll
                for (int h = 0; h < 4; h++) {
                    ps[h] += v * msS[kk + h];
                    pd[h] += v * mdS[kk + h];
                }
            }
#pragma unroll
            for (int mk = 1; mk < 16; mk <<= 1) {
#pragma unroll
                for (int h = 0; h < 4; h++) {
                    ps[h] += __shfl_xor(ps[h], mk, 64);
                    pd[h] += __shfl_xor(pd[h], mk, 64);
                }
            }
            int m = m_base + ty * 2 + i;
            if (tx == 0 && m < NN) {
                *(float4*)(as_ + (size_t)m * 4) = make_float4(ps[0], ps[1], ps[2], ps[3]);
                *(float4*)(ad_ + (size_t)m * 4) = make_float4(pd[0], pd[1], pd[2], pd[3]);
            }
        }
    }
}

// ---- SAGE mean aggregation into AB[:,0:64]; copy h2 into AB[:,64:128] ----
__global__ __launch_bounds__(256) void sage_agg3_kernel(
    const float* __restrict__ h2, const int* __restrict__ eoff,
    const int* __restrict__ src_sorted, float* __restrict__ AB) {
    int n = blockIdx.x * 16 + (threadIdx.x >> 4);
    if (n >= NN) return;
    int l = threadIdx.x & 15;
    const float4* h24 = (const float4*)h2;
    float4* AB4 = (float4*)AB;
    float ax = 0.f, ay = 0.f, az = 0.f, aw = 0.f;
    int b = eoff[n], e_end = eoff[n + 1];
    int idx = b;
    int stop = b + ((e_end - b) & ~7);
    if (idx < stop) {
        int sreg[8];
#pragma unroll
        for (int u = 0; u < 8; u++) sreg[u] = src_sorted[idx + u];
        idx += 8;
        while (true) {
            int sn[8];
            bool more = idx < stop;
            if (more) {
#pragma unroll
                for (int u = 0; u < 8; u++) sn[u] = src_sorted[idx + u];
            }
#pragma unroll
            for (int u = 0; u < 8; u++) {
                float4 v = h24[(size_t)sreg[u] * 16 + l];
                ax += v.x; ay += v.y; az += v.z; aw += v.w;
            }
            if (!more) break;
#pragma unroll
            for (int u = 0; u < 8; u++) sreg[u] = sn[u];
            idx += 8;
        }
    }
    for (; idx < e_end; idx++) {
        float4 v0 = h24[(size_t)src_sorted[idx] * 16 + l];
        ax += v0.x; ay += v0.y; az += v0.z; aw += v0.w;
    }
    float dg = (float)(e_end - b);
    if (dg < 1.f) dg = 1.f;
    float inv = 1.f / dg;
    AB4[(size_t)n * 32 + l] = make_float4(ax * inv, ay * inv, az * inv, aw * inv);
    AB4[(size_t)n * 32 + 16 + l] = h24[(size_t)n * 16 + l];
}

// ---- per-graph mean pool ----
__global__ void pool_kernel(const float* __restrict__ h3, const int* __restrict__ goff,
                            float* __restrict__ gmean) {
    __shared__ float red[256];
    int g = blockIdx.x, t = threadIdx.x;
    int c = t & 63, li = t >> 6;
    int b = goff[g], e = goff[g + 1];
    float sum = 0.f;
    for (int r = b + li; r < e; r += 4) sum += h3[(size_t)r * HID + c];
    red[t] = sum;
    __syncthreads();
    if (t < 64) {
        float v = red[t] + red[t + 64] + red[t + 128] + red[t + 192];
        float cntf = (float)(e - b);
        if (cntf < 1.f) cntf = 1.f;
        gmean[g * HID + t] = v / cntf;
    }
}

// ---- final MLP head -> d_out[192] ----
__global__ void mlp_kernel(const float* __restrict__ gmean, const float* __restrict__ lin1W,
                           const float* __restrict__ lin1b, const float* __restrict__ lin2W,
                           const float* __restrict__ lin2b, const float* __restrict__ telW,
                           const float* __restrict__ telb, const float* __restrict__ compW,
                           const float* __restrict__ compb, const float* __restrict__ pchW,
                           const float* __restrict__ pchb, float* __restrict__ out) {
    __shared__ float G[4096], Wb[4096], G1[4096], G2[4096];
    int t = threadIdx.x;
    for (int i = t; i < 4096; i += 256) { G[i] = gmean[i]; Wb[i] = lin1W[i]; }
    __syncthreads();
    int c = t & 63;
    for (int j = 0; j < 16; j++) {
        int r = (t >> 6) + 4 * j;
        float acc = lin1b[c];
        for (int k = 0; k < 64; k++) acc += G[r * 64 + k] * Wb[k * 64 + c];
        G1[r * 64 + c] = eluf(acc);
    }
    __syncthreads();
    for (int i = t; i < 4096; i += 256) Wb[i] = lin2W[i];
    __syncthreads();
    for (int j = 0; j < 16; j++) {
        int r = (t >> 6) + 4 * j;
        float acc = lin2b[c];
        for (int k = 0; k < 64; k++) acc += G1[r * 64 + k] * Wb[k * 64 + c];
        G2[r * 64 + c] = acc;
    }
    __syncthreads();
    if (t < 64) {
        int r = t;
        float a = telb[0], b_ = compb[0], p = pchb[0];
        for (int k = 0; k < 64; k++) {
            float v = G2[r * 64 + k];
            a += v * telW[k];
            b_ += v * compW[k];
            p += v * pchW[k];
        }
        out[r] = a;
        out[64 + r] = b_;
        out[128 + r] = p;
    }
}

extern "C" void kernel_launch(void* const* d_in, const int* in_sizes, int n_in,
                              void* d_out, int out_size, void* d_ws, size_t ws_size,
                              hipStream_t stream) {
    const float* x        = (const float*)d_in[0];
    const float* EA       = (const float*)d_in[1];
    const float* node_emb = (const float*)d_in[2];
    const float* edge_W   = (const float*)d_in[3];
    const float* edge_b   = (const float*)d_in[4];
    const float* W1       = (const float*)d_in[5];
    const float* as1      = (const float*)d_in[6];
    const float* ad1      = (const float*)d_in[7];
    const float* ae1      = (const float*)d_in[8];
    const float* leW1     = (const float*)d_in[9];
    const float* b1       = (const float*)d_in[10];
    const float* W2       = (const float*)d_in[11];
    const float* as2      = (const float*)d_in[12];
    const float* ad2      = (const float*)d_in[13];
    const float* ae2      = (const float*)d_in[14];
    const float* leW2     = (const float*)d_in[15];
    const float* b2       = (const float*)d_in[16];
    const float* sage_Wl  = (const float*)d_in[17];
    const float* sage_bl  = (const float*)d_in[18];
    const float* sage_Wr  = (const float*)d_in[19];
    const float* lin1_W   = (const float*)d_in[20];
    const float* lin1_b   = (const float*)d_in[21];
    const float* lin2_W   = (const float*)d_in[22];
    const float* lin2_b   = (const float*)d_in[23];
    const float* tel_W    = (const float*)d_in[24];
    const float* tel_b    = (const float*)d_in[25];
    const float* comp_W   = (const float*)d_in[26];
    const float* comp_b   = (const float*)d_in[27];
    const float* pch_W    = (const float*)d_in[28];
    const float* pch_b    = (const float*)d_in[29];
    const int* edge_index = (const int*)d_in[30];
    const int* batch      = (const int*)d_in[31];
    const int* node_type  = (const int*)d_in[32];
    float* outp = (float*)d_out;

    const int* srcp = edge_index;
    const int* dstp = edge_index + NE;

    float* wf = (float*)d_ws;
    constexpr size_t OFF_H0    = 0;                               // N*128 (h3 aliases later)
    constexpr size_t OFF_AGG   = OFF_H0 + (size_t)NN * 128;       // N*512 (agg1/agg2/AB alias)
    constexpr size_t OFF_H1    = OFF_AGG + (size_t)NN * 512;      // N*64
    constexpr size_t OFF_H2    = OFF_H1 + (size_t)NN * 64;        // N*64
    constexpr size_t OFF_SC    = OFF_H2 + (size_t)NN * 64;        // E*4
    constexpr size_t OFF_AE2   = OFF_SC + (size_t)NE * 4;         // E*4
    constexpr size_t OFF_AS    = OFF_AE2 + (size_t)NE * 4;        // N*4
    constexpr size_t OFF_AD    = OFF_AS + (size_t)NN * 4;         // N*4
    constexpr size_t OFF_SMALL = OFF_AD + (size_t)NN * 4;         // 4096
    constexpr size_t OFF_GMEAN = OFF_SMALL + 4096;                // 4096
    constexpr size_t OFF_WC1   = OFF_GMEAN + 4096;                // 32768
    constexpr size_t OFF_WC2   = OFF_WC1 + 32768;                 // 16384
    constexpr size_t OFF_B128  = OFF_WC2 + 16384;                 // 8192
    constexpr size_t F_TOTAL   = OFF_B128 + 8192;

    int* wi         = (int*)(wf + F_TOTAL);
    int* cnt        = wi;                        // N
    int* pos        = wi + NN;                   // N   (adjacent: one memset)
    int* eoff       = pos + NN;                  // N+1
    int* src_sorted = eoff + (NN + 1);           // E
    int* goff       = src_sorted + NE;           // NG+1
    int* bsum       = goff + (NG + 1);           // 64
    int* boff       = bsum + 64;                 // 64

    float* h0    = wf + OFF_H0;
    float* aggb  = wf + OFF_AGG;
    float* h1    = wf + OFF_H1;
    float* h2    = wf + OFF_H2;
    float* sc    = wf + OFF_SC;
    float* ae2s  = wf + OFF_AE2;
    float* as_   = wf + OFF_AS;
    float* ad_   = wf + OFF_AD;
    float* S     = wf + OFF_SMALL;
    float* gmean = wf + OFF_GMEAN;
    float* WC1   = wf + OFF_WC1;
    float* WC2   = wf + OFF_WC2;
    float* B128  = wf + OFF_B128;
    float* AB    = wf + OFF_AGG;                 // alias (agg dead after gemm L2)
    float* h3    = wf + OFF_H0;                  // alias (h0 dead after agg L1)

    hipMemsetAsync(S + S_MEANEA, 0, 16 * sizeof(float), stream);
    hipMemsetAsync(cnt, 0, 2 * NN * sizeof(int), stream);   // cnt + pos

    count_mean_kernel<<<(NE + 1023) / 1024, 256, 0, stream>>>(dstp, EA, cnt, S);
    prep_small_kernel<<<1, 256, 0, stream>>>(W1, as1, ad1, ae1, leW1,
                                             W2, as2, ad2, ae2, leW2,
                                             edge_W, edge_b, sage_Wl, sage_Wr,
                                             S, WC1, WC2, B128);
    {
        int nb = (NN + 1023) / 1024;  // 30
        scan_blocks_kernel<<<nb, 1024, 0, stream>>>(cnt, eoff, bsum);
        scan_tops_kernel<<<1, 64, 0, stream>>>(bsum, boff, nb);
        scan_add_kernel<<<(NN + 255) / 256, 256, 0, stream>>>(boff, eoff);
    }
    attn_h0_kernel<<<(NN + 63) / 64, 256, 0, stream>>>(x, node_emb, node_type, S, h0, as_, ad_);
    goff_bs_kernel<<<1, 128, 0, stream>>>(batch, goff);
    scatter_score_kernel<<<(NE + 255) / 256, 256, 0, stream>>>(
        srcp, dstp, EA, S, as_, ad_, eoff, pos, src_sorted, sc, ae2s);

    // ----- GAT layer 1 -----
    agg_gat_kernel<128, false><<<(NN + 3) / 4, 256, 0, stream>>>(
        eoff, src_sorted, sc, h0, as_, ad_, S + S_AEL1, aggb);
    gemm32_kernel<512, true><<<(NN + 31) / 32, 256, 0, stream>>>(
        aggb, WC1, b1, h1, S + S_MS2, S + S_MD2, as_, ad_);

    // ----- GAT layer 2 -----
    agg_gat_kernel<64, true><<<(NN + 3) / 4, 256, 0, stream>>>(
        eoff, src_sorted, ae2s, h1, as_, ad_, S + S_AEL2, aggb);
    gemm32_kernel<256, false><<<(NN + 31) / 32, 256, 0, stream>>>(
        aggb, WC2, b2, h2, nullptr, nullptr, nullptr, nullptr);

    // ----- SAGE -----
    sage_agg3_kernel<<<(NN + 15) / 16, 256, 0, stream>>>(h2, eoff, src_sorted, AB);
    gemm32_kernel<128, false><<<(NN + 31) / 32, 256, 0, stream>>>(
        AB, B128, sage_bl, h3, nullptr, nullptr, nullptr, nullptr);

    // ----- pool + MLP head -----
    pool_kernel<<<NG, 256, 0, stream>>>(h3, goff, gmean);
    mlp_kernel<<<1, 256, 0, stream>>>(gmean, lin1_W, lin1_b, lin2_W, lin2_b,
                                      tel_W, tel_b, comp_W, comp_b, pch_W, pch_b, outp);
}

// Round 6
// 480.249 us; speedup vs baseline: 2.6106x; 1.1646x over previous
//
#include <hip/hip_runtime.h>
#include <math.h>

#define NN 30000          // nodes
#define NE 480000         // edges
#define FEA 16            // edge feature dim
#define HID 64
#define NG 64             // graphs
#define LEAKK 0.2f

// ---- small-constant region layout (float offsets) ----
#define S_MEANEA 0    // 16
#define S_KF1    16   // 64  (K1 [16,4])
#define S_C1     80   // 4
#define S_AEL1   84   // 4
#define S_KF2    88   // 64
#define S_C2     152  // 4
#define S_AEL2   156  // 4
#define S_MS1    160  // 512 (Ms1 [128,4])
#define S_MD1    672  // 512
#define S_MS2    1184 // 256 (Ms2 [64,4])
#define S_MD2    1440 // 256

__device__ __forceinline__ float eluf(float v) { return v > 0.f ? v : expm1f(v); }
__device__ __forceinline__ float leakyf(float v) { return v >= 0.f ? v : LEAKK * v; }
__device__ __forceinline__ void fma4(float4& a, float w, const float4& x) {
    a.x += w * x.x; a.y += w * x.y; a.z += w * x.z; a.w += w * x.w;
}

// ---- count (CSR degree) + mean of edge_attr, one pass over edges ----
__global__ void count_mean_kernel(const int* __restrict__ dst, const float* __restrict__ EA,
                                  int* __restrict__ cnt, float* __restrict__ S) {
    __shared__ float red[256];
    int t = threadIdx.x;
    int base = blockIdx.x * 1024;
#pragma unroll
    for (int i = 0; i < 4; i++) {
        int e = base + i * 256 + t;
        if (e < NE) atomicAdd(&cnt[dst[e]], 1);
    }
    int col = t & 15;
    int rbase = base + (t >> 4);
    float sum = 0.f;
    for (int i = 0; i < 64; i++) {
        int r = rbase + i * 16;
        if (r < NE) sum += EA[(size_t)r * FEA + col];
    }
    red[t] = sum;
    __syncthreads();
    if (t < 16) {
        float v = 0.f;
        for (int j = 0; j < 16; j++) v += red[t + j * 16];
        atomicAdd(&S[S_MEANEA + t], v);
    }
}

// ---- parallel weight-layout build: WC1 (32768) + WC2 (16384) + B128 (8192) ----
__global__ void prep_weights_kernel(const float* __restrict__ W1, const float* __restrict__ W2,
                                    const float* __restrict__ Wl, const float* __restrict__ Wr,
                                    float* __restrict__ WC1, float* __restrict__ WC2,
                                    float* __restrict__ B128) {
    int i = blockIdx.x * 256 + threadIdx.x;
    if (i < 32768) {
        int hk = i >> 6, c = i & 63;
        int h = hk >> 7, k = hk & 127;
        WC1[i] = 0.25f * W1[k * 256 + h * 64 + c];
    } else if (i < 49152) {
        int j = i - 32768;
        int hk = j >> 6, c = j & 63;
        int h = hk >> 6, k = hk & 63;
        WC2[j] = 0.25f * W2[k * 256 + h * 64 + c];
    } else if (i < 57344) {
        int j = i - 49152;
        int k = j >> 6, c = j & 63;
        B128[j] = (k < 64) ? Wl[k * 64 + c] : Wr[(k - 64) * 64 + c];
    }
}

// ---- fold attention weights into small matrices (small work only) ----
__global__ void prep_small_kernel(
    const float* __restrict__ W1, const float* __restrict__ as1, const float* __restrict__ ad1,
    const float* __restrict__ ae1, const float* __restrict__ leW1,
    const float* __restrict__ W2, const float* __restrict__ as2, const float* __restrict__ ad2,
    const float* __restrict__ ae2, const float* __restrict__ leW2,
    const float* __restrict__ edge_W, const float* __restrict__ edge_b,
    float* __restrict__ S) {
    __shared__ float M1[256], M2[256], meh[64];
    int t = threadIdx.x;
    if (t < 16) S[S_MEANEA + t] *= (1.0f / (float)NE);
    __syncthreads();
    {
        int k = t >> 2, h = t & 3;
        float m1 = 0.f, m2 = 0.f;
        for (int c = 0; c < 64; c++) {
            m1 += leW1[k * 256 + h * 64 + c] * ae1[h * 64 + c];
            m2 += leW2[k * 256 + h * 64 + c] * ae2[h * 64 + c];
        }
        M1[t] = m1; M2[t] = m2;
    }
    if (t < 64) {
        float v = edge_b[t];
        for (int f = 0; f < FEA; f++) v += S[S_MEANEA + f] * edge_W[f * 64 + t];
        meh[t] = v;
    }
    __syncthreads();
    if (t < 64) {
        int f = t >> 2, h = t & 3;
        float k1 = 0.f, k2 = 0.f;
        for (int k = 0; k < 64; k++) {
            k1 += edge_W[f * 64 + k] * M1[k * 4 + h];
            k2 += edge_W[f * 64 + k] * M2[k * 4 + h];
        }
        S[S_KF1 + t] = k1; S[S_KF2 + t] = k2;
    } else if (t < 68) {
        int h = t - 64;
        float c1 = 0.f, c2 = 0.f, a1 = 0.f, a2 = 0.f;
        for (int k = 0; k < 64; k++) {
            c1 += edge_b[k] * M1[k * 4 + h];
            c2 += edge_b[k] * M2[k * 4 + h];
            a1 += meh[k] * M1[k * 4 + h];
            a2 += meh[k] * M2[k * 4 + h];
        }
        S[S_C1 + h] = c1; S[S_C2 + h] = c2;
        S[S_AEL1 + h] = a1; S[S_AEL2 + h] = a2;
    }
    for (int i = t; i < 512; i += 256) {
        int k = i >> 2, h = i & 3;
        float s = 0.f, d = 0.f;
        for (int c = 0; c < 64; c++) {
            float w = W1[k * 256 + h * 64 + c];
            s += w * as1[h * 64 + c];
            d += w * ad1[h * 64 + c];
        }
        S[S_MS1 + i] = s; S[S_MD1 + i] = d;
    }
    for (int i = t; i < 256; i += 256) {
        int k = i >> 2, h = i & 3;
        float s = 0.f, d = 0.f;
        for (int c = 0; c < 64; c++) {
            float w = W2[k * 256 + h * 64 + c];
            s += w * as2[h * 64 + c];
            d += w * ad2[h * 64 + c];
        }
        S[S_MS2 + i] = s; S[S_MD2 + i] = d;
    }
}

// ---- build h0 = concat(x, emb[type]) AND compute layer-1 a_s/a_d ----
__global__ __launch_bounds__(256) void attn_h0_kernel(
    const float* __restrict__ x, const float* __restrict__ node_emb,
    const int* __restrict__ node_type, const float* __restrict__ S,
    float* __restrict__ h0, float* __restrict__ as_, float* __restrict__ ad_) {
    __shared__ float xt[64 * 132];
    __shared__ float ms[512], md[512];
    __shared__ int ntS[64];
    int t = threadIdx.x;
    int n0 = blockIdx.x * 64;
    if (t < 64) {
        int n = n0 + t;
        ntS[t] = (n < NN) ? node_type[n] : 0;
    }
    for (int i = t; i < 512; i += 256) { ms[i] = S[S_MS1 + i]; md[i] = S[S_MD1 + i]; }
    __syncthreads();
    for (int i = t; i < 1024; i += 256) {
        int r = i >> 4, c4 = (i & 15) * 4;
        int n = n0 + r;
        float4 f = {0, 0, 0, 0};
        if (n < NN) f = *(const float4*)(x + (size_t)n * 64 + c4);
        *(float4*)&xt[r * 132 + c4] = f;
    }
    for (int i = t; i < 1024; i += 256) {
        int r = i >> 4, c4 = (i & 15) * 4;
        int n = n0 + r;
        float4 f = {0, 0, 0, 0};
        if (n < NN) f = *(const float4*)(node_emb + (size_t)ntS[r] * 64 + c4);
        *(float4*)&xt[r * 132 + 64 + c4] = f;
    }
    __syncthreads();
    for (int i = t; i < 2048; i += 256) {
        int r = i >> 5, c4 = (i & 31) * 4;
        int n = n0 + r;
        if (n < NN) *(float4*)(h0 + (size_t)n * 128 + c4) = *(const float4*)&xt[r * 132 + c4];
    }
    int r = t >> 2, h = t & 3;
    float s = 0.f, d = 0.f;
#pragma unroll 8
    for (int k = 0; k < 128; k++) {
        float xv = xt[r * 132 + k];
        s += xv * ms[k * 4 + h];
        d += xv * md[k * 4 + h];
    }
    int n = n0 + r;
    if (n < NN) { as_[n * 4 + h] = s; ad_[n * 4 + h] = d; }
}

// ---- 3-kernel decoupled scan ----
__global__ void scan_blocks_kernel(const int* __restrict__ cnt, int* __restrict__ eoff,
                                   int* __restrict__ bsum) {
    __shared__ int wsum[16];
    int t = threadIdx.x;
    int i = blockIdx.x * 1024 + t;
    int v = (i < NN) ? cnt[i] : 0;
    int lane = t & 63;
    int incl = v;
#pragma unroll
    for (int ofs = 1; ofs < 64; ofs <<= 1) {
        int u = __shfl_up(incl, ofs, 64);
        if (lane >= ofs) incl += u;
    }
    int wid = t >> 6;
    if (lane == 63) wsum[wid] = incl;
    __syncthreads();
    if (t < 16) {
        int s = wsum[t];
#pragma unroll
        for (int ofs = 1; ofs < 16; ofs <<= 1) {
            int u = __shfl_up(s, ofs, 64);
            if (t >= ofs) s += u;
        }
        wsum[t] = s;
    }
    __syncthreads();
    int excl = incl - v + (wid > 0 ? wsum[wid - 1] : 0);
    if (i < NN) eoff[i] = excl;
    if (t == 1023) bsum[blockIdx.x] = excl + v;
}

__global__ void scan_tops_kernel(const int* __restrict__ bsum, int* __restrict__ boff, int nb) {
    int t = threadIdx.x; // 64
    int v = (t < nb) ? bsum[t] : 0;
    int incl = v;
#pragma unroll
    for (int ofs = 1; ofs < 64; ofs <<= 1) {
        int u = __shfl_up(incl, ofs, 64);
        if (t >= ofs) incl += u;
    }
    boff[t] = incl - v;
}

__global__ void scan_add_kernel(const int* __restrict__ boff, int* __restrict__ eoff) {
    int i = blockIdx.x * 256 + threadIdx.x;
    if (i < NN) eoff[i] += boff[i >> 10];
    if (i == 0) eoff[NN] = NE;
}

// ---- fused scatter + scoring ----
__global__ void scatter_score_kernel(const int* __restrict__ src, const int* __restrict__ dst,
                                     const float* __restrict__ EA, const float* __restrict__ S,
                                     const float* __restrict__ as_, const float* __restrict__ ad_,
                                     const int* __restrict__ eoff, int* __restrict__ pos,
                                     int* __restrict__ src_sorted,
                                     float* __restrict__ sc1, float* __restrict__ ae2s) {
    int e = blockIdx.x * 256 + threadIdx.x;
    if (e >= NE) return;
    int s = src[e], d = dst[e];
    float a1[4], a2[4];
#pragma unroll
    for (int h = 0; h < 4; h++) { a1[h] = S[S_C1 + h]; a2[h] = S[S_C2 + h]; }
    const float4* EA4 = (const float4*)(EA + (size_t)e * FEA);
#pragma unroll
    for (int q = 0; q < 4; q++) {
        float4 v = EA4[q];
        float vv[4] = {v.x, v.y, v.z, v.w};
#pragma unroll
        for (int j = 0; j < 4; j++) {
            int f = q * 4 + j;
#pragma unroll
            for (int h = 0; h < 4; h++) {
                a1[h] += vv[j] * S[S_KF1 + f * 4 + h];
                a2[h] += vv[j] * S[S_KF2 + f * 4 + h];
            }
        }
    }
    int p = atomicAdd(&pos[d], 1);
    int idx = eoff[d] + p;
    src_sorted[idx] = s;
    ((float4*)ae2s)[idx] = make_float4(a2[0], a2[1], a2[2], a2[3]);
    float4 asv = ((const float4*)as_)[s];
    float4 adv = ((const float4*)ad_)[d];
    float4 r;
    r.x = expf(leakyf(asv.x + adv.x + a1[0]));
    r.y = expf(leakyf(asv.y + adv.y + a1[1]));
    r.z = expf(leakyf(asv.z + adv.z + a1[2]));
    r.w = expf(leakyf(asv.w + adv.w + a1[3]));
    ((float4*)sc1)[idx] = r;
}

// ---- goff via binary search over sorted batch ----
__global__ void goff_bs_kernel(const int* __restrict__ batch, int* __restrict__ goff) {
    int g = threadIdx.x;
    if (g > NG) return;
    int lo = 0, hi = NN;
    while (lo < hi) {
        int mid = (lo + hi) >> 1;
        if (batch[mid] < g) lo = mid + 1; else hi = mid;
    }
    goff[g] = lo;
}

// ---- GAT aggregate-first ----
template <int KD, bool CW>
__global__ __launch_bounds__(256) void agg_gat_kernel(
    const int* __restrict__ eoff, const int* __restrict__ src_sorted,
    const float* __restrict__ wsrc, const float* __restrict__ X,
    const float* __restrict__ as_, const float* __restrict__ ad_,
    const float* __restrict__ Sael, float* __restrict__ agg) {
    constexpr int CHUNKS = KD / 4;
    constexpr int EPW = 64 / CHUNKS;
    int n = blockIdx.x * 4 + (threadIdx.x >> 6);
    if (n >= NN) return;
    int lane = threadIdx.x & 63;
    int sub = lane / CHUNKS;
    int ch = lane % CHUNKS;
    const float4* X4 = (const float4*)X;
    const float4* W4 = (const float4*)wsrc;
    const float4* AS4 = (const float4*)as_;
    float4 asn = AS4[n];
    float4 adn = ((const float4*)ad_)[n];
    float4 a0 = {0, 0, 0, 0}, a1 = a0, a2 = a0, a3 = a0, dn = a0;
    int b = eoff[n], e = eoff[n + 1];
    int nE = e - b;
    int i = sub;
    for (; i + EPW < nE; i += 2 * EPW) {
        int idx0 = b + i, idx1 = b + i + EPW;
        int s0 = src_sorted[idx0], s1 = src_sorted[idx1];
        float4 w0 = W4[idx0], w1 = W4[idx1];
        if (CW) {
            float4 q0 = AS4[s0], q1 = AS4[s1];
            w0.x = expf(leakyf(q0.x + adn.x + w0.x));
            w0.y = expf(leakyf(q0.y + adn.y + w0.y));
            w0.z = expf(leakyf(q0.z + adn.z + w0.z));
            w0.w = expf(leakyf(q0.w + adn.w + w0.w));
            w1.x = expf(leakyf(q1.x + adn.x + w1.x));
            w1.y = expf(leakyf(q1.y + adn.y + w1.y));
            w1.z = expf(leakyf(q1.z + adn.z + w1.z));
            w1.w = expf(leakyf(q1.w + adn.w + w1.w));
        }
        float4 x0 = X4[(size_t)s0 * CHUNKS + ch];
        float4 x1 = X4[(size_t)s1 * CHUNKS + ch];
        fma4(a0, w0.x, x0); fma4(a1, w0.y, x0); fma4(a2, w0.z, x0); fma4(a3, w0.w, x0);
        fma4(a0, w1.x, x1); fma4(a1, w1.y, x1); fma4(a2, w1.z, x1); fma4(a3, w1.w, x1);
        dn.x += w0.x + w1.x; dn.y += w0.y + w1.y;
        dn.z += w0.z + w1.z; dn.w += w0.w + w1.w;
    }
    for (; i < nE; i += EPW) {
        int idx0 = b + i;
        int s0 = src_sorted[idx0];
        float4 w0 = W4[idx0];
        if (CW) {
            float4 q0 = AS4[s0];
            w0.x = expf(leakyf(q0.x + adn.x + w0.x));
            w0.y = expf(leakyf(q0.y + adn.y + w0.y));
            w0.z = expf(leakyf(q0.z + adn.z + w0.z));
            w0.w = expf(leakyf(q0.w + adn.w + w0.w));
        }
        float4 x0 = X4[(size_t)s0 * CHUNKS + ch];
        fma4(a0, w0.x, x0); fma4(a1, w0.y, x0); fma4(a2, w0.z, x0); fma4(a3, w0.w, x0);
        dn.x += w0.x; dn.y += w0.y; dn.z += w0.z; dn.w += w0.w;
    }
    if (sub == 0) {  // self loop
        float e0 = expf(leakyf(asn.x + adn.x + Sael[0]));
        float e1 = expf(leakyf(asn.y + adn.y + Sael[1]));
        float e2 = expf(leakyf(asn.z + adn.z + Sael[2]));
        float e3 = expf(leakyf(asn.w + adn.w + Sael[3]));
        float4 xs = X4[(size_t)n * CHUNKS + ch];
        fma4(a0, e0, xs); fma4(a1, e1, xs); fma4(a2, e2, xs); fma4(a3, e3, xs);
        dn.x += e0; dn.y += e1; dn.z += e2; dn.w += e3;
    }
#pragma unroll
    for (int mask = CHUNKS; mask < 64; mask <<= 1) {
        a0.x += __shfl_xor(a0.x, mask, 64); a0.y += __shfl_xor(a0.y, mask, 64);
        a0.z += __shfl_xor(a0.z, mask, 64); a0.w += __shfl_xor(a0.w, mask, 64);
        a1.x += __shfl_xor(a1.x, mask, 64); a1.y += __shfl_xor(a1.y, mask, 64);
        a1.z += __shfl_xor(a1.z, mask, 64); a1.w += __shfl_xor(a1.w, mask, 64);
        a2.x += __shfl_xor(a2.x, mask, 64); a2.y += __shfl_xor(a2.y, mask, 64);
        a2.z += __shfl_xor(a2.z, mask, 64); a2.w += __shfl_xor(a2.w, mask, 64);
        a3.x += __shfl_xor(a3.x, mask, 64); a3.y += __shfl_xor(a3.y, mask, 64);
        a3.z += __shfl_xor(a3.z, mask, 64); a3.w += __shfl_xor(a3.w, mask, 64);
        dn.x += __shfl_xor(dn.x, mask, 64); dn.y += __shfl_xor(dn.y, mask, 64);
        dn.z += __shfl_xor(dn.z, mask, 64); dn.w += __shfl_xor(dn.w, mask, 64);
    }
    if (sub == 0) {
        float i0 = 1.f / dn.x, i1 = 1.f / dn.y, i2 = 1.f / dn.z, i3 = 1.f / dn.w;
        float4* agg4 = (float4*)agg;
        size_t base = (size_t)n * 4 * CHUNKS + ch;
        agg4[base]              = make_float4(a0.x * i0, a0.y * i0, a0.z * i0, a0.w * i0);
        agg4[base + CHUNKS]     = make_float4(a1.x * i1, a1.y * i1, a1.z * i1, a1.w * i1);
        agg4[base + 2 * CHUNKS] = make_float4(a2.x * i2, a2.y * i2, a2.z * i2, a2.w * i2);
        agg4[base + 3 * CHUNKS] = make_float4(a3.x * i3, a3.y * i3, a3.z * i3, a3.w * i3);
    }
}

// ---- thin GEMM: out[M,64] = elu(A[M,K]@B[K,64]+bias); 32-row tiles ----
template <int K, bool DOATT>
__global__ __launch_bounds__(256) void gemm32_kernel(
    const float* __restrict__ A, const float* __restrict__ B,
    const float* __restrict__ bias, float* __restrict__ out,
    const float* __restrict__ ms_g, const float* __restrict__ md_g,
    float* __restrict__ as_, float* __restrict__ ad_) {
    __shared__ float As[32 * 34];
    __shared__ float Bs[32 * 68];
    __shared__ float msS[256], mdS[256];
    int t = threadIdx.x;
    int tx = t & 15, ty = t >> 4;
    int m_base = blockIdx.x * 32;
    if (DOATT) { msS[t] = ms_g[t]; mdS[t] = md_g[t]; }
    float acc[2][4] = {};
    for (int k0 = 0; k0 < K; k0 += 32) {
        {
            int row = t >> 3, kq = (t & 7) * 4;
            int m = m_base + row;
            float4 f = {0, 0, 0, 0};
            if (m < NN) f = *(const float4*)(A + (size_t)m * K + k0 + kq);
            As[(kq + 0) * 34 + row] = f.x;
            As[(kq + 1) * 34 + row] = f.y;
            As[(kq + 2) * 34 + row] = f.z;
            As[(kq + 3) * 34 + row] = f.w;
        }
        {
            int kr = t >> 4, nc = (t & 15) * 4;
            *(float4*)&Bs[kr * 68 + nc] = *(const float4*)(B + (size_t)(k0 + kr) * 64 + nc);
            *(float4*)&Bs[(kr + 16) * 68 + nc] =
                *(const float4*)(B + (size_t)(k0 + kr + 16) * 64 + nc);
        }
        __syncthreads();
#pragma unroll
        for (int k = 0; k < 32; k++) {
            float a0 = As[k * 34 + ty * 2];
            float a1v = As[k * 34 + ty * 2 + 1];
            float4 bv = *(const float4*)&Bs[k * 68 + tx * 4];
            acc[0][0] += a0 * bv.x;  acc[0][1] += a0 * bv.y;
            acc[0][2] += a0 * bv.z;  acc[0][3] += a0 * bv.w;
            acc[1][0] += a1v * bv.x; acc[1][1] += a1v * bv.y;
            acc[1][2] += a1v * bv.z; acc[1][3] += a1v * bv.w;
        }
        __syncthreads();
    }
    float4 bvv = ((const float4*)bias)[tx];
    float o[2][4];
#pragma unroll
    for (int i = 0; i < 2; i++) {
        o[i][0] = eluf(acc[i][0] + bvv.x);
        o[i][1] = eluf(acc[i][1] + bvv.y);
        o[i][2] = eluf(acc[i][2] + bvv.z);
        o[i][3] = eluf(acc[i][3] + bvv.w);
        int m = m_base + ty * 2 + i;
        if (m < NN)
            *(float4*)(out + (size_t)m * 64 + tx * 4) =
                make_float4(o[i][0], o[i][1], o[i][2], o[i][3]);
    }
    if (DOATT) {
#pragma unroll
        for (int i = 0; i < 2; i++) {
            float ps[4] = {0, 0, 0, 0}, pd[4] = {0, 0, 0, 0};
#pragma unroll
            for (int j = 0; j < 4; j++) {
                float v = o[i][j];
                int kk = (tx * 4 + j) * 4;
#pragma unroll
                for (int h = 0; h < 4; h++) {
                    ps[h] += v * msS[kk + h];
                    pd[h] += v * mdS[kk + h];
                }
            }
#pragma unroll
            for (int mk = 1; mk < 16; mk <<= 1) {
#pragma unroll
                for (int h = 0; h < 4; h++) {
                    ps[h] += __shfl_xor(ps[h], mk, 64);
                    pd[h] += __shfl_xor(pd[h], mk, 64);
                }
            }
            int m = m_base + ty * 2 + i;
            if (tx == 0 && m < NN) {
                *(float4*)(as_ + (size_t)m * 4) = make_float4(ps[0], ps[1], ps[2], ps[3]);
                *(float4*)(ad_ + (size_t)m * 4) = make_float4(pd[0], pd[1], pd[2], pd[3]);
            }
        }
    }
}

// ---- SAGE mean aggregation into AB[:,0:64]; copy h2 into AB[:,64:128] ----
__global__ __launch_bounds__(256) void sage_agg3_kernel(
    const float* __restrict__ h2, const int* __restrict__ eoff,
    const int* __restrict__ src_sorted, float* __restrict__ AB) {
    int n = blockIdx.x * 16 + (threadIdx.x >> 4);
    if (n >= NN) return;
    int l = threadIdx.x & 15;
    const float4* h24 = (const float4*)h2;
    float4* AB4 = (float4*)AB;
    float ax = 0.f, ay = 0.f, az = 0.f, aw = 0.f;
    int b = eoff[n], e_end = eoff[n + 1];
    int idx = b;
    int stop = b + ((e_end - b) & ~7);
    if (idx < stop) {
        int sreg[8];
#pragma unroll
        for (int u = 0; u < 8; u++) sreg[u] = src_sorted[idx + u];
        idx += 8;
        while (true) {
            int sn[8];
            bool more = idx < stop;
            if (more) {
#pragma unroll
                for (int u = 0; u < 8; u++) sn[u] = src_sorted[idx + u];
            }
#pragma unroll
            for (int u = 0; u < 8; u++) {
                float4 v = h24[(size_t)sreg[u] * 16 + l];
                ax += v.x; ay += v.y; az += v.z; aw += v.w;
            }
            if (!more) break;
#pragma unroll
            for (int u = 0; u < 8; u++) sreg[u] = sn[u];
            idx += 8;
        }
    }
    for (; idx < e_end; idx++) {
        float4 v0 = h24[(size_t)src_sorted[idx] * 16 + l];
        ax += v0.x; ay += v0.y; az += v0.z; aw += v0.w;
    }
    float dg = (float)(e_end - b);
    if (dg < 1.f) dg = 1.f;
    float inv = 1.f / dg;
    AB4[(size_t)n * 32 + l] = make_float4(ax * inv, ay * inv, az * inv, aw * inv);
    AB4[(size_t)n * 32 + 16 + l] = h24[(size_t)n * 16 + l];
}

// ---- fused pool + MLP head: one block per graph -> d_out[192] ----
__global__ __launch_bounds__(256) void pool_mlp_kernel(
    const float* __restrict__ h3, const int* __restrict__ goff,
    const float* __restrict__ lin1W, const float* __restrict__ lin1b,
    const float* __restrict__ lin2W, const float* __restrict__ lin2b,
    const float* __restrict__ telW, const float* __restrict__ telb,
    const float* __restrict__ compW, const float* __restrict__ compb,
    const float* __restrict__ pchW, const float* __restrict__ pchb,
    float* __restrict__ out) {
    __shared__ float red[256];
    __shared__ float g[64], G1[64], G2[64];
    int gi = blockIdx.x, t = threadIdx.x;
    int c = t & 63, li = t >> 6;
    int b = goff[gi], e = goff[gi + 1];
    float sum = 0.f;
    for (int r = b + li; r < e; r += 4) sum += h3[(size_t)r * HID + c];
    red[t] = sum;
    __syncthreads();
    if (t < 64) {
        float v = red[t] + red[t + 64] + red[t + 128] + red[t + 192];
        float cntf = (float)(e - b);
        if (cntf < 1.f) cntf = 1.f;
        g[t] = v / cntf;
    }
    __syncthreads();
    {   // G1 = elu(g @ lin1W + lin1b)
        float part = 0.f;
#pragma unroll
        for (int k = li * 16; k < li * 16 + 16; k++) part += g[k] * lin1W[k * 64 + c];
        red[t] = part;
        __syncthreads();
        if (t < 64)
            G1[c] = eluf(red[c] + red[c + 64] + red[c + 128] + red[c + 192] + lin1b[c]);
        __syncthreads();
    }
    {   // G2 = G1 @ lin2W + lin2b
        float part = 0.f;
#pragma unroll
        for (int k = li * 16; k < li * 16 + 16; k++) part += G1[k] * lin2W[k * 64 + c];
        red[t] = part;
        __syncthreads();
        if (t < 64)
            G2[c] = red[c] + red[c + 64] + red[c + 128] + red[c + 192] + lin2b[c];
        __syncthreads();
    }
    if (t < 192) {
        int h = t >> 6, k = t & 63;
        const float* W = (h == 0) ? telW : ((h == 1) ? compW : pchW);
        red[t] = G2[k] * W[k];
    }
    __syncthreads();
    if (t < 3) {
        float acc = 0.f;
        for (int k = 0; k < 64; k++) acc += red[t * 64 + k];
        float bb = (t == 0) ? telb[0] : ((t == 1) ? compb[0] : pchb[0]);
        out[t * 64 + gi] = acc + bb;
    }
}

extern "C" void kernel_launch(void* const* d_in, const int* in_sizes, int n_in,
                              void* d_out, int out_size, void* d_ws, size_t ws_size,
                              hipStream_t stream) {
    const float* x        = (const float*)d_in[0];
    const float* EA       = (const float*)d_in[1];
    const float* node_emb = (const float*)d_in[2];
    const float* edge_W   = (const float*)d_in[3];
    const float* edge_b   = (const float*)d_in[4];
    const float* W1       = (const float*)d_in[5];
    const float* as1      = (const float*)d_in[6];
    const float* ad1      = (const float*)d_in[7];
    const float* ae1      = (const float*)d_in[8];
    const float* leW1     = (const float*)d_in[9];
    const float* b1       = (const float*)d_in[10];
    const float* W2       = (const float*)d_in[11];
    const float* as2      = (const float*)d_in[12];
    const float* ad2      = (const float*)d_in[13];
    const float* ae2      = (const float*)d_in[14];
    const float* leW2     = (const float*)d_in[15];
    const float* b2       = (const float*)d_in[16];
    const float* sage_Wl  = (const float*)d_in[17];
    const float* sage_bl  = (const float*)d_in[18];
    const float* sage_Wr  = (const float*)d_in[19];
    const float* lin1_W   = (const float*)d_in[20];
    const float* lin1_b   = (const float*)d_in[21];
    const float* lin2_W   = (const float*)d_in[22];
    const float* lin2_b   = (const float*)d_in[23];
    const float* tel_W    = (const float*)d_in[24];
    const float* tel_b    = (const float*)d_in[25];
    const float* comp_W   = (const float*)d_in[26];
    const float* comp_b   = (const float*)d_in[27];
    const float* pch_W    = (const float*)d_in[28];
    const float* pch_b    = (const float*)d_in[29];
    const int* edge_index = (const int*)d_in[30];
    const int* batch      = (const int*)d_in[31];
    const int* node_type  = (const int*)d_in[32];
    float* outp = (float*)d_out;

    const int* srcp = edge_index;
    const int* dstp = edge_index + NE;

    float* wf = (float*)d_ws;
    constexpr size_t OFF_H0    = 0;                               // N*128 (h3 aliases later)
    constexpr size_t OFF_AGG   = OFF_H0 + (size_t)NN * 128;       // N*512 (agg1/agg2/AB alias)
    constexpr size_t OFF_H1    = OFF_AGG + (size_t)NN * 512;      // N*64
    constexpr size_t OFF_H2    = OFF_H1 + (size_t)NN * 64;        // N*64
    constexpr size_t OFF_SC    = OFF_H2 + (size_t)NN * 64;        // E*4
    constexpr size_t OFF_AE2   = OFF_SC + (size_t)NE * 4;         // E*4
    constexpr size_t OFF_AS    = OFF_AE2 + (size_t)NE * 4;        // N*4
    constexpr size_t OFF_AD    = OFF_AS + (size_t)NN * 4;         // N*4
    constexpr size_t OFF_SMALL = OFF_AD + (size_t)NN * 4;         // 4096
    constexpr size_t OFF_WC1   = OFF_SMALL + 4096;                // 32768
    constexpr size_t OFF_WC2   = OFF_WC1 + 32768;                 // 16384
    constexpr size_t OFF_B128  = OFF_WC2 + 16384;                 // 8192
    constexpr size_t F_TOTAL   = OFF_B128 + 8192;

    int* wi         = (int*)(wf + F_TOTAL);
    int* cnt        = wi;                        // N
    int* pos        = wi + NN;                   // N   (adjacent: one memset)
    int* eoff       = pos + NN;                  // N+1
    int* src_sorted = eoff + (NN + 1);           // E
    int* goff       = src_sorted + NE;           // NG+1
    int* bsum       = goff + (NG + 1);           // 64
    int* boff       = bsum + 64;                 // 64

    float* h0    = wf + OFF_H0;
    float* aggb  = wf + OFF_AGG;
    float* h1    = wf + OFF_H1;
    float* h2    = wf + OFF_H2;
    float* sc    = wf + OFF_SC;
    float* ae2s  = wf + OFF_AE2;
    float* as_   = wf + OFF_AS;
    float* ad_   = wf + OFF_AD;
    float* S     = wf + OFF_SMALL;
    float* WC1   = wf + OFF_WC1;
    float* WC2   = wf + OFF_WC2;
    float* B128  = wf + OFF_B128;
    float* AB    = wf + OFF_AGG;                 // alias (agg dead after gemm L2)
    float* h3    = wf + OFF_H0;                  // alias (h0 dead after agg L1)

    hipMemsetAsync(S + S_MEANEA, 0, 16 * sizeof(float), stream);
    hipMemsetAsync(cnt, 0, 2 * NN * sizeof(int), stream);   // cnt + pos

    count_mean_kernel<<<(NE + 1023) / 1024, 256, 0, stream>>>(dstp, EA, cnt, S);
    prep_weights_kernel<<<224, 256, 0, stream>>>(W1, W2, sage_Wl, sage_Wr, WC1, WC2, B128);
    prep_small_kernel<<<1, 256, 0, stream>>>(W1, as1, ad1, ae1, leW1,
                                             W2, as2, ad2, ae2, leW2,
                                             edge_W, edge_b, S);
    {
        int nb = (NN + 1023) / 1024;  // 30
        scan_blocks_kernel<<<nb, 1024, 0, stream>>>(cnt, eoff, bsum);
        scan_tops_kernel<<<1, 64, 0, stream>>>(bsum, boff, nb);
        scan_add_kernel<<<(NN + 255) / 256, 256, 0, stream>>>(boff, eoff);
    }
    attn_h0_kernel<<<(NN + 63) / 64, 256, 0, stream>>>(x, node_emb, node_type, S, h0, as_, ad_);
    goff_bs_kernel<<<1, 128, 0, stream>>>(batch, goff);
    scatter_score_kernel<<<(NE + 255) / 256, 256, 0, stream>>>(
        srcp, dstp, EA, S, as_, ad_, eoff, pos, src_sorted, sc, ae2s);

    // ----- GAT layer 1 -----
    agg_gat_kernel<128, false><<<(NN + 3) / 4, 256, 0, stream>>>(
        eoff, src_sorted, sc, h0, as_, ad_, S + S_AEL1, aggb);
    gemm32_kernel<512, true><<<(NN + 31) / 32, 256, 0, stream>>>(
        aggb, WC1, b1, h1, S + S_MS2, S + S_MD2, as_, ad_);

    // ----- GAT layer 2 -----
    agg_gat_kernel<64, true><<<(NN + 3) / 4, 256, 0, stream>>>(
        eoff, src_sorted, ae2s, h1, as_, ad_, S + S_AEL2, aggb);
    gemm32_kernel<256, false><<<(NN + 31) / 32, 256, 0, stream>>>(
        aggb, WC2, b2, h2, nullptr, nullptr, nullptr, nullptr);

    // ----- SAGE -----
    sage_agg3_kernel<<<(NN + 15) / 16, 256, 0, stream>>>(h2, eoff, src_sorted, AB);
    gemm32_kernel<128, false><<<(NN + 31) / 32, 256, 0, stream>>>(
        AB, B128, sage_bl, h3, nullptr, nullptr, nullptr, nullptr);

    // ----- fused pool + MLP head -----
    pool_mlp_kernel<<<NG, 256, 0, stream>>>(h3, goff, lin1_W, lin1_b, lin2_W, lin2_b,
                                            tel_W, tel_b, comp_W, comp_b, pch_W, pch_b, outp);
}

// Round 7
// 479.395 us; speedup vs baseline: 2.6153x; 1.0018x over previous
//
#include <hip/hip_runtime.h>
#include <math.h>

#define NN 30000          // nodes
#define NE 480000         // edges
#define FEA 16            // edge feature dim
#define HID 64
#define NG 64             // graphs
#define LEAKK 0.2f

// ---- small-constant region layout (float offsets) ----
#define S_MEANEA 0    // 16
#define S_KF1    16   // 64  (K1 [16,4])
#define S_C1     80   // 4
#define S_AEL1   84   // 4
#define S_KF2    88   // 64
#define S_C2     152  // 4
#define S_AEL2   156  // 4
#define S_MS1    160  // 512 (Ms1 [128,4])
#define S_MD1    672  // 512
#define S_MS2    1184 // 256 (Ms2 [64,4])
#define S_MD2    1440 // 256

__device__ __forceinline__ float eluf(float v) { return v > 0.f ? v : expm1f(v); }
__device__ __forceinline__ float leakyf(float v) { return v >= 0.f ? v : LEAKK * v; }
__device__ __forceinline__ void fma4(float4& a, float w, const float4& x) {
    a.x += w * x.x; a.y += w * x.y; a.z += w * x.z; a.w += w * x.w;
}

// ---- count (CSR degree) + mean of edge_attr, one pass over edges ----
__global__ void count_mean_kernel(const int* __restrict__ dst, const float* __restrict__ EA,
                                  int* __restrict__ cnt, float* __restrict__ S) {
    __shared__ float red[256];
    int t = threadIdx.x;
    int base = blockIdx.x * 1024;
#pragma unroll
    for (int i = 0; i < 4; i++) {
        int e = base + i * 256 + t;
        if (e < NE) atomicAdd(&cnt[dst[e]], 1);
    }
    int col = t & 15;
    int rbase = base + (t >> 4);
    float sum = 0.f;
    for (int i = 0; i < 64; i++) {
        int r = rbase + i * 16;
        if (r < NE) sum += EA[(size_t)r * FEA + col];
    }
    red[t] = sum;
    __syncthreads();
    if (t < 16) {
        float v = 0.f;
        for (int j = 0; j < 16; j++) v += red[t + j * 16];
        atomicAdd(&S[S_MEANEA + t], v);
    }
}

// ---- parallel weight-layout build ----
__global__ void prep_weights_kernel(const float* __restrict__ W1, const float* __restrict__ W2,
                                    const float* __restrict__ Wl, const float* __restrict__ Wr,
                                    float* __restrict__ WC1, float* __restrict__ WC2,
                                    float* __restrict__ B128) {
    int i = blockIdx.x * 256 + threadIdx.x;
    if (i < 32768) {
        int hk = i >> 6, c = i & 63;
        int h = hk >> 7, k = hk & 127;
        WC1[i] = 0.25f * W1[k * 256 + h * 64 + c];
    } else if (i < 49152) {
        int j = i - 32768;
        int hk = j >> 6, c = j & 63;
        int h = hk >> 6, k = hk & 63;
        WC2[j] = 0.25f * W2[k * 256 + h * 64 + c];
    } else if (i < 57344) {
        int j = i - 49152;
        int k = j >> 6, c = j & 63;
        B128[j] = (k < 64) ? Wl[k * 64 + c] : Wr[(k - 64) * 64 + c];
    }
}

// ---- fold attention weights into small matrices ----
__global__ void prep_small_kernel(
    const float* __restrict__ W1, const float* __restrict__ as1, const float* __restrict__ ad1,
    const float* __restrict__ ae1, const float* __restrict__ leW1,
    const float* __restrict__ W2, const float* __restrict__ as2, const float* __restrict__ ad2,
    const float* __restrict__ ae2, const float* __restrict__ leW2,
    const float* __restrict__ edge_W, const float* __restrict__ edge_b,
    float* __restrict__ S) {
    __shared__ float M1[256], M2[256], meh[64];
    int t = threadIdx.x;
    if (t < 16) S[S_MEANEA + t] *= (1.0f / (float)NE);
    __syncthreads();
    {
        int k = t >> 2, h = t & 3;
        float m1 = 0.f, m2 = 0.f;
        for (int c = 0; c < 64; c++) {
            m1 += leW1[k * 256 + h * 64 + c] * ae1[h * 64 + c];
            m2 += leW2[k * 256 + h * 64 + c] * ae2[h * 64 + c];
        }
        M1[t] = m1; M2[t] = m2;
    }
    if (t < 64) {
        float v = edge_b[t];
        for (int f = 0; f < FEA; f++) v += S[S_MEANEA + f] * edge_W[f * 64 + t];
        meh[t] = v;
    }
    __syncthreads();
    if (t < 64) {
        int f = t >> 2, h = t & 3;
        float k1 = 0.f, k2 = 0.f;
        for (int k = 0; k < 64; k++) {
            k1 += edge_W[f * 64 + k] * M1[k * 4 + h];
            k2 += edge_W[f * 64 + k] * M2[k * 4 + h];
        }
        S[S_KF1 + t] = k1; S[S_KF2 + t] = k2;
    } else if (t < 68) {
        int h = t - 64;
        float c1 = 0.f, c2 = 0.f, a1 = 0.f, a2 = 0.f;
        for (int k = 0; k < 64; k++) {
            c1 += edge_b[k] * M1[k * 4 + h];
            c2 += edge_b[k] * M2[k * 4 + h];
            a1 += meh[k] * M1[k * 4 + h];
            a2 += meh[k] * M2[k * 4 + h];
        }
        S[S_C1 + h] = c1; S[S_C2 + h] = c2;
        S[S_AEL1 + h] = a1; S[S_AEL2 + h] = a2;
    }
    for (int i = t; i < 512; i += 256) {
        int k = i >> 2, h = i & 3;
        float s = 0.f, d = 0.f;
        for (int c = 0; c < 64; c++) {
            float w = W1[k * 256 + h * 64 + c];
            s += w * as1[h * 64 + c];
            d += w * ad1[h * 64 + c];
        }
        S[S_MS1 + i] = s; S[S_MD1 + i] = d;
    }
    for (int i = t; i < 256; i += 256) {
        int k = i >> 2, h = i & 3;
        float s = 0.f, d = 0.f;
        for (int c = 0; c < 64; c++) {
            float w = W2[k * 256 + h * 64 + c];
            s += w * as2[h * 64 + c];
            d += w * ad2[h * 64 + c];
        }
        S[S_MS2 + i] = s; S[S_MD2 + i] = d;
    }
}

// ---- build h0 = concat(x, emb[type]) AND compute layer-1 a_s/a_d ----
__global__ __launch_bounds__(256) void attn_h0_kernel(
    const float* __restrict__ x, const float* __restrict__ node_emb,
    const int* __restrict__ node_type, const float* __restrict__ S,
    float* __restrict__ h0, float* __restrict__ as_, float* __restrict__ ad_) {
    __shared__ float xt[64 * 132];
    __shared__ float ms[512], md[512];
    __shared__ int ntS[64];
    int t = threadIdx.x;
    int n0 = blockIdx.x * 64;
    if (t < 64) {
        int n = n0 + t;
        ntS[t] = (n < NN) ? node_type[n] : 0;
    }
    for (int i = t; i < 512; i += 256) { ms[i] = S[S_MS1 + i]; md[i] = S[S_MD1 + i]; }
    __syncthreads();
    for (int i = t; i < 1024; i += 256) {
        int r = i >> 4, c4 = (i & 15) * 4;
        int n = n0 + r;
        float4 f = {0, 0, 0, 0};
        if (n < NN) f = *(const float4*)(x + (size_t)n * 64 + c4);
        *(float4*)&xt[r * 132 + c4] = f;
    }
    for (int i = t; i < 1024; i += 256) {
        int r = i >> 4, c4 = (i & 15) * 4;
        int n = n0 + r;
        float4 f = {0, 0, 0, 0};
        if (n < NN) f = *(const float4*)(node_emb + (size_t)ntS[r] * 64 + c4);
        *(float4*)&xt[r * 132 + 64 + c4] = f;
    }
    __syncthreads();
    for (int i = t; i < 2048; i += 256) {
        int r = i >> 5, c4 = (i & 31) * 4;
        int n = n0 + r;
        if (n < NN) *(float4*)(h0 + (size_t)n * 128 + c4) = *(const float4*)&xt[r * 132 + c4];
    }
    int r = t >> 2, h = t & 3;
    float s = 0.f, d = 0.f;
#pragma unroll 8
    for (int k = 0; k < 128; k++) {
        float xv = xt[r * 132 + k];
        s += xv * ms[k * 4 + h];
        d += xv * md[k * 4 + h];
    }
    int n = n0 + r;
    if (n < NN) { as_[n * 4 + h] = s; ad_[n * 4 + h] = d; }
}

// ---- 3-kernel decoupled scan ----
__global__ void scan_blocks_kernel(const int* __restrict__ cnt, int* __restrict__ eoff,
                                   int* __restrict__ bsum) {
    __shared__ int wsum[16];
    int t = threadIdx.x;
    int i = blockIdx.x * 1024 + t;
    int v = (i < NN) ? cnt[i] : 0;
    int lane = t & 63;
    int incl = v;
#pragma unroll
    for (int ofs = 1; ofs < 64; ofs <<= 1) {
        int u = __shfl_up(incl, ofs, 64);
        if (lane >= ofs) incl += u;
    }
    int wid = t >> 6;
    if (lane == 63) wsum[wid] = incl;
    __syncthreads();
    if (t < 16) {
        int s = wsum[t];
#pragma unroll
        for (int ofs = 1; ofs < 16; ofs <<= 1) {
            int u = __shfl_up(s, ofs, 64);
            if (t >= ofs) s += u;
        }
        wsum[t] = s;
    }
    __syncthreads();
    int excl = incl - v + (wid > 0 ? wsum[wid - 1] : 0);
    if (i < NN) eoff[i] = excl;
    if (t == 1023) bsum[blockIdx.x] = excl + v;
}

__global__ void scan_tops_kernel(const int* __restrict__ bsum, int* __restrict__ boff, int nb) {
    int t = threadIdx.x; // 64
    int v = (t < nb) ? bsum[t] : 0;
    int incl = v;
#pragma unroll
    for (int ofs = 1; ofs < 64; ofs <<= 1) {
        int u = __shfl_up(incl, ofs, 64);
        if (t >= ofs) incl += u;
    }
    boff[t] = incl - v;
}

__global__ void scan_add_kernel(const int* __restrict__ boff, int* __restrict__ eoff) {
    int i = blockIdx.x * 256 + threadIdx.x;
    if (i < NN) eoff[i] += boff[i >> 10];
    if (i == 0) eoff[NN] = NE;
}

// ---- fused scatter + scoring ----
__global__ void scatter_score_kernel(const int* __restrict__ src, const int* __restrict__ dst,
                                     const float* __restrict__ EA, const float* __restrict__ S,
                                     const float* __restrict__ as_, const float* __restrict__ ad_,
                                     const int* __restrict__ eoff, int* __restrict__ pos,
                                     int* __restrict__ src_sorted,
                                     float* __restrict__ sc1, float* __restrict__ ae2s) {
    int e = blockIdx.x * 256 + threadIdx.x;
    if (e >= NE) return;
    int s = src[e], d = dst[e];
    float a1[4], a2[4];
#pragma unroll
    for (int h = 0; h < 4; h++) { a1[h] = S[S_C1 + h]; a2[h] = S[S_C2 + h]; }
    const float4* EA4 = (const float4*)(EA + (size_t)e * FEA);
#pragma unroll
    for (int q = 0; q < 4; q++) {
        float4 v = EA4[q];
        float vv[4] = {v.x, v.y, v.z, v.w};
#pragma unroll
        for (int j = 0; j < 4; j++) {
            int f = q * 4 + j;
#pragma unroll
            for (int h = 0; h < 4; h++) {
                a1[h] += vv[j] * S[S_KF1 + f * 4 + h];
                a2[h] += vv[j] * S[S_KF2 + f * 4 + h];
            }
        }
    }
    int p = atomicAdd(&pos[d], 1);
    int idx = eoff[d] + p;
    src_sorted[idx] = s;
    ((float4*)ae2s)[idx] = make_float4(a2[0], a2[1], a2[2], a2[3]);
    float4 asv = ((const float4*)as_)[s];
    float4 adv = ((const float4*)ad_)[d];
    float4 r;
    r.x = expf(leakyf(asv.x + adv.x + a1[0]));
    r.y = expf(leakyf(asv.y + adv.y + a1[1]));
    r.z = expf(leakyf(asv.z + adv.z + a1[2]));
    r.w = expf(leakyf(asv.w + adv.w + a1[3]));
    ((float4*)sc1)[idx] = r;
}

// ---- goff via binary search over sorted batch ----
__global__ void goff_bs_kernel(const int* __restrict__ batch, int* __restrict__ goff) {
    int g = threadIdx.x;
    if (g > NG) return;
    int lo = 0, hi = NN;
    while (lo < hi) {
        int mid = (lo + hi) >> 1;
        if (batch[mid] < g) lo = mid + 1; else hi = mid;
    }
    goff[g] = lo;
}

// ---- GAT aggregate-first ----
template <int KD, bool CW>
__global__ __launch_bounds__(256) void agg_gat_kernel(
    const int* __restrict__ eoff, const int* __restrict__ src_sorted,
    const float* __restrict__ wsrc, const float* __restrict__ X,
    const float* __restrict__ as_, const float* __restrict__ ad_,
    const float* __restrict__ Sael, float* __restrict__ agg) {
    constexpr int CHUNKS = KD / 4;
    constexpr int EPW = 64 / CHUNKS;
    int n = blockIdx.x * 4 + (threadIdx.x >> 6);
    if (n >= NN) return;
    int lane = threadIdx.x & 63;
    int sub = lane / CHUNKS;
    int ch = lane % CHUNKS;
    const float4* X4 = (const float4*)X;
    const float4* W4 = (const float4*)wsrc;
    const float4* AS4 = (const float4*)as_;
    float4 asn = AS4[n];
    float4 adn = ((const float4*)ad_)[n];
    float4 a0 = {0, 0, 0, 0}, a1 = a0, a2 = a0, a3 = a0, dn = a0;
    int b = eoff[n], e = eoff[n + 1];
    int nE = e - b;
    int i = sub;
    for (; i + EPW < nE; i += 2 * EPW) {
        int idx0 = b + i, idx1 = b + i + EPW;
        int s0 = src_sorted[idx0], s1 = src_sorted[idx1];
        float4 w0 = W4[idx0], w1 = W4[idx1];
        if (CW) {
            float4 q0 = AS4[s0], q1 = AS4[s1];
            w0.x = expf(leakyf(q0.x + adn.x + w0.x));
            w0.y = expf(leakyf(q0.y + adn.y + w0.y));
            w0.z = expf(leakyf(q0.z + adn.z + w0.z));
            w0.w = expf(leakyf(q0.w + adn.w + w0.w));
            w1.x = expf(leakyf(q1.x + adn.x + w1.x));
            w1.y = expf(leakyf(q1.y + adn.y + w1.y));
            w1.z = expf(leakyf(q1.z + adn.z + w1.z));
            w1.w = expf(leakyf(q1.w + adn.w + w1.w));
        }
        float4 x0 = X4[(size_t)s0 * CHUNKS + ch];
        float4 x1 = X4[(size_t)s1 * CHUNKS + ch];
        fma4(a0, w0.x, x0); fma4(a1, w0.y, x0); fma4(a2, w0.z, x0); fma4(a3, w0.w, x0);
        fma4(a0, w1.x, x1); fma4(a1, w1.y, x1); fma4(a2, w1.z, x1); fma4(a3, w1.w, x1);
        dn.x += w0.x + w1.x; dn.y += w0.y + w1.y;
        dn.z += w0.z + w1.z; dn.w += w0.w + w1.w;
    }
    for (; i < nE; i += EPW) {
        int idx0 = b + i;
        int s0 = src_sorted[idx0];
        float4 w0 = W4[idx0];
        if (CW) {
            float4 q0 = AS4[s0];
            w0.x = expf(leakyf(q0.x + adn.x + w0.x));
            w0.y = expf(leakyf(q0.y + adn.y + w0.y));
            w0.z = expf(leakyf(q0.z + adn.z + w0.z));
            w0.w = expf(leakyf(q0.w + adn.w + w0.w));
        }
        float4 x0 = X4[(size_t)s0 * CHUNKS + ch];
        fma4(a0, w0.x, x0); fma4(a1, w0.y, x0); fma4(a2, w0.z, x0); fma4(a3, w0.w, x0);
        dn.x += w0.x; dn.y += w0.y; dn.z += w0.z; dn.w += w0.w;
    }
    if (sub == 0) {  // self loop
        float e0 = expf(leakyf(asn.x + adn.x + Sael[0]));
        float e1 = expf(leakyf(asn.y + adn.y + Sael[1]));
        float e2 = expf(leakyf(asn.z + adn.z + Sael[2]));
        float e3 = expf(leakyf(asn.w + adn.w + Sael[3]));
        float4 xs = X4[(size_t)n * CHUNKS + ch];
        fma4(a0, e0, xs); fma4(a1, e1, xs); fma4(a2, e2, xs); fma4(a3, e3, xs);
        dn.x += e0; dn.y += e1; dn.z += e2; dn.w += e3;
    }
#pragma unroll
    for (int mask = CHUNKS; mask < 64; mask <<= 1) {
        a0.x += __shfl_xor(a0.x, mask, 64); a0.y += __shfl_xor(a0.y, mask, 64);
        a0.z += __shfl_xor(a0.z, mask, 64); a0.w += __shfl_xor(a0.w, mask, 64);
        a1.x += __shfl_xor(a1.x, mask, 64); a1.y += __shfl_xor(a1.y, mask, 64);
        a1.z += __shfl_xor(a1.z, mask, 64); a1.w += __shfl_xor(a1.w, mask, 64);
        a2.x += __shfl_xor(a2.x, mask, 64); a2.y += __shfl_xor(a2.y, mask, 64);
        a2.z += __shfl_xor(a2.z, mask, 64); a2.w += __shfl_xor(a2.w, mask, 64);
        a3.x += __shfl_xor(a3.x, mask, 64); a3.y += __shfl_xor(a3.y, mask, 64);
        a3.z += __shfl_xor(a3.z, mask, 64); a3.w += __shfl_xor(a3.w, mask, 64);
        dn.x += __shfl_xor(dn.x, mask, 64); dn.y += __shfl_xor(dn.y, mask, 64);
        dn.z += __shfl_xor(dn.z, mask, 64); dn.w += __shfl_xor(dn.w, mask, 64);
    }
    if (sub == 0) {
        float i0 = 1.f / dn.x, i1 = 1.f / dn.y, i2 = 1.f / dn.z, i3 = 1.f / dn.w;
        float4* agg4 = (float4*)agg;
        size_t base = (size_t)n * 4 * CHUNKS + ch;
        agg4[base]              = make_float4(a0.x * i0, a0.y * i0, a0.z * i0, a0.w * i0);
        agg4[base + CHUNKS]     = make_float4(a1.x * i1, a1.y * i1, a1.z * i1, a1.w * i1);
        agg4[base + 2 * CHUNKS] = make_float4(a2.x * i2, a2.y * i2, a2.z * i2, a2.w * i2);
        agg4[base + 3 * CHUNKS] = make_float4(a3.x * i3, a3.y * i3, a3.z * i3, a3.w * i3);
    }
}

// ---- GEMM: out[M,64] = elu(A[M,K]@B[K,64]+bias); 64-row tiles, acc 4x4,
//      A staged k-major stride 68 so the 4 acc rows are ONE ds_read_b128 ----
template <int K, bool DOATT>
__global__ __launch_bounds__(256) void gemm64_kernel(
    const float* __restrict__ A, const float* __restrict__ B,
    const float* __restrict__ bias, float* __restrict__ out,
    const float* __restrict__ ms_g, const float* __restrict__ md_g,
    float* __restrict__ as_, float* __restrict__ ad_) {
    __shared__ float As[32 * 68];   // [k][row], stride 68 (272B: 16B-aligned rows)
    __shared__ float Bs[32 * 68];   // [k][c]
    __shared__ float msS[256], mdS[256];
    int t = threadIdx.x;
    int tx = t & 15, ty = t >> 4;   // tx: 4-col group, ty: 4-row group
    int m_base = blockIdx.x * 64;
    if (DOATT) { msS[t] = ms_g[t]; mdS[t] = md_g[t]; }
    float acc[4][4] = {};
    for (int k0 = 0; k0 < K; k0 += 32) {
#pragma unroll
        for (int i = 0; i < 2; i++) {   // stage A: 64 rows x 32 k
            int lin = t + i * 256;
            int row = lin >> 3, kq = (lin & 7) * 4;
            int m = m_base + row;
            float4 f = {0, 0, 0, 0};
            if (m < NN) f = *(const float4*)(A + (size_t)m * K + k0 + kq);
            As[(kq + 0) * 68 + row] = f.x;
            As[(kq + 1) * 68 + row] = f.y;
            As[(kq + 2) * 68 + row] = f.z;
            As[(kq + 3) * 68 + row] = f.w;
        }
#pragma unroll
        for (int i = 0; i < 2; i++) {   // stage B: 32 k x 64 c
            int lin = t + i * 256;
            int kr = lin >> 4, nc = (lin & 15) * 4;
            *(float4*)&Bs[kr * 68 + nc] = *(const float4*)(B + (size_t)(k0 + kr) * 64 + nc);
        }
        __syncthreads();
#pragma unroll
        for (int k = 0; k < 32; k++) {
            float4 av = *(const float4*)&As[k * 68 + ty * 4];
            float4 bv = *(const float4*)&Bs[k * 68 + tx * 4];
            float a[4] = {av.x, av.y, av.z, av.w};
            float b[4] = {bv.x, bv.y, bv.z, bv.w};
#pragma unroll
            for (int i = 0; i < 4; i++)
#pragma unroll
                for (int j = 0; j < 4; j++) acc[i][j] += a[i] * b[j];
        }
        __syncthreads();
    }
    float4 bvv = ((const float4*)bias)[tx];
    float o[4][4];
#pragma unroll
    for (int i = 0; i < 4; i++) {
        o[i][0] = eluf(acc[i][0] + bvv.x);
        o[i][1] = eluf(acc[i][1] + bvv.y);
        o[i][2] = eluf(acc[i][2] + bvv.z);
        o[i][3] = eluf(acc[i][3] + bvv.w);
        int m = m_base + ty * 4 + i;
        if (m < NN)
            *(float4*)(out + (size_t)m * 64 + tx * 4) =
                make_float4(o[i][0], o[i][1], o[i][2], o[i][3]);
    }
    if (DOATT) {
        float ps[4][4] = {}, pd[4][4] = {};
#pragma unroll
        for (int i = 0; i < 4; i++)
#pragma unroll
            for (int j = 0; j < 4; j++) {
                float v = o[i][j];
                int kk = (tx * 4 + j) * 4;
#pragma unroll
                for (int h = 0; h < 4; h++) {
                    ps[i][h] += v * msS[kk + h];
                    pd[i][h] += v * mdS[kk + h];
                }
            }
#pragma unroll
        for (int mk = 1; mk < 16; mk <<= 1) {
#pragma unroll
            for (int i = 0; i < 4; i++)
#pragma unroll
                for (int h = 0; h < 4; h++) {
                    ps[i][h] += __shfl_xor(ps[i][h], mk, 64);
                    pd[i][h] += __shfl_xor(pd[i][h], mk, 64);
                }
        }
        if (tx == 0) {
#pragma unroll
            for (int i = 0; i < 4; i++) {
                int m = m_base + ty * 4 + i;
                if (m < NN) {
                    *(float4*)(as_ + (size_t)m * 4) =
                        make_float4(ps[i][0], ps[i][1], ps[i][2], ps[i][3]);
                    *(float4*)(ad_ + (size_t)m * 4) =
                        make_float4(pd[i][0], pd[i][1], pd[i][2], pd[i][3]);
                }
            }
        }
    }
}

// ---- SAGE mean aggregation into AB[:,0:64]; copy h2 into AB[:,64:128] ----
__global__ __launch_bounds__(256) void sage_agg3_kernel(
    const float* __restrict__ h2, const int* __restrict__ eoff,
    const int* __restrict__ src_sorted, float* __restrict__ AB) {
    int n = blockIdx.x * 16 + (threadIdx.x >> 4);
    if (n >= NN) return;
    int l = threadIdx.x & 15;
    const float4* h24 = (const float4*)h2;
    float4* AB4 = (float4*)AB;
    float ax = 0.f, ay = 0.f, az = 0.f, aw = 0.f;
    int b = eoff[n], e_end = eoff[n + 1];
    int idx = b;
    int stop = b + ((e_end - b) & ~7);
    if (idx < stop) {
        int sreg[8];
#pragma unroll
        for (int u = 0; u < 8; u++) sreg[u] = src_sorted[idx + u];
        idx += 8;
        while (true) {
            int sn[8];
            bool more = idx < stop;
            if (more) {
#pragma unroll
                for (int u = 0; u < 8; u++) sn[u] = src_sorted[idx + u];
            }
#pragma unroll
            for (int u = 0; u < 8; u++) {
                float4 v = h24[(size_t)sreg[u] * 16 + l];
                ax += v.x; ay += v.y; az += v.z; aw += v.w;
            }
            if (!more) break;
#pragma unroll
            for (int u = 0; u < 8; u++) sreg[u] = sn[u];
            idx += 8;
        }
    }
    for (; idx < e_end; idx++) {
        float4 v0 = h24[(size_t)src_sorted[idx] * 16 + l];
        ax += v0.x; ay += v0.y; az += v0.z; aw += v0.w;
    }
    float dg = (float)(e_end - b);
    if (dg < 1.f) dg = 1.f;
    float inv = 1.f / dg;
    AB4[(size_t)n * 32 + l] = make_float4(ax * inv, ay * inv, az * inv, aw * inv);
    AB4[(size_t)n * 32 + 16 + l] = h24[(size_t)n * 16 + l];
}

// ---- fused pool + MLP head: one block per graph -> d_out[192] ----
__global__ __launch_bounds__(256) void pool_mlp_kernel(
    const float* __restrict__ h3, const int* __restrict__ goff,
    const float* __restrict__ lin1W, const float* __restrict__ lin1b,
    const float* __restrict__ lin2W, const float* __restrict__ lin2b,
    const float* __restrict__ telW, const float* __restrict__ telb,
    const float* __restrict__ compW, const float* __restrict__ compb,
    const float* __restrict__ pchW, const float* __restrict__ pchb,
    float* __restrict__ out) {
    __shared__ float red[256];
    __shared__ float g[64], G1[64], G2[64];
    int gi = blockIdx.x, t = threadIdx.x;
    int c = t & 63, li = t >> 6;
    int b = goff[gi], e = goff[gi + 1];
    float sum = 0.f;
    for (int r = b + li; r < e; r += 4) sum += h3[(size_t)r * HID + c];
    red[t] = sum;
    __syncthreads();
    if (t < 64) {
        float v = red[t] + red[t + 64] + red[t + 128] + red[t + 192];
        float cntf = (float)(e - b);
        if (cntf < 1.f) cntf = 1.f;
        g[t] = v / cntf;
    }
    __syncthreads();
    {
        float part = 0.f;
#pragma unroll
        for (int k = li * 16; k < li * 16 + 16; k++) part += g[k] * lin1W[k * 64 + c];
        red[t] = part;
        __syncthreads();
        if (t < 64)
            G1[c] = eluf(red[c] + red[c + 64] + red[c + 128] + red[c + 192] + lin1b[c]);
        __syncthreads();
    }
    {
        float part = 0.f;
#pragma unroll
        for (int k = li * 16; k < li * 16 + 16; k++) part += G1[k] * lin2W[k * 64 + c];
        red[t] = part;
        __syncthreads();
        if (t < 64)
            G2[c] = red[c] + red[c + 64] + red[c + 128] + red[c + 192] + lin2b[c];
        __syncthreads();
    }
    if (t < 192) {
        int h = t >> 6, k = t & 63;
        const float* W = (h == 0) ? telW : ((h == 1) ? compW : pchW);
        red[t] = G2[k] * W[k];
    }
    __syncthreads();
    if (t < 3) {
        float acc = 0.f;
        for (int k = 0; k < 64; k++) acc += red[t * 64 + k];
        float bb = (t == 0) ? telb[0] : ((t == 1) ? compb[0] : pchb[0]);
        out[t * 64 + gi] = acc + bb;
    }
}

extern "C" void kernel_launch(void* const* d_in, const int* in_sizes, int n_in,
                              void* d_out, int out_size, void* d_ws, size_t ws_size,
                              hipStream_t stream) {
    const float* x        = (const float*)d_in[0];
    const float* EA       = (const float*)d_in[1];
    const float* node_emb = (const float*)d_in[2];
    const float* edge_W   = (const float*)d_in[3];
    const float* edge_b   = (const float*)d_in[4];
    const float* W1       = (const float*)d_in[5];
    const float* as1      = (const float*)d_in[6];
    const float* ad1      = (const float*)d_in[7];
    const float* ae1      = (const float*)d_in[8];
    const float* leW1     = (const float*)d_in[9];
    const float* b1       = (const float*)d_in[10];
    const float* W2       = (const float*)d_in[11];
    const float* as2      = (const float*)d_in[12];
    const float* ad2      = (const float*)d_in[13];
    const float* ae2      = (const float*)d_in[14];
    const float* leW2     = (const float*)d_in[15];
    const float* b2       = (const float*)d_in[16];
    const float* sage_Wl  = (const float*)d_in[17];
    const float* sage_bl  = (const float*)d_in[18];
    const float* sage_Wr  = (const float*)d_in[19];
    const float* lin1_W   = (const float*)d_in[20];
    const float* lin1_b   = (const float*)d_in[21];
    const float* lin2_W   = (const float*)d_in[22];
    const float* lin2_b   = (const float*)d_in[23];
    const float* tel_W    = (const float*)d_in[24];
    const float* tel_b    = (const float*)d_in[25];
    const float* comp_W   = (const float*)d_in[26];
    const float* comp_b   = (const float*)d_in[27];
    const float* pch_W    = (const float*)d_in[28];
    const float* pch_b    = (const float*)d_in[29];
    const int* edge_index = (const int*)d_in[30];
    const int* batch      = (const int*)d_in[31];
    const int* node_type  = (const int*)d_in[32];
    float* outp = (float*)d_out;

    const int* srcp = edge_index;
    const int* dstp = edge_index + NE;

    float* wf = (float*)d_ws;
    constexpr size_t OFF_H0    = 0;                               // N*128 (h3 aliases later)
    constexpr size_t OFF_AGG   = OFF_H0 + (size_t)NN * 128;       // N*512 (agg1/agg2/AB alias)
    constexpr size_t OFF_H1    = OFF_AGG + (size_t)NN * 512;      // N*64
    constexpr size_t OFF_H2    = OFF_H1 + (size_t)NN * 64;        // N*64
    constexpr size_t OFF_SC    = OFF_H2 + (size_t)NN * 64;        // E*4
    constexpr size_t OFF_AE2   = OFF_SC + (size_t)NE * 4;         // E*4
    constexpr size_t OFF_AS    = OFF_AE2 + (size_t)NE * 4;        // N*4
    constexpr size_t OFF_AD    = OFF_AS + (size_t)NN * 4;         // N*4
    constexpr size_t OFF_SMALL = OFF_AD + (size_t)NN * 4;         // 4096
    constexpr size_t OFF_WC1   = OFF_SMALL + 4096;                // 32768
    constexpr size_t OFF_WC2   = OFF_WC1 + 32768;                 // 16384
    constexpr size_t OFF_B128  = OFF_WC2 + 16384;                 // 8192
    constexpr size_t F_TOTAL   = OFF_B128 + 8192;

    int* wi         = (int*)(wf + F_TOTAL);
    int* cnt        = wi;                        // N
    int* pos        = wi + NN;                   // N   (adjacent: one memset)
    int* eoff       = pos + NN;                  // N+1
    int* src_sorted = eoff + (NN + 1);           // E
    int* goff       = src_sorted + NE;           // NG+1
    int* bsum       = goff + (NG + 1);           // 64
    int* boff       = bsum + 64;                 // 64

    float* h0    = wf + OFF_H0;
    float* aggb  = wf + OFF_AGG;
    float* h1    = wf + OFF_H1;
    float* h2    = wf + OFF_H2;
    float* sc    = wf + OFF_SC;
    float* ae2s  = wf + OFF_AE2;
    float* as_   = wf + OFF_AS;
    float* ad_   = wf + OFF_AD;
    float* S     = wf + OFF_SMALL;
    float* WC1   = wf + OFF_WC1;
    float* WC2   = wf + OFF_WC2;
    float* B128  = wf + OFF_B128;
    float* AB    = wf + OFF_AGG;                 // alias (agg dead after gemm L2)
    float* h3    = wf + OFF_H0;                  // alias (h0 dead after agg L1)

    hipMemsetAsync(S + S_MEANEA, 0, 16 * sizeof(float), stream);
    hipMemsetAsync(cnt, 0, 2 * NN * sizeof(int), stream);   // cnt + pos

    count_mean_kernel<<<(NE + 1023) / 1024, 256, 0, stream>>>(dstp, EA, cnt, S);
    prep_weights_kernel<<<224, 256, 0, stream>>>(W1, W2, sage_Wl, sage_Wr, WC1, WC2, B128);
    prep_small_kernel<<<1, 256, 0, stream>>>(W1, as1, ad1, ae1, leW1,
                                             W2, as2, ad2, ae2, leW2,
                                             edge_W, edge_b, S);
    {
        int nb = (NN + 1023) / 1024;  // 30
        scan_blocks_kernel<<<nb, 1024, 0, stream>>>(cnt, eoff, bsum);
        scan_tops_kernel<<<1, 64, 0, stream>>>(bsum, boff, nb);
        scan_add_kernel<<<(NN + 255) / 256, 256, 0, stream>>>(boff, eoff);
    }
    attn_h0_kernel<<<(NN + 63) / 64, 256, 0, stream>>>(x, node_emb, node_type, S, h0, as_, ad_);
    goff_bs_kernel<<<1, 128, 0, stream>>>(batch, goff);
    scatter_score_kernel<<<(NE + 255) / 256, 256, 0, stream>>>(
        srcp, dstp, EA, S, as_, ad_, eoff, pos, src_sorted, sc, ae2s);

    // ----- GAT layer 1 -----
    agg_gat_kernel<128, false><<<(NN + 3) / 4, 256, 0, stream>>>(
        eoff, src_sorted, sc, h0, as_, ad_, S + S_AEL1, aggb);
    gemm64_kernel<512, true><<<(NN + 63) / 64, 256, 0, stream>>>(
        aggb, WC1, b1, h1, S + S_MS2, S + S_MD2, as_, ad_);

    // ----- GAT layer 2 -----
    agg_gat_kernel<64, true><<<(NN + 3) / 4, 256, 0, stream>>>(
        eoff, src_sorted, ae2s, h1, as_, ad_, S + S_AEL2, aggb);
    gemm64_kernel<256, false><<<(NN + 63) / 64, 256, 0, stream>>>(
        aggb, WC2, b2, h2, nullptr, nullptr, nullptr, nullptr);

    // ----- SAGE -----
    sage_agg3_kernel<<<(NN + 15) / 16, 256, 0, stream>>>(h2, eoff, src_sorted, AB);
    gemm64_kernel<128, false><<<(NN + 63) / 64, 256, 0, stream>>>(
        AB, B128, sage_bl, h3, nullptr, nullptr, nullptr, nullptr);

    // ----- fused pool + MLP head -----
    pool_mlp_kernel<<<NG, 256, 0, stream>>>(h3, goff, lin1_W, lin1_b, lin2_W, lin2_b,
                                            tel_W, tel_b, comp_W, comp_b, pch_W, pch_b, outp);
}

// Round 8
// 458.461 us; speedup vs baseline: 2.7347x; 1.0457x over previous
//
#include <hip/hip_runtime.h>
#include <math.h>

#define NN 30000          // nodes
#define NE 480000         // edges
#define FEA 16            // edge feature dim
#define HID 64
#define NG 64             // graphs
#define LEAKK 0.2f

// ---- small-constant region layout (float offsets) ----
#define S_MEANEA 0    // 16
#define S_KF1    16   // 64  (K1 [16,4])
#define S_C1     80   // 4
#define S_AEL1   84   // 4
#define S_KF2    88   // 64
#define S_C2     152  // 4
#define S_AEL2   156  // 4
#define S_MS1    160  // 512 (Ms1 [128,4])
#define S_MD1    672  // 512
#define S_MS2    1184 // 256 (Ms2 [64,4])
#define S_MD2    1440 // 256

__device__ __forceinline__ float eluf(float v) { return v > 0.f ? v : expm1f(v); }
__device__ __forceinline__ float leakyf(float v) { return v >= 0.f ? v : LEAKK * v; }
__device__ __forceinline__ void fma4(float4& a, float w, const float4& x) {
    a.x += w * x.x; a.y += w * x.y; a.z += w * x.z; a.w += w * x.w;
}

// ---- count (CSR degree) + mean of edge_attr: 938 blocks x 512 edges ----
__global__ __launch_bounds__(256) void count_mean_kernel(
    const int* __restrict__ dst, const float* __restrict__ EA,
    int* __restrict__ cnt, float* __restrict__ S) {
    __shared__ float red[1024];
    int t = threadIdx.x;
    int base = blockIdx.x * 512;
#pragma unroll
    for (int i = 0; i < 2; i++) {
        int e = base + i * 256 + t;
        if (e < NE) atomicAdd(&cnt[dst[e]], 1);
    }
    // mean: float4 loads; thread covers f4-col (t&3), rows base+(t>>2)+i*64
    int c4 = t & 3;
    int rbase = base + (t >> 2);
    float4 acc = {0, 0, 0, 0};
#pragma unroll
    for (int i = 0; i < 8; i++) {
        int r = rbase + i * 64;
        if (r < NE) {
            float4 v = *(const float4*)(EA + (size_t)r * FEA + c4 * 4);
            acc.x += v.x; acc.y += v.y; acc.z += v.z; acc.w += v.w;
        }
    }
    *(float4*)&red[t * 4] = acc;
    __syncthreads();
    if (t < 16) {
        int grp = t >> 2;     // which (t&3) group
        int comp = t & 3;     // component within float4
        float sum = 0.f;
        for (int j = 0; j < 64; j++) sum += red[(grp + 4 * j) * 4 + comp];
        atomicAdd(&S[S_MEANEA + grp * 4 + comp], sum);
    }
}

// ---- parallel weight-layout build ----
__global__ void prep_weights_kernel(const float* __restrict__ W1, const float* __restrict__ W2,
                                    const float* __restrict__ Wl, const float* __restrict__ Wr,
                                    float* __restrict__ WC1, float* __restrict__ WC2,
                                    float* __restrict__ B128) {
    int i = blockIdx.x * 256 + threadIdx.x;
    if (i < 32768) {
        int hk = i >> 6, c = i & 63;
        int h = hk >> 7, k = hk & 127;
        WC1[i] = 0.25f * W1[k * 256 + h * 64 + c];
    } else if (i < 49152) {
        int j = i - 32768;
        int hk = j >> 6, c = j & 63;
        int h = hk >> 6, k = hk & 63;
        WC2[j] = 0.25f * W2[k * 256 + h * 64 + c];
    } else if (i < 57344) {
        int j = i - 49152;
        int k = j >> 6, c = j & 63;
        B128[j] = (k < 64) ? Wl[k * 64 + c] : Wr[(k - 64) * 64 + c];
    }
}

// ---- fold attention weights into small matrices ----
__global__ void prep_small_kernel(
    const float* __restrict__ W1, const float* __restrict__ as1, const float* __restrict__ ad1,
    const float* __restrict__ ae1, const float* __restrict__ leW1,
    const float* __restrict__ W2, const float* __restrict__ as2, const float* __restrict__ ad2,
    const float* __restrict__ ae2, const float* __restrict__ leW2,
    const float* __restrict__ edge_W, const float* __restrict__ edge_b,
    float* __restrict__ S) {
    __shared__ float M1[256], M2[256], meh[64];
    int t = threadIdx.x;
    if (t < 16) S[S_MEANEA + t] *= (1.0f / (float)NE);
    __syncthreads();
    {
        int k = t >> 2, h = t & 3;
        float m1 = 0.f, m2 = 0.f;
        for (int c = 0; c < 64; c++) {
            m1 += leW1[k * 256 + h * 64 + c] * ae1[h * 64 + c];
            m2 += leW2[k * 256 + h * 64 + c] * ae2[h * 64 + c];
        }
        M1[t] = m1; M2[t] = m2;
    }
    if (t < 64) {
        float v = edge_b[t];
        for (int f = 0; f < FEA; f++) v += S[S_MEANEA + f] * edge_W[f * 64 + t];
        meh[t] = v;
    }
    __syncthreads();
    if (t < 64) {
        int f = t >> 2, h = t & 3;
        float k1 = 0.f, k2 = 0.f;
        for (int k = 0; k < 64; k++) {
            k1 += edge_W[f * 64 + k] * M1[k * 4 + h];
            k2 += edge_W[f * 64 + k] * M2[k * 4 + h];
        }
        S[S_KF1 + t] = k1; S[S_KF2 + t] = k2;
    } else if (t < 68) {
        int h = t - 64;
        float c1 = 0.f, c2 = 0.f, a1 = 0.f, a2 = 0.f;
        for (int k = 0; k < 64; k++) {
            c1 += edge_b[k] * M1[k * 4 + h];
            c2 += edge_b[k] * M2[k * 4 + h];
            a1 += meh[k] * M1[k * 4 + h];
            a2 += meh[k] * M2[k * 4 + h];
        }
        S[S_C1 + h] = c1; S[S_C2 + h] = c2;
        S[S_AEL1 + h] = a1; S[S_AEL2 + h] = a2;
    }
    for (int i = t; i < 512; i += 256) {
        int k = i >> 2, h = i & 3;
        float s = 0.f, d = 0.f;
        for (int c = 0; c < 64; c++) {
            float w = W1[k * 256 + h * 64 + c];
            s += w * as1[h * 64 + c];
            d += w * ad1[h * 64 + c];
        }
        S[S_MS1 + i] = s; S[S_MD1 + i] = d;
    }
    for (int i = t; i < 256; i += 256) {
        int k = i >> 2, h = i & 3;
        float s = 0.f, d = 0.f;
        for (int c = 0; c < 64; c++) {
            float w = W2[k * 256 + h * 64 + c];
            s += w * as2[h * 64 + c];
            d += w * ad2[h * 64 + c];
        }
        S[S_MS2 + i] = s; S[S_MD2 + i] = d;
    }
}

// ---- build h0 = concat(x, emb[type]) AND compute layer-1 a_s/a_d ----
__global__ __launch_bounds__(256) void attn_h0_kernel(
    const float* __restrict__ x, const float* __restrict__ node_emb,
    const int* __restrict__ node_type, const float* __restrict__ S,
    float* __restrict__ h0, float* __restrict__ as_, float* __restrict__ ad_) {
    __shared__ float xt[64 * 132];
    __shared__ float ms[512], md[512];
    __shared__ int ntS[64];
    int t = threadIdx.x;
    int n0 = blockIdx.x * 64;
    if (t < 64) {
        int n = n0 + t;
        ntS[t] = (n < NN) ? node_type[n] : 0;
    }
    for (int i = t; i < 512; i += 256) { ms[i] = S[S_MS1 + i]; md[i] = S[S_MD1 + i]; }
    __syncthreads();
    for (int i = t; i < 1024; i += 256) {
        int r = i >> 4, c4 = (i & 15) * 4;
        int n = n0 + r;
        float4 f = {0, 0, 0, 0};
        if (n < NN) f = *(const float4*)(x + (size_t)n * 64 + c4);
        *(float4*)&xt[r * 132 + c4] = f;
    }
    for (int i = t; i < 1024; i += 256) {
        int r = i >> 4, c4 = (i & 15) * 4;
        int n = n0 + r;
        float4 f = {0, 0, 0, 0};
        if (n < NN) f = *(const float4*)(node_emb + (size_t)ntS[r] * 64 + c4);
        *(float4*)&xt[r * 132 + 64 + c4] = f;
    }
    __syncthreads();
    for (int i = t; i < 2048; i += 256) {
        int r = i >> 5, c4 = (i & 31) * 4;
        int n = n0 + r;
        if (n < NN) *(float4*)(h0 + (size_t)n * 128 + c4) = *(const float4*)&xt[r * 132 + c4];
    }
    int r = t >> 2, h = t & 3;
    float s = 0.f, d = 0.f;
#pragma unroll 8
    for (int k = 0; k < 128; k++) {
        float xv = xt[r * 132 + k];
        s += xv * ms[k * 4 + h];
        d += xv * md[k * 4 + h];
    }
    int n = n0 + r;
    if (n < NN) { as_[n * 4 + h] = s; ad_[n * 4 + h] = d; }
}

// ---- 3-kernel decoupled scan ----
__global__ void scan_blocks_kernel(const int* __restrict__ cnt, int* __restrict__ eoff,
                                   int* __restrict__ bsum) {
    __shared__ int wsum[16];
    int t = threadIdx.x;
    int i = blockIdx.x * 1024 + t;
    int v = (i < NN) ? cnt[i] : 0;
    int lane = t & 63;
    int incl = v;
#pragma unroll
    for (int ofs = 1; ofs < 64; ofs <<= 1) {
        int u = __shfl_up(incl, ofs, 64);
        if (lane >= ofs) incl += u;
    }
    int wid = t >> 6;
    if (lane == 63) wsum[wid] = incl;
    __syncthreads();
    if (t < 16) {
        int s = wsum[t];
#pragma unroll
        for (int ofs = 1; ofs < 16; ofs <<= 1) {
            int u = __shfl_up(s, ofs, 64);
            if (t >= ofs) s += u;
        }
        wsum[t] = s;
    }
    __syncthreads();
    int excl = incl - v + (wid > 0 ? wsum[wid - 1] : 0);
    if (i < NN) eoff[i] = excl;
    if (t == 1023) bsum[blockIdx.x] = excl + v;
}

__global__ void scan_tops_kernel(const int* __restrict__ bsum, int* __restrict__ boff, int nb) {
    int t = threadIdx.x; // 64
    int v = (t < nb) ? bsum[t] : 0;
    int incl = v;
#pragma unroll
    for (int ofs = 1; ofs < 64; ofs <<= 1) {
        int u = __shfl_up(incl, ofs, 64);
        if (t >= ofs) incl += u;
    }
    boff[t] = incl - v;
}

__global__ void scan_add_kernel(const int* __restrict__ boff, int* __restrict__ eoff) {
    int i = blockIdx.x * 256 + threadIdx.x;
    if (i < NN) eoff[i] += boff[i >> 10];
    if (i == 0) eoff[NN] = NE;
}

// ---- fused scatter + scoring ----
__global__ void scatter_score_kernel(const int* __restrict__ src, const int* __restrict__ dst,
                                     const float* __restrict__ EA, const float* __restrict__ S,
                                     const float* __restrict__ as_, const float* __restrict__ ad_,
                                     const int* __restrict__ eoff, int* __restrict__ pos,
                                     int* __restrict__ src_sorted,
                                     float* __restrict__ sc1, float* __restrict__ ae2s) {
    int e = blockIdx.x * 256 + threadIdx.x;
    if (e >= NE) return;
    int s = src[e], d = dst[e];
    float a1[4], a2[4];
#pragma unroll
    for (int h = 0; h < 4; h++) { a1[h] = S[S_C1 + h]; a2[h] = S[S_C2 + h]; }
    const float4* EA4 = (const float4*)(EA + (size_t)e * FEA);
#pragma unroll
    for (int q = 0; q < 4; q++) {
        float4 v = EA4[q];
        float vv[4] = {v.x, v.y, v.z, v.w};
#pragma unroll
        for (int j = 0; j < 4; j++) {
            int f = q * 4 + j;
#pragma unroll
            for (int h = 0; h < 4; h++) {
                a1[h] += vv[j] * S[S_KF1 + f * 4 + h];
                a2[h] += vv[j] * S[S_KF2 + f * 4 + h];
            }
        }
    }
    int p = atomicAdd(&pos[d], 1);
    int idx = eoff[d] + p;
    src_sorted[idx] = s;
    ((float4*)ae2s)[idx] = make_float4(a2[0], a2[1], a2[2], a2[3]);
    float4 asv = ((const float4*)as_)[s];
    float4 adv = ((const float4*)ad_)[d];
    float4 r;
    r.x = expf(leakyf(asv.x + adv.x + a1[0]));
    r.y = expf(leakyf(asv.y + adv.y + a1[1]));
    r.z = expf(leakyf(asv.z + adv.z + a1[2]));
    r.w = expf(leakyf(asv.w + adv.w + a1[3]));
    ((float4*)sc1)[idx] = r;
}

// ---- goff via binary search over sorted batch ----
__global__ void goff_bs_kernel(const int* __restrict__ batch, int* __restrict__ goff) {
    int g = threadIdx.x;
    if (g > NG) return;
    int lo = 0, hi = NN;
    while (lo < hi) {
        int mid = (lo + hi) >> 1;
        if (batch[mid] < g) lo = mid + 1; else hi = mid;
    }
    goff[g] = lo;
}

// ---- GAT aggregate-first ----
template <int KD, bool CW>
__global__ __launch_bounds__(256) void agg_gat_kernel(
    const int* __restrict__ eoff, const int* __restrict__ src_sorted,
    const float* __restrict__ wsrc, const float* __restrict__ X,
    const float* __restrict__ as_, const float* __restrict__ ad_,
    const float* __restrict__ Sael, float* __restrict__ agg) {
    constexpr int CHUNKS = KD / 4;
    constexpr int EPW = 64 / CHUNKS;
    int n = blockIdx.x * 4 + (threadIdx.x >> 6);
    if (n >= NN) return;
    int lane = threadIdx.x & 63;
    int sub = lane / CHUNKS;
    int ch = lane % CHUNKS;
    const float4* X4 = (const float4*)X;
    const float4* W4 = (const float4*)wsrc;
    const float4* AS4 = (const float4*)as_;
    float4 asn = AS4[n];
    float4 adn = ((const float4*)ad_)[n];
    float4 a0 = {0, 0, 0, 0}, a1 = a0, a2 = a0, a3 = a0, dn = a0;
    int b = eoff[n], e = eoff[n + 1];
    int nE = e - b;
    int i = sub;
    for (; i + EPW < nE; i += 2 * EPW) {
        int idx0 = b + i, idx1 = b + i + EPW;
        int s0 = src_sorted[idx0], s1 = src_sorted[idx1];
        float4 w0 = W4[idx0], w1 = W4[idx1];
        if (CW) {
            float4 q0 = AS4[s0], q1 = AS4[s1];
            w0.x = expf(leakyf(q0.x + adn.x + w0.x));
            w0.y = expf(leakyf(q0.y + adn.y + w0.y));
            w0.z = expf(leakyf(q0.z + adn.z + w0.z));
            w0.w = expf(leakyf(q0.w + adn.w + w0.w));
            w1.x = expf(leakyf(q1.x + adn.x + w1.x));
            w1.y = expf(leakyf(q1.y + adn.y + w1.y));
            w1.z = expf(leakyf(q1.z + adn.z + w1.z));
            w1.w = expf(leakyf(q1.w + adn.w + w1.w));
        }
        float4 x0 = X4[(size_t)s0 * CHUNKS + ch];
        float4 x1 = X4[(size_t)s1 * CHUNKS + ch];
        fma4(a0, w0.x, x0); fma4(a1, w0.y, x0); fma4(a2, w0.z, x0); fma4(a3, w0.w, x0);
        fma4(a0, w1.x, x1); fma4(a1, w1.y, x1); fma4(a2, w1.z, x1); fma4(a3, w1.w, x1);
        dn.x += w0.x + w1.x; dn.y += w0.y + w1.y;
        dn.z += w0.z + w1.z; dn.w += w0.w + w1.w;
    }
    for (; i < nE; i += EPW) {
        int idx0 = b + i;
        int s0 = src_sorted[idx0];
        float4 w0 = W4[idx0];
        if (CW) {
            float4 q0 = AS4[s0];
            w0.x = expf(leakyf(q0.x + adn.x + w0.x));
            w0.y = expf(leakyf(q0.y + adn.y + w0.y));
            w0.z = expf(leakyf(q0.z + adn.z + w0.z));
            w0.w = expf(leakyf(q0.w + adn.w + w0.w));
        }
        float4 x0 = X4[(size_t)s0 * CHUNKS + ch];
        fma4(a0, w0.x, x0); fma4(a1, w0.y, x0); fma4(a2, w0.z, x0); fma4(a3, w0.w, x0);
        dn.x += w0.x; dn.y += w0.y; dn.z += w0.z; dn.w += w0.w;
    }
    if (sub == 0) {  // self loop
        float e0 = expf(leakyf(asn.x + adn.x + Sael[0]));
        float e1 = expf(leakyf(asn.y + adn.y + Sael[1]));
        float e2 = expf(leakyf(asn.z + adn.z + Sael[2]));
        float e3 = expf(leakyf(asn.w + adn.w + Sael[3]));
        float4 xs = X4[(size_t)n * CHUNKS + ch];
        fma4(a0, e0, xs); fma4(a1, e1, xs); fma4(a2, e2, xs); fma4(a3, e3, xs);
        dn.x += e0; dn.y += e1; dn.z += e2; dn.w += e3;
    }
#pragma unroll
    for (int mask = CHUNKS; mask < 64; mask <<= 1) {
        a0.x += __shfl_xor(a0.x, mask, 64); a0.y += __shfl_xor(a0.y, mask, 64);
        a0.z += __shfl_xor(a0.z, mask, 64); a0.w += __shfl_xor(a0.w, mask, 64);
        a1.x += __shfl_xor(a1.x, mask, 64); a1.y += __shfl_xor(a1.y, mask, 64);
        a1.z += __shfl_xor(a1.z, mask, 64); a1.w += __shfl_xor(a1.w, mask, 64);
        a2.x += __shfl_xor(a2.x, mask, 64); a2.y += __shfl_xor(a2.y, mask, 64);
        a2.z += __shfl_xor(a2.z, mask, 64); a2.w += __shfl_xor(a2.w, mask, 64);
        a3.x += __shfl_xor(a3.x, mask, 64); a3.y += __shfl_xor(a3.y, mask, 64);
        a3.z += __shfl_xor(a3.z, mask, 64); a3.w += __shfl_xor(a3.w, mask, 64);
        dn.x += __shfl_xor(dn.x, mask, 64); dn.y += __shfl_xor(dn.y, mask, 64);
        dn.z += __shfl_xor(dn.z, mask, 64); dn.w += __shfl_xor(dn.w, mask, 64);
    }
    if (sub == 0) {
        float i0 = 1.f / dn.x, i1 = 1.f / dn.y, i2 = 1.f / dn.z, i3 = 1.f / dn.w;
        float4* agg4 = (float4*)agg;
        size_t base = (size_t)n * 4 * CHUNKS + ch;
        agg4[base]              = make_float4(a0.x * i0, a0.y * i0, a0.z * i0, a0.w * i0);
        agg4[base + CHUNKS]     = make_float4(a1.x * i1, a1.y * i1, a1.z * i1, a1.w * i1);
        agg4[base + 2 * CHUNKS] = make_float4(a2.x * i2, a2.y * i2, a2.z * i2, a2.w * i2);
        agg4[base + 3 * CHUNKS] = make_float4(a3.x * i3, a3.y * i3, a3.z * i3, a3.w * i3);
    }
}

// ---- GEMM: out[M,64] = elu(A[M,K]@B[K,64]+bias); 64-row tiles, acc 4x4,
//      register-prefetch software pipeline over 32-k chunks ----
template <int K, bool DOATT>
__global__ __launch_bounds__(256) void gemm64_kernel(
    const float* __restrict__ A, const float* __restrict__ B,
    const float* __restrict__ bias, float* __restrict__ out,
    const float* __restrict__ ms_g, const float* __restrict__ md_g,
    float* __restrict__ as_, float* __restrict__ ad_) {
    __shared__ float As[32 * 68];   // [k][row]
    __shared__ float Bs[32 * 68];   // [k][c]
    __shared__ float msS[256], mdS[256];
    int t = threadIdx.x;
    int tx = t & 15, ty = t >> 4;
    int m_base = blockIdx.x * 64;
    if (DOATT) { msS[t] = ms_g[t]; mdS[t] = md_g[t]; }
    // staging indices (computed once)
    int arow0 = t >> 3, akq0 = (t & 7) * 4;
    int arow1 = (t + 256) >> 3, akq1 = ((t + 256) & 7) * 4;
    int bkr = t >> 4, bnc = (t & 15) * 4;
    int am0 = m_base + arow0, am1 = m_base + arow1;
    float4 fa0, fa1, fb0, fb1;
    // load chunk 0
    fa0 = (am0 < NN) ? *(const float4*)(A + (size_t)am0 * K + akq0) : make_float4(0, 0, 0, 0);
    fa1 = (am1 < NN) ? *(const float4*)(A + (size_t)am1 * K + akq1) : make_float4(0, 0, 0, 0);
    fb0 = *(const float4*)(B + (size_t)bkr * 64 + bnc);
    fb1 = *(const float4*)(B + (size_t)(bkr + 16) * 64 + bnc);
    float acc[4][4] = {};
    for (int k0 = 0;; k0 += 32) {
        // store staged regs to LDS
        As[(akq0 + 0) * 68 + arow0] = fa0.x;
        As[(akq0 + 1) * 68 + arow0] = fa0.y;
        As[(akq0 + 2) * 68 + arow0] = fa0.z;
        As[(akq0 + 3) * 68 + arow0] = fa0.w;
        As[(akq1 + 0) * 68 + arow1] = fa1.x;
        As[(akq1 + 1) * 68 + arow1] = fa1.y;
        As[(akq1 + 2) * 68 + arow1] = fa1.z;
        As[(akq1 + 3) * 68 + arow1] = fa1.w;
        *(float4*)&Bs[bkr * 68 + bnc] = fb0;
        *(float4*)&Bs[(bkr + 16) * 68 + bnc] = fb1;
        __syncthreads();
        // prefetch next chunk while computing this one
        bool more = (k0 + 32 < K);
        if (more) {
            int kn = k0 + 32;
            fa0 = (am0 < NN) ? *(const float4*)(A + (size_t)am0 * K + kn + akq0)
                             : make_float4(0, 0, 0, 0);
            fa1 = (am1 < NN) ? *(const float4*)(A + (size_t)am1 * K + kn + akq1)
                             : make_float4(0, 0, 0, 0);
            fb0 = *(const float4*)(B + (size_t)(kn + bkr) * 64 + bnc);
            fb1 = *(const float4*)(B + (size_t)(kn + bkr + 16) * 64 + bnc);
        }
#pragma unroll
        for (int k = 0; k < 32; k++) {
            float4 av = *(const float4*)&As[k * 68 + ty * 4];
            float4 bv = *(const float4*)&Bs[k * 68 + tx * 4];
            float a[4] = {av.x, av.y, av.z, av.w};
            float b[4] = {bv.x, bv.y, bv.z, bv.w};
#pragma unroll
            for (int i = 0; i < 4; i++)
#pragma unroll
                for (int j = 0; j < 4; j++) acc[i][j] += a[i] * b[j];
        }
        if (!more) break;
        __syncthreads();
    }
    float4 bvv = ((const float4*)bias)[tx];
    float o[4][4];
#pragma unroll
    for (int i = 0; i < 4; i++) {
        o[i][0] = eluf(acc[i][0] + bvv.x);
        o[i][1] = eluf(acc[i][1] + bvv.y);
        o[i][2] = eluf(acc[i][2] + bvv.z);
        o[i][3] = eluf(acc[i][3] + bvv.w);
        int m = m_base + ty * 4 + i;
        if (m < NN)
            *(float4*)(out + (size_t)m * 64 + tx * 4) =
                make_float4(o[i][0], o[i][1], o[i][2], o[i][3]);
    }
    if (DOATT) {
        float ps[4][4] = {}, pd[4][4] = {};
#pragma unroll
        for (int i = 0; i < 4; i++)
#pragma unroll
            for (int j = 0; j < 4; j++) {
                float v = o[i][j];
                int kk = (tx * 4 + j) * 4;
#pragma unroll
                for (int h = 0; h < 4; h++) {
                    ps[i][h] += v * msS[kk + h];
                    pd[i][h] += v * mdS[kk + h];
                }
            }
#pragma unroll
        for (int mk = 1; mk < 16; mk <<= 1) {
#pragma unroll
            for (int i = 0; i < 4; i++)
#pragma unroll
                for (int h = 0; h < 4; h++) {
                    ps[i][h] += __shfl_xor(ps[i][h], mk, 64);
                    pd[i][h] += __shfl_xor(pd[i][h], mk, 64);
                }
        }
        if (tx == 0) {
#pragma unroll
            for (int i = 0; i < 4; i++) {
                int m = m_base + ty * 4 + i;
                if (m < NN) {
                    *(float4*)(as_ + (size_t)m * 4) =
                        make_float4(ps[i][0], ps[i][1], ps[i][2], ps[i][3]);
                    *(float4*)(ad_ + (size_t)m * 4) =
                        make_float4(pd[i][0], pd[i][1], pd[i][2], pd[i][3]);
                }
            }
        }
    }
}

// ---- SAGE mean aggregation into AB[:,0:64]; copy h2 into AB[:,64:128] ----
__global__ __launch_bounds__(256) void sage_agg3_kernel(
    const float* __restrict__ h2, const int* __restrict__ eoff,
    const int* __restrict__ src_sorted, float* __restrict__ AB) {
    int n = blockIdx.x * 16 + (threadIdx.x >> 4);
    if (n >= NN) return;
    int l = threadIdx.x & 15;
    const float4* h24 = (const float4*)h2;
    float4* AB4 = (float4*)AB;
    float ax = 0.f, ay = 0.f, az = 0.f, aw = 0.f;
    int b = eoff[n], e_end = eoff[n + 1];
    int idx = b;
    int stop = b + ((e_end - b) & ~7);
    if (idx < stop) {
        int sreg[8];
#pragma unroll
        for (int u = 0; u < 8; u++) sreg[u] = src_sorted[idx + u];
        idx += 8;
        while (true) {
            int sn[8];
            bool more = idx < stop;
            if (more) {
#pragma unroll
                for (int u = 0; u < 8; u++) sn[u] = src_sorted[idx + u];
            }
#pragma unroll
            for (int u = 0; u < 8; u++) {
                float4 v = h24[(size_t)sreg[u] * 16 + l];
                ax += v.x; ay += v.y; az += v.z; aw += v.w;
            }
            if (!more) break;
#pragma unroll
            for (int u = 0; u < 8; u++) sreg[u] = sn[u];
            idx += 8;
        }
    }
    for (; idx < e_end; idx++) {
        float4 v0 = h24[(size_t)src_sorted[idx] * 16 + l];
        ax += v0.x; ay += v0.y; az += v0.z; aw += v0.w;
    }
    float dg = (float)(e_end - b);
    if (dg < 1.f) dg = 1.f;
    float inv = 1.f / dg;
    AB4[(size_t)n * 32 + l] = make_float4(ax * inv, ay * inv, az * inv, aw * inv);
    AB4[(size_t)n * 32 + 16 + l] = h24[(size_t)n * 16 + l];
}

// ---- fused pool + MLP head: one block per graph -> d_out[192] ----
__global__ __launch_bounds__(256) void pool_mlp_kernel(
    const float* __restrict__ h3, const int* __restrict__ goff,
    const float* __restrict__ lin1W, const float* __restrict__ lin1b,
    const float* __restrict__ lin2W, const float* __restrict__ lin2b,
    const float* __restrict__ telW, const float* __restrict__ telb,
    const float* __restrict__ compW, const float* __restrict__ compb,
    const float* __restrict__ pchW, const float* __restrict__ pchb,
    float* __restrict__ out) {
    __shared__ float red[256];
    __shared__ float g[64], G1[64], G2[64];
    int gi = blockIdx.x, t = threadIdx.x;
    int c = t & 63, li = t >> 6;
    int b = goff[gi], e = goff[gi + 1];
    float sum = 0.f;
    for (int r = b + li; r < e; r += 4) sum += h3[(size_t)r * HID + c];
    red[t] = sum;
    __syncthreads();
    if (t < 64) {
        float v = red[t] + red[t + 64] + red[t + 128] + red[t + 192];
        float cntf = (float)(e - b);
        if (cntf < 1.f) cntf = 1.f;
        g[t] = v / cntf;
    }
    __syncthreads();
    {
        float part = 0.f;
#pragma unroll
        for (int k = li * 16; k < li * 16 + 16; k++) part += g[k] * lin1W[k * 64 + c];
        red[t] = part;
        __syncthreads();
        if (t < 64)
            G1[c] = eluf(red[c] + red[c + 64] + red[c + 128] + red[c + 192] + lin1b[c]);
        __syncthreads();
    }
    {
        float part = 0.f;
#pragma unroll
        for (int k = li * 16; k < li * 16 + 16; k++) part += G1[k] * lin2W[k * 64 + c];
        red[t] = part;
        __syncthreads();
        if (t < 64)
            G2[c] = red[c] + red[c + 64] + red[c + 128] + red[c + 192] + lin2b[c];
        __syncthreads();
    }
    if (t < 192) {
        int h = t >> 6, k = t & 63;
        const float* W = (h == 0) ? telW : ((h == 1) ? compW : pchW);
        red[t] = G2[k] * W[k];
    }
    __syncthreads();
    if (t < 3) {
        float acc = 0.f;
        for (int k = 0; k < 64; k++) acc += red[t * 64 + k];
        float bb = (t == 0) ? telb[0] : ((t == 1) ? compb[0] : pchb[0]);
        out[t * 64 + gi] = acc + bb;
    }
}

extern "C" void kernel_launch(void* const* d_in, const int* in_sizes, int n_in,
                              void* d_out, int out_size, void* d_ws, size_t ws_size,
                              hipStream_t stream) {
    const float* x        = (const float*)d_in[0];
    const float* EA       = (const float*)d_in[1];
    const float* node_emb = (const float*)d_in[2];
    const float* edge_W   = (const float*)d_in[3];
    const float* edge_b   = (const float*)d_in[4];
    const float* W1       = (const float*)d_in[5];
    const float* as1      = (const float*)d_in[6];
    const float* ad1      = (const float*)d_in[7];
    const float* ae1      = (const float*)d_in[8];
    const float* leW1     = (const float*)d_in[9];
    const float* b1       = (const float*)d_in[10];
    const float* W2       = (const float*)d_in[11];
    const float* as2      = (const float*)d_in[12];
    const float* ad2      = (const float*)d_in[13];
    const float* ae2      = (const float*)d_in[14];
    const float* leW2     = (const float*)d_in[15];
    const float* b2       = (const float*)d_in[16];
    const float* sage_Wl  = (const float*)d_in[17];
    const float* sage_bl  = (const float*)d_in[18];
    const float* sage_Wr  = (const float*)d_in[19];
    const float* lin1_W   = (const float*)d_in[20];
    const float* lin1_b   = (const float*)d_in[21];
    const float* lin2_W   = (const float*)d_in[22];
    const float* lin2_b   = (const float*)d_in[23];
    const float* tel_W    = (const float*)d_in[24];
    const float* tel_b    = (const float*)d_in[25];
    const float* comp_W   = (const float*)d_in[26];
    const float* comp_b   = (const float*)d_in[27];
    const float* pch_W    = (const float*)d_in[28];
    const float* pch_b    = (const float*)d_in[29];
    const int* edge_index = (const int*)d_in[30];
    const int* batch      = (const int*)d_in[31];
    const int* node_type  = (const int*)d_in[32];
    float* outp = (float*)d_out;

    const int* srcp = edge_index;
    const int* dstp = edge_index + NE;

    float* wf = (float*)d_ws;
    constexpr size_t OFF_H0    = 0;                               // N*128 (h3 aliases later)
    constexpr size_t OFF_AGG   = OFF_H0 + (size_t)NN * 128;       // N*512 (agg1/agg2/AB alias)
    constexpr size_t OFF_H1    = OFF_AGG + (size_t)NN * 512;      // N*64
    constexpr size_t OFF_H2    = OFF_H1 + (size_t)NN * 64;        // N*64
    constexpr size_t OFF_SC    = OFF_H2 + (size_t)NN * 64;        // E*4
    constexpr size_t OFF_AE2   = OFF_SC + (size_t)NE * 4;         // E*4
    constexpr size_t OFF_AS    = OFF_AE2 + (size_t)NE * 4;        // N*4
    constexpr size_t OFF_AD    = OFF_AS + (size_t)NN * 4;         // N*4
    constexpr size_t OFF_SMALL = OFF_AD + (size_t)NN * 4;         // 4096
    constexpr size_t OFF_WC1   = OFF_SMALL + 4096;                // 32768
    constexpr size_t OFF_WC2   = OFF_WC1 + 32768;                 // 16384
    constexpr size_t OFF_B128  = OFF_WC2 + 16384;                 // 8192
    constexpr size_t F_TOTAL   = OFF_B128 + 8192;

    int* wi         = (int*)(wf + F_TOTAL);
    int* cnt        = wi;                        // N
    int* pos        = wi + NN;                   // N   (adjacent: one memset)
    int* eoff       = pos + NN;                  // N+1
    int* src_sorted = eoff + (NN + 1);           // E
    int* goff       = src_sorted + NE;           // NG+1
    int* bsum       = goff + (NG + 1);           // 64
    int* boff       = bsum + 64;                 // 64

    float* h0    = wf + OFF_H0;
    float* aggb  = wf + OFF_AGG;
    float* h1    = wf + OFF_H1;
    float* h2    = wf + OFF_H2;
    float* sc    = wf + OFF_SC;
    float* ae2s  = wf + OFF_AE2;
    float* as_   = wf + OFF_AS;
    float* ad_   = wf + OFF_AD;
    float* S     = wf + OFF_SMALL;
    float* WC1   = wf + OFF_WC1;
    float* WC2   = wf + OFF_WC2;
    float* B128  = wf + OFF_B128;
    float* AB    = wf + OFF_AGG;                 // alias (agg dead after gemm L2)
    float* h3    = wf + OFF_H0;                  // alias (h0 dead after agg L1)

    hipMemsetAsync(S + S_MEANEA, 0, 16 * sizeof(float), stream);
    hipMemsetAsync(cnt, 0, 2 * NN * sizeof(int), stream);   // cnt + pos

    count_mean_kernel<<<(NE + 511) / 512, 256, 0, stream>>>(dstp, EA, cnt, S);
    prep_weights_kernel<<<224, 256, 0, stream>>>(W1, W2, sage_Wl, sage_Wr, WC1, WC2, B128);
    prep_small_kernel<<<1, 256, 0, stream>>>(W1, as1, ad1, ae1, leW1,
                                             W2, as2, ad2, ae2, leW2,
                                             edge_W, edge_b, S);
    {
        int nb = (NN + 1023) / 1024;  // 30
        scan_blocks_kernel<<<nb, 1024, 0, stream>>>(cnt, eoff, bsum);
        scan_tops_kernel<<<1, 64, 0, stream>>>(bsum, boff, nb);
        scan_add_kernel<<<(NN + 255) / 256, 256, 0, stream>>>(boff, eoff);
    }
    attn_h0_kernel<<<(NN + 63) / 64, 256, 0, stream>>>(x, node_emb, node_type, S, h0, as_, ad_);
    goff_bs_kernel<<<1, 128, 0, stream>>>(batch, goff);
    scatter_score_kernel<<<(NE + 255) / 256, 256, 0, stream>>>(
        srcp, dstp, EA, S, as_, ad_, eoff, pos, src_sorted, sc, ae2s);

    // ----- GAT layer 1 -----
    agg_gat_kernel<128, false><<<(NN + 3) / 4, 256, 0, stream>>>(
        eoff, src_sorted, sc, h0, as_, ad_, S + S_AEL1, aggb);
    gemm64_kernel<512, true><<<(NN + 63) / 64, 256, 0, stream>>>(
        aggb, WC1, b1, h1, S + S_MS2, S + S_MD2, as_, ad_);

    // ----- GAT layer 2 -----
    agg_gat_kernel<64, true><<<(NN + 3) / 4, 256, 0, stream>>>(
        eoff, src_sorted, ae2s, h1, as_, ad_, S + S_AEL2, aggb);
    gemm64_kernel<256, false><<<(NN + 63) / 64, 256, 0, stream>>>(
        aggb, WC2, b2, h2, nullptr, nullptr, nullptr, nullptr);

    // ----- SAGE -----
    sage_agg3_kernel<<<(NN + 15) / 16, 256, 0, stream>>>(h2, eoff, src_sorted, AB);
    gemm64_kernel<128, false><<<(NN + 63) / 64, 256, 0, stream>>>(
        AB, B128, sage_bl, h3, nullptr, nullptr, nullptr, nullptr);

    // ----- fused pool + MLP head -----
    pool_mlp_kernel<<<NG, 256, 0, stream>>>(h3, goff, lin1_W, lin1_b, lin2_W, lin2_b,
                                            tel_W, tel_b, comp_W, comp_b, pch_W, pch_b, outp);
}